// Round 1
// 1733.424 us; speedup vs baseline: 1.1517x; 1.1517x over previous
//
#include <hip/hip_runtime.h>
#include <hip/hip_bf16.h>
#include <math.h>

typedef __hip_bfloat16 bf16;
#define DEVI __device__ __forceinline__
static DEVI float b2f(bf16 v) { return __bfloat162float(v); }
static DEVI float scrub(float v) { return (v - v == 0.f) ? v : 0.f; }

constexpr int SLICE = 64 * 64 * 192;           // per-b elements = 786432

// ws layout (float offsets). Total 64,755,812 floats = 259,023,248 B (~247 MiB)
constexpr size_t O_XH   = 0;          // 25165824
constexpr size_t O_SI   = 25165824;   // 25165824
constexpr size_t O_ZB   = 50331648;   // bf16 z (25165824 elems = 12582912 slots)
constexpr size_t O_KMAP = 62914560;   // 786432
constexpr size_t O_FREQ = 63700992;   // 786432 (converted fp32 freq_embed)
constexpr size_t O_E64  = 64487424;   // 8192 (4096 float2)
constexpr size_t O_DM   = 64495616;   // 4096
constexpr size_t O_DT   = 64499712;   // 4096
constexpr size_t O_WT   = 64503808;   // 36864
constexpr size_t O_POOL = 64540672;   // 6144
constexpr size_t O_SEL  = 64546816;   // 32
constexpr size_t O_FLAG = 64546848;   // 32 (flag int + pad)
constexpr size_t O_W    = 64546880;   // 208932 packed fp32 weights
constexpr size_t WS_NEEDED_BYTES = (size_t)64755812 * 4;

// packed-weight offsets (relative to ws base)
constexpr size_t W_GN   = O_W + 0;      // 96
constexpr size_t W_DWW  = O_W + 96;     // 1728
constexpr size_t W_DWB  = O_W + 1824;   // 192
constexpr size_t W_LINW = O_W + 2016;   // 73728
constexpr size_t W_LINB = O_W + 75744;  // 384
constexpr size_t W_P1W  = O_W + 76128;  // 49152
constexpr size_t W_P1B  = O_W + 125280; // 256
constexpr size_t W_G1   = O_W + 125536; // 256
constexpr size_t W_B1   = O_W + 125792; // 256
constexpr size_t W_P2W  = O_W + 126048; // 8192
constexpr size_t W_P2B  = O_W + 134240; // 32
constexpr size_t W_G2   = O_W + 134272; // 32
constexpr size_t W_B2   = O_W + 134304; // 32
constexpr size_t W_P3W  = O_W + 134336; // 96
constexpr size_t W_P3B  = O_W + 134432; // 4 (3 used)
constexpr size_t W_TOKW = O_W + 134436; // 36864
constexpr size_t W_TOKB = O_W + 171300; // 192
constexpr size_t W_LNG  = O_W + 171492; // 192
constexpr size_t W_LNB  = O_W + 171684; // 192
constexpr size_t W_OUTW = O_W + 171876; // 36864
constexpr size_t W_OUTB = O_W + 208740; // 192

struct CvtArgs {
  const void* src[22];
  int n[22];
  long long off[22];   // float offset into ws
};

// ----------------------------------------------------------------------------
// dtype sniff: bf16 array -> ~64/64 sane uint16 exponents; fp32 -> ~40/64
// flag: 0 = bf16 inputs, 1 = fp32 inputs
// ----------------------------------------------------------------------------
__global__ void sniff_kernel(const unsigned short* xu, int* flag) {
  __shared__ int cnt;
  if (threadIdx.x == 0) cnt = 0;
  __syncthreads();
  unsigned short u = xu[threadIdx.x];
  int e = (u >> 7) & 0xFF;
  int sane = ((e >= 97 && e <= 160) || (u & 0x7FFF) == 0) ? 1 : 0;
  atomicAdd(&cnt, sane);
  __syncthreads();
  if (threadIdx.x == 0) *flag = (cnt >= 56) ? 0 : 1;
}

// convert all small inputs (+freq) to fp32 in ws, per flag
__global__ __launch_bounds__(256) void cvt_kernel(CvtArgs a, float* ws, const int* flag) {
  int flg = *flag;
  int gt = blockIdx.x * 256 + threadIdx.x;
  int gs = gridDim.x * 256;
  for (int s = 0; s < 22; ++s) {
    const void* sp = a.src[s];
    int n = a.n[s];
    float* dst = ws + a.off[s];
    if (flg) {
      const float* f = (const float*)sp;
      for (int i = gt; i < n; i += gs) dst[i] = f[i];
    } else {
      const bf16* h = (const bf16*)sp;
      for (int i = gt; i < n; i += gs) dst[i] = b2f(h[i]);
    }
  }
}

// fallback: zero-fill (2 bytes/elem, safe under both out dtypes)
__global__ __launch_bounds__(256) void fill_zero_kernel(unsigned short* out, int n) {
  int i = blockIdx.x * 256 + threadIdx.x;
  if (i < n) out[i] = 0;
}

// ----------------------------------------------------------------------------
// setup: DCT matrices, E64 twiddles, wT = out_w^T (from converted fp32 outw)
// ----------------------------------------------------------------------------
__global__ __launch_bounds__(256) void setup_kernel(
    float* Dm, float* DT, float2* E64, float* wT, const float* out_w)
{
  int t = blockIdx.x * 256 + threadIdx.x;
  int NTH = gridDim.x * 256;
  const double PI = 3.14159265358979323846;
  for (int i = t; i < 64 * 64; i += NTH) {
    int n = i >> 6, x = i & 63;
    double v = cos((double)n * (((double)x + 0.5) / 64.0) * PI) * sqrt(2.0 / 64.0);
    if (n == 0) v *= 0.70710678118654752440;
    Dm[n * 64 + x] = (float)v;
    DT[x * 64 + n] = (float)v;
  }
  for (int i = t; i < 64 * 64; i += NTH) {
    int k = i >> 6, n = i & 63;
    int m = (k * n) & 63;
    double th = -2.0 * PI * (double)m / 64.0;
    E64[i] = make_float2((float)cos(th), (float)sin(th));
  }
  for (int i = t; i < 192 * 192; i += NTH) {
    int co = i / 192, c = i - co * 192;
    wT[c * 192 + co] = out_w[i];
  }
}

// ----------------------------------------------------------------------------
// depthwise 3x3 conv (NCHW in, NHWC fp32 out), pad 1. grid (6,64,32)
// ----------------------------------------------------------------------------
__global__ __launch_bounds__(256) void conv_kernel(
    const void* xin, const int* flag, const float* dww, const float* dwb, float* out)
{
  int flg = *flag;
  const float* xf = (const float*)xin;
  const bf16*  xb = (const bf16*)xin;
  int c0 = blockIdx.x * 32;
  int h  = blockIdx.y;
  int b  = blockIdx.z;
  __shared__ float in_s[3][32][66];
  __shared__ float wg[32][10];
  __shared__ float bias[32];
  int t = threadIdx.x;
  for (int idx = t; idx < 3 * 32 * 66; idx += 256) {
    int r = idx / (32 * 66);
    int rem = idx - r * (32 * 66);
    int ci = rem / 66, wi = rem - ci * 66;
    int hh = h + r - 1, wwi = wi - 1;
    float v = 0.f;
    if (hh >= 0 && hh < 64 && wwi >= 0 && wwi < 64) {
      size_t ix = (((size_t)b * 192 + c0 + ci) * 64 + hh) * 64 + wwi;
      v = flg ? xf[ix] : b2f(xb[ix]);
    }
    in_s[r][ci][wi] = v;
  }
  for (int idx = t; idx < 32 * 9; idx += 256) {
    int ci = idx / 9;
    wg[ci][idx - ci * 9] = dww[(c0 + ci) * 9 + (idx - ci * 9)];
  }
  if (t < 32) bias[t] = dwb[c0 + t];
  __syncthreads();
  int cc = t & 31, wq = t >> 5;
  for (int j = 0; j < 8; ++j) {
    int w = wq + 8 * j;
    float acc = bias[cc];
#pragma unroll
    for (int r = 0; r < 3; ++r)
#pragma unroll
      for (int kw = 0; kw < 3; ++kw)
        acc += in_s[r][cc][w + kw] * wg[cc][r * 3 + kw];
    out[(((size_t)b * 64 + h) * 64 + w) * 192 + c0 + cc] = acc;
  }
}

// ----------------------------------------------------------------------------
// linear: (131072 x 192) @ lin_w^T (384 x 192) + lin_b -> xh | z(bf16)
// grid (2048, 6)
// ----------------------------------------------------------------------------
__global__ __launch_bounds__(256) void linear_kernel(
    const float* A, const float* Wt, const float* bias, float* xh, bf16* zb)
{
  __shared__ float As[32][65];
  __shared__ float Bs[32][65];
  int m0 = blockIdx.x * 64, n0 = blockIdx.y * 64;
  int t = threadIdx.x, tx = t & 15, ty = t >> 4;
  float acc[4][4] = {};
  for (int k0 = 0; k0 < 192; k0 += 32) {
    int kk = t & 31, mm = t >> 5;
#pragma unroll
    for (int i = 0; i < 8; ++i) {
      As[kk][mm + 8 * i] = A[(size_t)(m0 + mm + 8 * i) * 192 + k0 + kk];
      Bs[kk][mm + 8 * i] = Wt[(size_t)(n0 + mm + 8 * i) * 192 + k0 + kk];
    }
    __syncthreads();
    for (int k = 0; k < 32; ++k) {
      float a[4], bb[4];
#pragma unroll
      for (int i = 0; i < 4; ++i) a[i] = As[k][ty * 4 + i];
#pragma unroll
      for (int j = 0; j < 4; ++j) bb[j] = Bs[k][tx * 4 + j];
#pragma unroll
      for (int i = 0; i < 4; ++i)
#pragma unroll
        for (int j = 0; j < 4; ++j) acc[i][j] += a[i] * bb[j];
    }
    __syncthreads();
  }
  for (int i = 0; i < 4; ++i) {
    int m = m0 + ty * 4 + i;
    for (int j = 0; j < 4; ++j) {
      int n = n0 + tx * 4 + j;
      float v = acc[i][j] + bias[n];
      if (n < 192) xh[(size_t)m * 192 + n] = v;
      else         zb[(size_t)m * 192 + (n - 192)] = __float2bfloat16(v);
    }
  }
}

// ----------------------------------------------------------------------------
// kmap: e = relu(freq @ tok_w^T + tok_b); k = exp(-((pi i/64)^2+(pi j/64)^2)*e)
// grid (64, 3)
// ----------------------------------------------------------------------------
__global__ __launch_bounds__(256) void kmap_kernel(
    const float* A, const float* Wt, const float* bias, float* kout)
{
  __shared__ float As[32][65];
  __shared__ float Bs[32][65];
  int m0 = blockIdx.x * 64, n0 = blockIdx.y * 64;
  int t = threadIdx.x, tx = t & 15, ty = t >> 4;
  float acc[4][4] = {};
  for (int k0 = 0; k0 < 192; k0 += 32) {
    int kk = t & 31, mm = t >> 5;
#pragma unroll
    for (int i = 0; i < 8; ++i) {
      As[kk][mm + 8 * i] = A[(size_t)(m0 + mm + 8 * i) * 192 + k0 + kk];
      Bs[kk][mm + 8 * i] = Wt[(size_t)(n0 + mm + 8 * i) * 192 + k0 + kk];
    }
    __syncthreads();
    for (int k = 0; k < 32; ++k) {
      float a[4], bb[4];
#pragma unroll
      for (int i = 0; i < 4; ++i) a[i] = As[k][ty * 4 + i];
#pragma unroll
      for (int j = 0; j < 4; ++j) bb[j] = Bs[k][tx * 4 + j];
#pragma unroll
      for (int i = 0; i < 4; ++i)
#pragma unroll
        for (int j = 0; j < 4; ++j) acc[i][j] += a[i] * bb[j];
    }
    __syncthreads();
  }
  const float PI2 = 9.86960440108935862f;
  for (int i = 0; i < 4; ++i) {
    int m = m0 + ty * 4 + i;
    int ii = m >> 6, jj = m & 63;
    float d2 = (PI2 / 4096.f) * (float)(ii * ii + jj * jj);
    for (int j = 0; j < 4; ++j) {
      int n = n0 + tx * 4 + j;
      float e = acc[i][j] + bias[n];
      e = e > 0.f ? e : 0.f;
      kout[(size_t)m * 192 + n] = expf(-d2 * e);
    }
  }
}

// ----------------------------------------------------------------------------
// pooled[b,c] = mean_{hw} xh ; grid (12, 32)
// ----------------------------------------------------------------------------
__global__ __launch_bounds__(256) void pool_kernel(const float* xh, float* pooled)
{
  int b = blockIdx.y;
  int ct = blockIdx.x * 16;
  int t = threadIdx.x;
  int cl = t & 15, rg = t >> 4;
  float s = 0.f;
  for (int p = rg; p < 4096; p += 16)
    s += scrub(xh[((size_t)b * 4096 + p) * 192 + ct + cl]);
  __shared__ float red[16][17];
  red[rg][cl] = s;
  __syncthreads();
  if (t < 16) {
    float tot = 0.f;
    for (int r = 0; r < 16; ++r) tot += red[r][t];
    pooled[b * 192 + ct + t] = tot * (1.f / 4096.f);
  }
}

// ----------------------------------------------------------------------------
// MLP + batchnorms + gumbel argmax -> sel[32] ; 1 block
// ----------------------------------------------------------------------------
__global__ __launch_bounds__(256) void mlp_kernel(
    const float* pooled, const float* gn,
    const float* p1w, const float* p1b, const float* g1, const float* b1,
    const float* p2w, const float* p2b, const float* g2, const float* b2,
    const float* p3w, const float* p3b, int* sel)
{
  __shared__ float pl[32 * 192];
  __shared__ float h1s[32 * 256];
  __shared__ float h2s[32 * 32];
  int t = threadIdx.x;
  for (int i = t; i < 32 * 192; i += 256) pl[i] = pooled[i];
  __syncthreads();
  {
    float acc[32];
    float bb = p1b[t];
#pragma unroll
    for (int b = 0; b < 32; ++b) acc[b] = bb;
    for (int c = 0; c < 192; ++c) {
      float w = p1w[t * 192 + c];
#pragma unroll
      for (int b = 0; b < 32; ++b) acc[b] += w * pl[b * 192 + c];
    }
    for (int b = 0; b < 32; ++b) {
      float v = acc[b];
      v = v > 0.f ? v : 0.1f * v;
      h1s[b * 256 + t] = v;
    }
  }
  __syncthreads();
  {
    float m = 0.f;
    for (int b = 0; b < 32; ++b) m += h1s[b * 256 + t];
    m *= (1.f / 32.f);
    float v = 0.f;
    for (int b = 0; b < 32; ++b) { float d = h1s[b * 256 + t] - m; v += d * d; }
    v *= (1.f / 32.f);
    float sc = g1[t] / sqrtf(v + 1e-5f);
    float sh = b1[t] - m * sc;
    for (int b = 0; b < 32; ++b) h1s[b * 256 + t] = h1s[b * 256 + t] * sc + sh;
  }
  __syncthreads();
  {
    int j = t & 31, bg = t >> 5;
    float acc[4];
    float bb = p2b[j];
    for (int i = 0; i < 4; ++i) acc[i] = bb;
    for (int c = 0; c < 256; ++c) {
      float w = p2w[j * 256 + c];
#pragma unroll
      for (int i = 0; i < 4; ++i) acc[i] += w * h1s[(bg * 4 + i) * 256 + c];
    }
    for (int i = 0; i < 4; ++i) {
      float v = acc[i];
      v = v > 0.f ? v : 0.1f * v;
      h2s[(bg * 4 + i) * 32 + j] = v;
    }
  }
  __syncthreads();
  if (t < 32) {
    float m = 0.f;
    for (int b = 0; b < 32; ++b) m += h2s[b * 32 + t];
    m *= (1.f / 32.f);
    float v = 0.f;
    for (int b = 0; b < 32; ++b) { float d = h2s[b * 32 + t] - m; v += d * d; }
    v *= (1.f / 32.f);
    float sc = g2[t] / sqrtf(v + 1e-5f);
    float sh = b2[t] - m * sc;
    for (int b = 0; b < 32; ++b) h2s[b * 32 + t] = h2s[b * 32 + t] * sc + sh;
  }
  __syncthreads();
  if (t < 32) {
    float best = -1e30f; int bi = 0;
    for (int r = 0; r < 3; ++r) {
      float l = p3b[r];
      for (int c = 0; c < 32; ++c) l += p3w[r * 32 + c] * h2s[t * 32 + c];
      l += gn[t * 3 + r];
      if (l > best) { best = l; bi = r; }
    }
    sel[t] = bi;
  }
}

// ----------------------------------------------------------------------------
// DCT stage over first axis of (64, 12288), in-place. grid (192, 32)
// ----------------------------------------------------------------------------
__global__ __launch_bounds__(256) void axis0_kernel(
    float* buf, const float* mat, const int* sel, int branch)
{
  int b = blockIdx.y;
  if (sel[b] != branch) return;
  int q0 = blockIdx.x * 64;
  __shared__ float mT[64][65];
  __shared__ float xs[64][65];
  int t = threadIdx.x;
  for (int i = t; i < 4096; i += 256) {
    int r = i >> 6, c = i & 63;
    mT[c][r] = mat[i];
    xs[r][c] = buf[(size_t)b * SLICE + r * 12288 + q0 + c];
  }
  __syncthreads();
  int tx = t & 15, ty = t >> 4;
  float acc[4][4] = {};
  for (int l = 0; l < 64; ++l) {
    float a[4], xv[4];
#pragma unroll
    for (int i = 0; i < 4; ++i) a[i] = mT[l][ty * 4 + i];
#pragma unroll
    for (int j = 0; j < 4; ++j) xv[j] = xs[l][tx * 4 + j];
#pragma unroll
    for (int i = 0; i < 4; ++i)
#pragma unroll
      for (int j = 0; j < 4; ++j) acc[i][j] += a[i] * xv[j];
  }
  float* ob = buf + (size_t)b * SLICE;
  for (int i = 0; i < 4; ++i)
    for (int j = 0; j < 4; ++j)
      ob[(ty * 4 + i) * 12288 + q0 + tx * 4 + j] = acc[i][j];
}

// DCT stage over middle axis, in-place, optional k multiply. grid (192, 32)
__global__ __launch_bounds__(256) void axis1_kernel(
    float* buf, const float* mat, const float* kmul, const int* sel, int branch)
{
  int b = blockIdx.y;
  if (sel[b] != branch) return;
  int n = blockIdx.x / 3;
  int ct = (blockIdx.x - n * 3) * 64;
  float* base = buf + (size_t)b * SLICE + n * (64 * 192) + ct;
  __shared__ float mT[64][65];
  __shared__ float xs[64][65];
  int t = threadIdx.x;
  for (int i = t; i < 4096; i += 256) {
    int r = i >> 6, c = i & 63;
    mT[c][r] = mat[i];
    xs[r][c] = base[r * 192 + c];
  }
  __syncthreads();
  int tx = t & 15, ty = t >> 4;
  float acc[4][4] = {};
  for (int l = 0; l < 64; ++l) {
    float a[4], xv[4];
#pragma unroll
    for (int i = 0; i < 4; ++i) a[i] = mT[l][ty * 4 + i];
#pragma unroll
    for (int j = 0; j < 4; ++j) xv[j] = xs[l][tx * 4 + j];
#pragma unroll
    for (int i = 0; i < 4; ++i)
#pragma unroll
      for (int j = 0; j < 4; ++j) acc[i][j] += a[i] * xv[j];
  }
  if (kmul) {
    for (int i = 0; i < 4; ++i)
      for (int j = 0; j < 4; ++j)
        acc[i][j] *= kmul[(size_t)(n * 64 + ty * 4 + i) * 192 + ct + tx * 4 + j];
  }
  for (int i = 0; i < 4; ++i)
    for (int j = 0; j < 4; ++j)
      base[(ty * 4 + i) * 192 + tx * 4 + j] = acc[i][j];
}

// ----------------------------------------------------------------------------
// FFT forward over h (real -> complex), real in-place into xh, imag -> Si
// ----------------------------------------------------------------------------
__global__ __launch_bounds__(256) void ffth_kernel(
    float* xh, float* Si, const float2* E64, const int* sel)
{
  int b = blockIdx.y;
  if (sel[b] != 1) return;
  int q0 = blockIdx.x * 64;
  __shared__ float er[64][65], ei[64][65], xs[64][65];
  int t = threadIdx.x;
  for (int i = t; i < 4096; i += 256) {
    int r = i >> 6, c = i & 63;
    float2 e = E64[i];
    er[r][c] = e.x; ei[r][c] = e.y;
    xs[r][c] = xh[(size_t)b * SLICE + r * 12288 + q0 + c];
  }
  __syncthreads();
  int tx = t & 15, ty = t >> 4;
  float ar[4][4] = {}, ai[4][4] = {};
  for (int l = 0; l < 64; ++l) {
    float e1[4], e2[4], xv[4];
#pragma unroll
    for (int i = 0; i < 4; ++i) { e1[i] = er[l][ty * 4 + i]; e2[i] = ei[l][ty * 4 + i]; }
#pragma unroll
    for (int j = 0; j < 4; ++j) xv[j] = xs[l][tx * 4 + j];
#pragma unroll
    for (int i = 0; i < 4; ++i)
#pragma unroll
      for (int j = 0; j < 4; ++j) { ar[i][j] += e1[i] * xv[j]; ai[i][j] += e2[i] * xv[j]; }
  }
  size_t ob = (size_t)b * SLICE;
  for (int i = 0; i < 4; ++i)
    for (int j = 0; j < 4; ++j) {
      size_t o = ob + (size_t)(ty * 4 + i) * 12288 + q0 + tx * 4 + j;
      xh[o] = ar[i][j];
      Si[o] = ai[i][j];
    }
}

// FFT over w (complex, in-place). grid (384, 32)
__global__ __launch_bounds__(256) void fftw_kernel(
    float* Sr, float* Si, const float2* E64, const int* sel, float s)
{
  int b = blockIdx.y;
  if (sel[b] != 1) return;
  int kh = blockIdx.x / 6;
  int ct = (blockIdx.x - kh * 6) * 32;
  float* br = Sr + (size_t)b * SLICE + kh * 12288 + ct;
  float* bi = Si + (size_t)b * SLICE + kh * 12288 + ct;
  __shared__ float er[64][65], ei[64][65];
  __shared__ float xr[64][33], xi[64][33];
  int t = threadIdx.x;
  for (int i = t; i < 4096; i += 256) {
    float2 e = E64[i];
    er[i >> 6][i & 63] = e.x;
    ei[i >> 6][i & 63] = s * e.y;
  }
  for (int i = t; i < 2048; i += 256) {
    int l = i >> 5, q = i & 31;
    xr[l][q] = br[l * 192 + q];
    xi[l][q] = bi[l * 192 + q];
  }
  __syncthreads();
  int tx = t & 7, ty = t >> 3;
  float ar[2][4] = {}, ac[2][4] = {};
  for (int l = 0; l < 64; ++l) {
    float e1a = er[l][ty],      e2a = ei[l][ty];
    float e1b = er[l][ty + 32], e2b = ei[l][ty + 32];
#pragma unroll
    for (int j = 0; j < 4; ++j) {
      float vr = xr[l][tx * 4 + j], vi = xi[l][tx * 4 + j];
      ar[0][j] += e1a * vr - e2a * vi;
      ac[0][j] += e1a * vi + e2a * vr;
      ar[1][j] += e1b * vr - e2b * vi;
      ac[1][j] += e1b * vi + e2b * vr;
    }
  }
  for (int r = 0; r < 2; ++r) {
    int kw = ty + r * 32;
    for (int j = 0; j < 4; ++j) {
      br[kw * 192 + tx * 4 + j] = ar[r][j];
      bi[kw * 192 + tx * 4 + j] = ac[r][j];
    }
  }
}

// ----------------------------------------------------------------------------
// Fused c-stage via Cooley-Tukey 3x64: S <- IDFT_c( DFT_c(S) * k*SCALE ),
// in-place per 32-row tile. Complex data LDS-interleaved: float2 T[c][row],
// row-stride 34 complex (272 B: 16B-aligned, b128-able).
// Forward: n = 3*n2+n1 -> three strided DFT-64 (one shared rotator since all
// three use identical omega64 twiddles) -> W192^{n1 m} twiddle -> radix-3
// combine (in registers). k-multiply. Inverse: radix-3 split (registers) ->
// conj twiddle -> LDS transpose -> three IDFT-64. ~2.9x fewer VALU ops than
// direct 192-pt DFT; LDS reads are 6 broadcast b128/step.
// Thread map: tx=t&31 -> m in {tx,tx+32}; ty=t>>5 -> rows 4*ty..4*ty+3.
// grid (128, 32). LDS 52224 B (3 blocks/CU).
// ----------------------------------------------------------------------------
__global__ __launch_bounds__(256, 3) void fftc_fused_kernel(
    float* Sr, float* Si, const float* kmap, const int* sel)
{
  int b = blockIdx.y;
  if (sel[b] != 1) return;
  int m0 = blockIdx.x * 32;
  float* gr = Sr + (size_t)b * SLICE + (size_t)m0 * 192;
  float* gi = Si + (size_t)b * SLICE + (size_t)m0 * 192;
  __shared__ __align__(16) float2 T[192][34];
  int t = threadIdx.x;
  for (int i = t; i < 6144; i += 256) {
    int row = i / 192, c = i - row * 192;
    T[c][row] = make_float2(gr[i], gi[i]);
  }
  int tx = t & 31, ty = t >> 5;
  int rbase = ty * 4;
  // per-thread constants (2 double sincos, everything else derived)
  double A = 2.0 * 3.14159265358979323846 * (double)tx;
  double sa, ca, sb, cb;
  sincos(A / 64.0, &sa, &ca);    // angle of omega64^tx
  sincos(A / 192.0, &sb, &cb);   // angle of W192^tx
  float c64 = (float)ca, s64 = (float)sa;
  float cw = (float)cb, sw = (float)sb;
  const float S3 = 0.86602540378443864676f;
  // forward rotator steps: omega64^{tx+32u} (u=1 is -u=0 since omega64^32=-1)
  float fsr[2], fsi[2];
  fsr[0] = c64;  fsi[0] = -s64;
  fsr[1] = -c64; fsi[1] = s64;
  // forward twiddles w1[u] = W192^{tx+32u} (W192^32 = (0.5, -S3)), w2 = w1^2
  float w1r[2], w1i[2], w2r[2], w2i[2];
  w1r[0] = cw;                   w1i[0] = -sw;
  w1r[1] = 0.5f * cw - S3 * sw;  w1i[1] = -S3 * cw - 0.5f * sw;
#pragma unroll
  for (int u = 0; u < 2; ++u) {
    w2r[u] = w1r[u] * w1r[u] - w1i[u] * w1i[u];
    w2i[u] = 2.f * w1r[u] * w1i[u];
  }
  __syncthreads();
  // ---- pass 1: Y_{n1}[m] = sum_{n2} x[3*n2+n1] * omega64^{n2 m} ----
  float ar[2][3][4], ai[2][3][4];
#pragma unroll
  for (int u = 0; u < 2; ++u)
#pragma unroll
    for (int n1 = 0; n1 < 3; ++n1)
#pragma unroll
      for (int r = 0; r < 4; ++r) { ar[u][n1][r] = 0.f; ai[u][n1][r] = 0.f; }
  {
    float pr[2], pq[2];
    pr[0] = 1.f; pr[1] = 1.f; pq[0] = 0.f; pq[1] = 0.f;
    for (int n2 = 0; n2 < 64; ++n2) {
      const float4* p0 = (const float4*)&T[3 * n2][rbase];
      const float4* p1 = (const float4*)&T[3 * n2 + 1][rbase];
      const float4* p2 = (const float4*)&T[3 * n2 + 2][rbase];
      float4 q00 = p0[0], q01 = p0[1];
      float4 q10 = p1[0], q11 = p1[1];
      float4 q20 = p2[0], q21 = p2[1];
      float xr[3][4], xi[3][4];
      xr[0][0] = q00.x; xi[0][0] = q00.y; xr[0][1] = q00.z; xi[0][1] = q00.w;
      xr[0][2] = q01.x; xi[0][2] = q01.y; xr[0][3] = q01.z; xi[0][3] = q01.w;
      xr[1][0] = q10.x; xi[1][0] = q10.y; xr[1][1] = q10.z; xi[1][1] = q10.w;
      xr[1][2] = q11.x; xi[1][2] = q11.y; xr[1][3] = q11.z; xi[1][3] = q11.w;
      xr[2][0] = q20.x; xi[2][0] = q20.y; xr[2][1] = q20.z; xi[2][1] = q20.w;
      xr[2][2] = q21.x; xi[2][2] = q21.y; xr[2][3] = q21.z; xi[2][3] = q21.w;
#pragma unroll
      for (int u = 0; u < 2; ++u) {
        float er = pr[u], ei = pq[u];
#pragma unroll
        for (int n1 = 0; n1 < 3; ++n1)
#pragma unroll
          for (int r = 0; r < 4; ++r) {
            ar[u][n1][r] += xr[n1][r] * er - xi[n1][r] * ei;
            ai[u][n1][r] += xr[n1][r] * ei + xi[n1][r] * er;
          }
        float nr = er * fsr[u] - ei * fsi[u];
        pq[u] = er * fsi[u] + ei * fsr[u];
        pr[u] = nr;
      }
    }
  }
  // ---- twiddle + radix-3 combine, k-multiply, radix-3 split + conj twiddle
  // (all in registers; result V_{n1}[m] overwrites ar/ai) ----
  const float SCALE = 1.0f / 786432.0f;
#pragma unroll
  for (int u = 0; u < 2; ++u) {
    int m = tx + 32 * u;
#pragma unroll
    for (int r = 0; r < 4; ++r) {
      int row = rbase + r;
      float Y0r = ar[u][0][r], Y0i = ai[u][0][r];
      float Y1r = ar[u][1][r], Y1i = ai[u][1][r];
      float Y2r = ar[u][2][r], Y2i = ai[u][2][r];
      float T1r = Y1r * w1r[u] - Y1i * w1i[u];
      float T1i = Y1r * w1i[u] + Y1i * w1r[u];
      float T2r = Y2r * w2r[u] - Y2i * w2i[u];
      float T2i = Y2r * w2i[u] + Y2i * w2r[u];
      // forward radix-3: X_j = sum_{n1} omega3^{n1 j} T_{n1}
      float aRr = T1r + T2r, aRi = T1i + T2i;
      float bRr = T1r - T2r, bRi = T1i - T2i;
      float X0r = Y0r + aRr, X0i = Y0i + aRi;
      float cfr = Y0r - 0.5f * aRr, cfi = Y0i - 0.5f * aRi;
      float X1r = cfr + S3 * bRi, X1i = cfi - S3 * bRr;
      float X2r = cfr - S3 * bRi, X2i = cfi + S3 * bRr;
      const float* kp = kmap + (size_t)(m0 + row) * 192 + m;
      float k0 = kp[0] * SCALE, k1 = kp[64] * SCALE, k2 = kp[128] * SCALE;
      X0r *= k0; X0i *= k0; X1r *= k1; X1i *= k1; X2r *= k2; X2i *= k2;
      // inverse radix-3: U_{n1} = sum_j omega3^{-n1 j} X'_j
      float a2r = X1r + X2r, a2i = X1i + X2i;
      float b2r = X1r - X2r, b2i = X1i - X2i;
      float U0r = X0r + a2r, U0i = X0i + a2i;
      float c2r = X0r - 0.5f * a2r, c2i = X0i - 0.5f * a2i;
      float U1r = c2r - S3 * b2i, U1i = c2i + S3 * b2r;
      float U2r = c2r + S3 * b2i, U2i = c2i - S3 * b2r;
      // V_{n1} = U_{n1} * conj(w_{n1})
      ar[u][0][r] = U0r;
      ai[u][0][r] = U0i;
      ar[u][1][r] = U1r * w1r[u] + U1i * w1i[u];
      ai[u][1][r] = U1i * w1r[u] - U1r * w1i[u];
      ar[u][2][r] = U2r * w2r[u] + U2i * w2i[u];
      ai[u][2][r] = U2i * w2r[u] - U2r * w2i[u];
    }
  }
  __syncthreads();   // all pass-1 reads of T done before overwriting with V
#pragma unroll
  for (int u = 0; u < 2; ++u)
#pragma unroll
    for (int n1 = 0; n1 < 3; ++n1)
#pragma unroll
      for (int r = 0; r < 4; ++r)
        T[n1 * 64 + tx + 32 * u][rbase + r] =
            make_float2(ar[u][n1][r], ai[u][n1][r]);
  __syncthreads();
  // ---- pass 2: x[3*n2+n1] = sum_m V_{n1}[m] * omega64^{-n2 m}, n2=tx+32u ----
  float qr_[2][3][4], qi_[2][3][4];
#pragma unroll
  for (int u = 0; u < 2; ++u)
#pragma unroll
    for (int n1 = 0; n1 < 3; ++n1)
#pragma unroll
      for (int r = 0; r < 4; ++r) { qr_[u][n1][r] = 0.f; qi_[u][n1][r] = 0.f; }
  {
    // inverse rotator steps: conj(omega64^{tx+32u})
    float isr[2], isi[2];
    isr[0] = c64;  isi[0] = s64;
    isr[1] = -c64; isi[1] = -s64;
    float pr[2], pq[2];
    pr[0] = 1.f; pr[1] = 1.f; pq[0] = 0.f; pq[1] = 0.f;
    for (int ms = 0; ms < 64; ++ms) {
      const float4* p0 = (const float4*)&T[ms][rbase];
      const float4* p1 = (const float4*)&T[64 + ms][rbase];
      const float4* p2 = (const float4*)&T[128 + ms][rbase];
      float4 q00 = p0[0], q01 = p0[1];
      float4 q10 = p1[0], q11 = p1[1];
      float4 q20 = p2[0], q21 = p2[1];
      float xr[3][4], xi[3][4];
      xr[0][0] = q00.x; xi[0][0] = q00.y; xr[0][1] = q00.z; xi[0][1] = q00.w;
      xr[0][2] = q01.x; xi[0][2] = q01.y; xr[0][3] = q01.z; xi[0][3] = q01.w;
      xr[1][0] = q10.x; xi[1][0] = q10.y; xr[1][1] = q10.z; xi[1][1] = q10.w;
      xr[1][2] = q11.x; xi[1][2] = q11.y; xr[1][3] = q11.z; xi[1][3] = q11.w;
      xr[2][0] = q20.x; xi[2][0] = q20.y; xr[2][1] = q20.z; xi[2][1] = q20.w;
      xr[2][2] = q21.x; xi[2][2] = q21.y; xr[2][3] = q21.z; xi[2][3] = q21.w;
#pragma unroll
      for (int u = 0; u < 2; ++u) {
        float er = pr[u], ei = pq[u];
#pragma unroll
        for (int n1 = 0; n1 < 3; ++n1)
#pragma unroll
          for (int r = 0; r < 4; ++r) {
            qr_[u][n1][r] += xr[n1][r] * er - xi[n1][r] * ei;
            qi_[u][n1][r] += xr[n1][r] * ei + xi[n1][r] * er;
          }
        float nr = er * isr[u] - ei * isi[u];
        pq[u] = er * isi[u] + ei * isr[u];
        pr[u] = nr;
      }
    }
  }
#pragma unroll
  for (int r = 0; r < 4; ++r) {
    int row = rbase + r;
#pragma unroll
    for (int u = 0; u < 2; ++u) {
      int c0 = 3 * (tx + 32 * u);
#pragma unroll
      for (int n1 = 0; n1 < 3; ++n1) {
        gr[(size_t)row * 192 + c0 + n1] = qr_[u][n1][r];
        gi[(size_t)row * 192 + c0 + n1] = qi_[u][n1][r];
      }
    }
  }
}

// inverse h-stage, real part only, in-place into xh. grid (384, 32)
__global__ __launch_bounds__(256) void ffthi_kernel(
    float* Sr, const float* Si, const float2* E64, const int* sel)
{
  int b = blockIdx.y;
  if (sel[b] != 1) return;
  int q0 = blockIdx.x * 32;
  __shared__ float er[64][65], ei[64][65];
  __shared__ float xr[64][33], xi[64][33];
  int t = threadIdx.x;
  for (int i = t; i < 4096; i += 256) {
    float2 e = E64[i];
    er[i >> 6][i & 63] = e.x;
    ei[i >> 6][i & 63] = e.y;
  }
  for (int i = t; i < 2048; i += 256) {
    int l = i >> 5, q = i & 31;
    size_t o = (size_t)b * SLICE + (size_t)l * 12288 + q0 + q;
    xr[l][q] = Sr[o];
    xi[l][q] = Si[o];
  }
  __syncthreads();
  int tx = t & 7, ty = t >> 3;
  float acc[2][4] = {};
  for (int l = 0; l < 64; ++l) {
    float e1a = er[l][ty],      e2a = ei[l][ty];
    float e1b = er[l][ty + 32], e2b = ei[l][ty + 32];
#pragma unroll
    for (int j = 0; j < 4; ++j) {
      float vr = xr[l][tx * 4 + j], vi = xi[l][tx * 4 + j];
      acc[0][j] += e1a * vr + e2a * vi;   // Re(e^{+i th} A), ei = -sin
      acc[1][j] += e1b * vr + e2b * vi;
    }
  }
  for (int r = 0; r < 2; ++r) {
    int h = ty + r * 32;
    for (int j = 0; j < 4; ++j)
      Sr[(size_t)b * SLICE + (size_t)h * 12288 + q0 + tx * 4 + j] = acc[r][j];
  }
}

// ----------------------------------------------------------------------------
// Haar branch, in-place on xh (haar along C: 64-chunks then full 192)
// grid (128, 32)
// ----------------------------------------------------------------------------
__global__ __launch_bounds__(256) void haar_kernel(
    float* xh, const float* kmap, const int* sel)
{
  int b = blockIdx.y;
  if (sel[b] != 2) return;
  int h = blockIdx.x >> 1;
  int w0 = (blockIdx.x & 1) * 32;
  size_t base = (size_t)b * SLICE + ((size_t)h * 64 + w0) * 192;
  __shared__ float A[32 * 192];
  __shared__ float Bf[32 * 192];
  int t = threadIdx.x;
  for (int i = t; i < 6144; i += 256) A[i] = xh[base + i];
  __syncthreads();
  for (int u = t; u < 32 * 96; u += 256) {
    int p = u / 96, r = u - p * 96;
    int ch = r >> 5, i = r & 31;
    float v0 = A[p * 192 + ch * 64 + 2 * i];
    float v1 = A[p * 192 + ch * 64 + 2 * i + 1];
    Bf[p * 192 + ch * 64 + i]      = (v0 + v1) * 0.5f;
    Bf[p * 192 + ch * 64 + 32 + i] = (v0 - v1) * 0.5f;
  }
  __syncthreads();
  for (int u = t; u < 32 * 96; u += 256) {
    int p = u / 96, i = u - p * 96;
    float v0 = Bf[p * 192 + 2 * i];
    float v1 = Bf[p * 192 + 2 * i + 1];
    A[p * 192 + i]      = (v0 + v1) * 0.5f;
    A[p * 192 + 96 + i] = (v0 - v1) * 0.5f;
  }
  __syncthreads();
  for (int i = t; i < 6144; i += 256)
    A[i] *= kmap[((size_t)h * 64 + w0) * 192 + i];
  __syncthreads();
  for (int u = t; u < 32 * 96; u += 256) {
    int p = u / 96, r = u - p * 96;
    int ch = r >> 5, i = r & 31;
    float a = A[p * 192 + ch * 64 + i];
    float d = A[p * 192 + ch * 64 + 32 + i];
    Bf[p * 192 + ch * 64 + 2 * i]     = a + d;
    Bf[p * 192 + ch * 64 + 2 * i + 1] = a - d;
  }
  __syncthreads();
  for (int u = t; u < 32 * 96; u += 256) {
    int p = u / 96, i = u - p * 96;
    float a = Bf[p * 192 + i];
    float d = Bf[p * 192 + 96 + i];
    A[p * 192 + 2 * i]     = a + d;
    A[p * 192 + 2 * i + 1] = a - d;
  }
  __syncthreads();
  for (int i = t; i < 6144; i += 256) xh[base + i] = A[i];
}

// ----------------------------------------------------------------------------
// final: LN(c) * silu(z) @ out_w^T + out_b, dual-dtype store. grid 2048
// ----------------------------------------------------------------------------
__global__ __launch_bounds__(256) void final_kernel(
    const float* comb, const bf16* zb, const float* lng, const float* lnb,
    const float* wT, const float* outb, void* outp, const int* flag)
{
  int flg = *flag;
  int bi = blockIdx.x;
  int b = bi >> 6, h = bi & 63;
  size_t base = ((size_t)b * 4096 + (size_t)h * 64) * 192;
  __shared__ float As[64 * 194];
  __shared__ float mu[64], rs[64];
  int t = threadIdx.x;
  for (int e = t; e < 12288; e += 256) {
    int p = e / 192, c = e - p * 192;
    As[p * 194 + c] = scrub(comb[base + e]);
  }
  __syncthreads();
  if (t < 64) {
    float s = 0.f;
    for (int c = 0; c < 192; ++c) s += As[t * 194 + c];
    float m = s * (1.f / 192.f);
    float v = 0.f;
    for (int c = 0; c < 192; ++c) { float d = As[t * 194 + c] - m; v += d * d; }
    v *= (1.f / 192.f);
    mu[t] = m;
    rs[t] = 1.f / sqrtf(v + 1e-5f);
  }
  __syncthreads();
  for (int e = t; e < 12288; e += 256) {
    int p = e / 192, c = e - p * 192;
    float v = (As[p * 194 + c] - mu[p]) * rs[p] * lng[c] + lnb[c];
    float zv = scrub(b2f(zb[base + e]));
    v *= zv / (1.f + expf(-zv));
    As[p * 194 + c] = v;
  }
  __syncthreads();
  int tx = t & 15, ty = t >> 4;
  float acc[4][12];
  for (int i = 0; i < 4; ++i)
    for (int j = 0; j < 12; ++j) acc[i][j] = 0.f;
  for (int c = 0; c < 192; ++c) {
    float av[4];
#pragma unroll
    for (int i = 0; i < 4; ++i) av[i] = As[(ty * 4 + i) * 194 + c];
    float wv[12];
#pragma unroll
    for (int j = 0; j < 12; ++j) wv[j] = wT[(size_t)c * 192 + tx * 12 + j];
#pragma unroll
    for (int i = 0; i < 4; ++i)
#pragma unroll
      for (int j = 0; j < 12; ++j) acc[i][j] += av[i] * wv[j];
  }
  __syncthreads();
  for (int i = 0; i < 4; ++i)
    for (int j = 0; j < 12; ++j) {
      int co = tx * 12 + j, p = ty * 4 + i;
      As[co * 64 + p] = acc[i][j] + outb[co];
    }
  __syncthreads();
  for (int e = t; e < 12288; e += 256) {
    int co = e >> 6, w = e & 63;
    size_t oi = (((size_t)b * 192 + co) * 64 + h) * 64 + w;
    if (flg) ((float*)outp)[oi] = As[e];
    else     ((bf16*)outp)[oi] = __float2bfloat16(As[e]);
  }
}

// ----------------------------------------------------------------------------
extern "C" void kernel_launch(void* const* d_in, const int* in_sizes, int n_in,
                              void* d_out, int out_size, void* d_ws, size_t ws_size,
                              hipStream_t stream) {
  (void)in_sizes; (void)n_in;
  if (ws_size < WS_NEEDED_BYTES) {
    fill_zero_kernel<<<(out_size + 255) / 256, 256, 0, stream>>>(
        (unsigned short*)d_out, out_size);
    return;
  }
  float* ws    = (float*)d_ws;
  float* xh    = ws + O_XH;
  float* Si    = ws + O_SI;
  bf16*  zb    = (bf16*)(ws + O_ZB);
  float* kmap  = ws + O_KMAP;
  float2* E64  = (float2*)(ws + O_E64);
  float* Dm    = ws + O_DM;
  float* DT    = ws + O_DT;
  float* wT    = ws + O_WT;
  float* pooled= ws + O_POOL;
  int*   sel   = (int*)(ws + O_SEL);
  int*   flag  = (int*)(ws + O_FLAG);

  sniff_kernel<<<1, 64, 0, stream>>>((const unsigned short*)d_in[0], flag);

  CvtArgs ca;
  const int srcidx[22] = {2,3,4,5,6,7,8,9,10,11,12,13,14,15,16,17,18,19,20,21,22,1};
  const int ns[22] = {96,1728,192,73728,384,49152,256,256,256,8192,32,32,32,96,3,
                      36864,192,192,192,36864,192,786432};
  const long long offs[22] = {
    (long long)W_GN,(long long)W_DWW,(long long)W_DWB,(long long)W_LINW,
    (long long)W_LINB,(long long)W_P1W,(long long)W_P1B,(long long)W_G1,
    (long long)W_B1,(long long)W_P2W,(long long)W_P2B,(long long)W_G2,
    (long long)W_B2,(long long)W_P3W,(long long)W_P3B,(long long)W_TOKW,
    (long long)W_TOKB,(long long)W_LNG,(long long)W_LNB,(long long)W_OUTW,
    (long long)W_OUTB,(long long)O_FREQ};
  for (int i = 0; i < 22; ++i) { ca.src[i] = d_in[srcidx[i]]; ca.n[i] = ns[i]; ca.off[i] = offs[i]; }
  cvt_kernel<<<64, 256, 0, stream>>>(ca, ws, flag);

  setup_kernel<<<64, 256, 0, stream>>>(Dm, DT, E64, wT, ws + W_OUTW);
  conv_kernel<<<dim3(6, 64, 32), 256, 0, stream>>>(d_in[0], flag, ws + W_DWW, ws + W_DWB, Si);
  linear_kernel<<<dim3(2048, 6), 256, 0, stream>>>(Si, ws + W_LINW, ws + W_LINB, xh, zb);
  pool_kernel<<<dim3(12, 32), 256, 0, stream>>>(xh, pooled);
  mlp_kernel<<<1, 256, 0, stream>>>(pooled, ws + W_GN,
      ws + W_P1W, ws + W_P1B, ws + W_G1, ws + W_B1,
      ws + W_P2W, ws + W_P2B, ws + W_G2, ws + W_B2,
      ws + W_P3W, ws + W_P3B, sel);
  kmap_kernel<<<dim3(64, 3), 256, 0, stream>>>(ws + O_FREQ, ws + W_TOKW, ws + W_TOKB, kmap);
  // DCT branch (sel==0), in-place on xh
  axis0_kernel<<<dim3(192, 32), 256, 0, stream>>>(xh, Dm, sel, 0);
  axis1_kernel<<<dim3(192, 32), 256, 0, stream>>>(xh, Dm, kmap, sel, 0);
  axis1_kernel<<<dim3(192, 32), 256, 0, stream>>>(xh, DT, nullptr, sel, 0);
  axis0_kernel<<<dim3(192, 32), 256, 0, stream>>>(xh, DT, sel, 0);
  // FFT branch (sel==1); b-axis FFT/IFFT cancels analytically; in-place (xh,Si)
  ffth_kernel<<<dim3(192, 32), 256, 0, stream>>>(xh, Si, E64, sel);
  fftw_kernel<<<dim3(384, 32), 256, 0, stream>>>(xh, Si, E64, sel, 1.f);
  fftc_fused_kernel<<<dim3(128, 32), 256, 0, stream>>>(xh, Si, kmap, sel);
  fftw_kernel<<<dim3(384, 32), 256, 0, stream>>>(xh, Si, E64, sel, -1.f);
  ffthi_kernel<<<dim3(384, 32), 256, 0, stream>>>(xh, Si, E64, sel);
  // Haar branch (sel==2), in-place on xh
  haar_kernel<<<dim3(128, 32), 256, 0, stream>>>(xh, kmap, sel);
  // epilogue
  final_kernel<<<2048, 256, 0, stream>>>(xh, zb, ws + W_LNG, ws + W_LNB,
                                         wT, ws + W_OUTB, d_out, flag);
}

// Round 2
// 1618.143 us; speedup vs baseline: 1.2338x; 1.0712x over previous
//
#include <hip/hip_runtime.h>
#include <hip/hip_bf16.h>
#include <math.h>

typedef __hip_bfloat16 bf16;
#define DEVI __device__ __forceinline__
static DEVI float b2f(bf16 v) { return __bfloat162float(v); }
static DEVI float scrub(float v) { return (v - v == 0.f) ? v : 0.f; }

constexpr int SLICE = 64 * 64 * 192;           // per-b elements = 786432

// ws layout (float offsets). Total 64,755,812 floats = 259,023,248 B (~247 MiB)
constexpr size_t O_XH   = 0;          // 25165824
constexpr size_t O_SI   = 25165824;   // 25165824
constexpr size_t O_ZB   = 50331648;   // bf16 z (25165824 elems = 12582912 slots)
constexpr size_t O_KMAP = 62914560;   // 786432
constexpr size_t O_FREQ = 63700992;   // 786432 (converted fp32 freq_embed)
constexpr size_t O_E64  = 64487424;   // 8192 (4096 float2)
constexpr size_t O_DM   = 64495616;   // 4096
constexpr size_t O_DT   = 64499712;   // 4096
constexpr size_t O_WT   = 64503808;   // 36864
constexpr size_t O_POOL = 64540672;   // 6144
constexpr size_t O_SEL  = 64546816;   // 32
constexpr size_t O_FLAG = 64546848;   // 32 (flag int + pad)
constexpr size_t O_W    = 64546880;   // 208932 packed fp32 weights
constexpr size_t WS_NEEDED_BYTES = (size_t)64755812 * 4;

// packed-weight offsets (relative to ws base)
constexpr size_t W_GN   = O_W + 0;      // 96
constexpr size_t W_DWW  = O_W + 96;     // 1728
constexpr size_t W_DWB  = O_W + 1824;   // 192
constexpr size_t W_LINW = O_W + 2016;   // 73728
constexpr size_t W_LINB = O_W + 75744;  // 384
constexpr size_t W_P1W  = O_W + 76128;  // 49152
constexpr size_t W_P1B  = O_W + 125280; // 256
constexpr size_t W_G1   = O_W + 125536; // 256
constexpr size_t W_B1   = O_W + 125792; // 256
constexpr size_t W_P2W  = O_W + 126048; // 8192
constexpr size_t W_P2B  = O_W + 134240; // 32
constexpr size_t W_G2   = O_W + 134272; // 32
constexpr size_t W_B2   = O_W + 134304; // 32
constexpr size_t W_P3W  = O_W + 134336; // 96
constexpr size_t W_P3B  = O_W + 134432; // 4 (3 used)
constexpr size_t W_TOKW = O_W + 134436; // 36864
constexpr size_t W_TOKB = O_W + 171300; // 192
constexpr size_t W_LNG  = O_W + 171492; // 192
constexpr size_t W_LNB  = O_W + 171684; // 192
constexpr size_t W_OUTW = O_W + 171876; // 36864
constexpr size_t W_OUTB = O_W + 208740; // 192

struct CvtArgs {
  const void* src[22];
  int n[22];
  long long off[22];   // float offset into ws
};

// ----------------------------------------------------------------------------
// dtype sniff: bf16 array -> ~64/64 sane uint16 exponents; fp32 -> ~40/64
// flag: 0 = bf16 inputs, 1 = fp32 inputs
// ----------------------------------------------------------------------------
__global__ void sniff_kernel(const unsigned short* xu, int* flag) {
  __shared__ int cnt;
  if (threadIdx.x == 0) cnt = 0;
  __syncthreads();
  unsigned short u = xu[threadIdx.x];
  int e = (u >> 7) & 0xFF;
  int sane = ((e >= 97 && e <= 160) || (u & 0x7FFF) == 0) ? 1 : 0;
  atomicAdd(&cnt, sane);
  __syncthreads();
  if (threadIdx.x == 0) *flag = (cnt >= 56) ? 0 : 1;
}

// convert all small inputs (+freq) to fp32 in ws, per flag
__global__ __launch_bounds__(256) void cvt_kernel(CvtArgs a, float* ws, const int* flag) {
  int flg = *flag;
  int gt = blockIdx.x * 256 + threadIdx.x;
  int gs = gridDim.x * 256;
  for (int s = 0; s < 22; ++s) {
    const void* sp = a.src[s];
    int n = a.n[s];
    float* dst = ws + a.off[s];
    if (flg) {
      const float* f = (const float*)sp;
      for (int i = gt; i < n; i += gs) dst[i] = f[i];
    } else {
      const bf16* h = (const bf16*)sp;
      for (int i = gt; i < n; i += gs) dst[i] = b2f(h[i]);
    }
  }
}

// fallback: zero-fill (2 bytes/elem, safe under both out dtypes)
__global__ __launch_bounds__(256) void fill_zero_kernel(unsigned short* out, int n) {
  int i = blockIdx.x * 256 + threadIdx.x;
  if (i < n) out[i] = 0;
}

// ----------------------------------------------------------------------------
// setup: DCT matrices, E64 twiddles, wT = out_w^T (from converted fp32 outw)
// ----------------------------------------------------------------------------
__global__ __launch_bounds__(256) void setup_kernel(
    float* Dm, float* DT, float2* E64, float* wT, const float* out_w)
{
  int t = blockIdx.x * 256 + threadIdx.x;
  int NTH = gridDim.x * 256;
  const double PI = 3.14159265358979323846;
  for (int i = t; i < 64 * 64; i += NTH) {
    int n = i >> 6, x = i & 63;
    double v = cos((double)n * (((double)x + 0.5) / 64.0) * PI) * sqrt(2.0 / 64.0);
    if (n == 0) v *= 0.70710678118654752440;
    Dm[n * 64 + x] = (float)v;
    DT[x * 64 + n] = (float)v;
  }
  for (int i = t; i < 64 * 64; i += NTH) {
    int k = i >> 6, n = i & 63;
    int m = (k * n) & 63;
    double th = -2.0 * PI * (double)m / 64.0;
    E64[i] = make_float2((float)cos(th), (float)sin(th));
  }
  for (int i = t; i < 192 * 192; i += NTH) {
    int co = i / 192, c = i - co * 192;
    wT[c * 192 + co] = out_w[i];
  }
}

// ----------------------------------------------------------------------------
// depthwise 3x3 conv (NCHW in, NHWC fp32 out), pad 1. grid (6,64,32)
// ----------------------------------------------------------------------------
__global__ __launch_bounds__(256) void conv_kernel(
    const void* xin, const int* flag, const float* dww, const float* dwb, float* out)
{
  int flg = *flag;
  const float* xf = (const float*)xin;
  const bf16*  xb = (const bf16*)xin;
  int c0 = blockIdx.x * 32;
  int h  = blockIdx.y;
  int b  = blockIdx.z;
  __shared__ float in_s[3][32][66];
  __shared__ float wg[32][10];
  __shared__ float bias[32];
  int t = threadIdx.x;
  for (int idx = t; idx < 3 * 32 * 66; idx += 256) {
    int r = idx / (32 * 66);
    int rem = idx - r * (32 * 66);
    int ci = rem / 66, wi = rem - ci * 66;
    int hh = h + r - 1, wwi = wi - 1;
    float v = 0.f;
    if (hh >= 0 && hh < 64 && wwi >= 0 && wwi < 64) {
      size_t ix = (((size_t)b * 192 + c0 + ci) * 64 + hh) * 64 + wwi;
      v = flg ? xf[ix] : b2f(xb[ix]);
    }
    in_s[r][ci][wi] = v;
  }
  for (int idx = t; idx < 32 * 9; idx += 256) {
    int ci = idx / 9;
    wg[ci][idx - ci * 9] = dww[(c0 + ci) * 9 + (idx - ci * 9)];
  }
  if (t < 32) bias[t] = dwb[c0 + t];
  __syncthreads();
  int cc = t & 31, wq = t >> 5;
  for (int j = 0; j < 8; ++j) {
    int w = wq + 8 * j;
    float acc = bias[cc];
#pragma unroll
    for (int r = 0; r < 3; ++r)
#pragma unroll
      for (int kw = 0; kw < 3; ++kw)
        acc += in_s[r][cc][w + kw] * wg[cc][r * 3 + kw];
    out[(((size_t)b * 64 + h) * 64 + w) * 192 + c0 + cc] = acc;
  }
}

// ----------------------------------------------------------------------------
// linear: (131072 x 192) @ lin_w^T (384 x 192) + lin_b -> xh | z(bf16)
// 128x128 tile, 8x8/thread, K-tiles of 32, [k][m] LDS layout (stride 132,
// 16B-aligned rows -> ds_read_b128 inner loop: 4 reads per 64 FMA).
// grid (1024, 3)
// ----------------------------------------------------------------------------
__global__ __launch_bounds__(256, 4) void linear_kernel(
    const float* A, const float* Wt, const float* bias, float* xh, bf16* zb)
{
  __shared__ __align__(16) float As[32 * 132];
  __shared__ __align__(16) float Bs[32 * 132];
  int m0 = blockIdx.x * 128, n0 = blockIdx.y * 128;
  int t = threadIdx.x, tx = t & 15, ty = t >> 4;
  float acc[8][8] = {};
  for (int k0 = 0; k0 < 192; k0 += 32) {
    // stage A,B tiles transposed to [k][m] (scalar writes, ~4-way conflict,
    // amortized over 32*64 FMA of inner loop)
#pragma unroll
    for (int i = 0; i < 4; ++i) {
      int qi = t + 256 * i;
      int row = qi >> 3, qk = qi & 7;
      float4 av = *(const float4*)&A[(size_t)(m0 + row) * 192 + k0 + qk * 4];
      float4 bv = *(const float4*)&Wt[(size_t)(n0 + row) * 192 + k0 + qk * 4];
      As[(qk * 4 + 0) * 132 + row] = av.x;
      As[(qk * 4 + 1) * 132 + row] = av.y;
      As[(qk * 4 + 2) * 132 + row] = av.z;
      As[(qk * 4 + 3) * 132 + row] = av.w;
      Bs[(qk * 4 + 0) * 132 + row] = bv.x;
      Bs[(qk * 4 + 1) * 132 + row] = bv.y;
      Bs[(qk * 4 + 2) * 132 + row] = bv.z;
      Bs[(qk * 4 + 3) * 132 + row] = bv.w;
    }
    __syncthreads();
#pragma unroll 4
    for (int k = 0; k < 32; ++k) {
      float4 a0 = *(const float4*)&As[k * 132 + ty * 8];
      float4 a1 = *(const float4*)&As[k * 132 + ty * 8 + 4];
      float4 b0 = *(const float4*)&Bs[k * 132 + tx * 8];
      float4 b1 = *(const float4*)&Bs[k * 132 + tx * 8 + 4];
      float a[8] = {a0.x, a0.y, a0.z, a0.w, a1.x, a1.y, a1.z, a1.w};
      float bb[8] = {b0.x, b0.y, b0.z, b0.w, b1.x, b1.y, b1.z, b1.w};
#pragma unroll
      for (int i = 0; i < 8; ++i)
#pragma unroll
        for (int j = 0; j < 8; ++j) acc[i][j] += a[i] * bb[j];
    }
    __syncthreads();
  }
  float bb[8];
#pragma unroll
  for (int j = 0; j < 8; ++j) bb[j] = bias[n0 + tx * 8 + j];
  for (int i = 0; i < 8; ++i) {
    int m = m0 + ty * 8 + i;
    for (int j = 0; j < 8; ++j) {
      int n = n0 + tx * 8 + j;
      float v = acc[i][j] + bb[j];
      if (n < 192) xh[(size_t)m * 192 + n] = v;
      else         zb[(size_t)m * 192 + (n - 192)] = __float2bfloat16(v);
    }
  }
}

// ----------------------------------------------------------------------------
// kmap: e = relu(freq @ tok_w^T + tok_b); k = exp(-((pi i/64)^2+(pi j/64)^2)*e)
// grid (64, 3)
// ----------------------------------------------------------------------------
__global__ __launch_bounds__(256) void kmap_kernel(
    const float* A, const float* Wt, const float* bias, float* kout)
{
  __shared__ float As[32][65];
  __shared__ float Bs[32][65];
  int m0 = blockIdx.x * 64, n0 = blockIdx.y * 64;
  int t = threadIdx.x, tx = t & 15, ty = t >> 4;
  float acc[4][4] = {};
  for (int k0 = 0; k0 < 192; k0 += 32) {
    int kk = t & 31, mm = t >> 5;
#pragma unroll
    for (int i = 0; i < 8; ++i) {
      As[kk][mm + 8 * i] = A[(size_t)(m0 + mm + 8 * i) * 192 + k0 + kk];
      Bs[kk][mm + 8 * i] = Wt[(size_t)(n0 + mm + 8 * i) * 192 + k0 + kk];
    }
    __syncthreads();
    for (int k = 0; k < 32; ++k) {
      float a[4], bb[4];
#pragma unroll
      for (int i = 0; i < 4; ++i) a[i] = As[k][ty * 4 + i];
#pragma unroll
      for (int j = 0; j < 4; ++j) bb[j] = Bs[k][tx * 4 + j];
#pragma unroll
      for (int i = 0; i < 4; ++i)
#pragma unroll
        for (int j = 0; j < 4; ++j) acc[i][j] += a[i] * bb[j];
    }
    __syncthreads();
  }
  const float PI2 = 9.86960440108935862f;
  for (int i = 0; i < 4; ++i) {
    int m = m0 + ty * 4 + i;
    int ii = m >> 6, jj = m & 63;
    float d2 = (PI2 / 4096.f) * (float)(ii * ii + jj * jj);
    for (int j = 0; j < 4; ++j) {
      int n = n0 + tx * 4 + j;
      float e = acc[i][j] + bias[n];
      e = e > 0.f ? e : 0.f;
      kout[(size_t)m * 192 + n] = expf(-d2 * e);
    }
  }
}

// ----------------------------------------------------------------------------
// pooled[b,c] = mean_{hw} xh ; grid (12, 32)
// ----------------------------------------------------------------------------
__global__ __launch_bounds__(256) void pool_kernel(const float* xh, float* pooled)
{
  int b = blockIdx.y;
  int ct = blockIdx.x * 16;
  int t = threadIdx.x;
  int cl = t & 15, rg = t >> 4;
  float s = 0.f;
  for (int p = rg; p < 4096; p += 16)
    s += scrub(xh[((size_t)b * 4096 + p) * 192 + ct + cl]);
  __shared__ float red[16][17];
  red[rg][cl] = s;
  __syncthreads();
  if (t < 16) {
    float tot = 0.f;
    for (int r = 0; r < 16; ++r) tot += red[r][t];
    pooled[b * 192 + ct + t] = tot * (1.f / 4096.f);
  }
}

// ----------------------------------------------------------------------------
// MLP + batchnorms + gumbel argmax -> sel[32] ; 1 block
// ----------------------------------------------------------------------------
__global__ __launch_bounds__(256) void mlp_kernel(
    const float* pooled, const float* gn,
    const float* p1w, const float* p1b, const float* g1, const float* b1,
    const float* p2w, const float* p2b, const float* g2, const float* b2,
    const float* p3w, const float* p3b, int* sel)
{
  __shared__ float pl[32 * 192];
  __shared__ float h1s[32 * 256];
  __shared__ float h2s[32 * 32];
  int t = threadIdx.x;
  for (int i = t; i < 32 * 192; i += 256) pl[i] = pooled[i];
  __syncthreads();
  {
    float acc[32];
    float bb = p1b[t];
#pragma unroll
    for (int b = 0; b < 32; ++b) acc[b] = bb;
    for (int c = 0; c < 192; ++c) {
      float w = p1w[t * 192 + c];
#pragma unroll
      for (int b = 0; b < 32; ++b) acc[b] += w * pl[b * 192 + c];
    }
    for (int b = 0; b < 32; ++b) {
      float v = acc[b];
      v = v > 0.f ? v : 0.1f * v;
      h1s[b * 256 + t] = v;
    }
  }
  __syncthreads();
  {
    float m = 0.f;
    for (int b = 0; b < 32; ++b) m += h1s[b * 256 + t];
    m *= (1.f / 32.f);
    float v = 0.f;
    for (int b = 0; b < 32; ++b) { float d = h1s[b * 256 + t] - m; v += d * d; }
    v *= (1.f / 32.f);
    float sc = g1[t] / sqrtf(v + 1e-5f);
    float sh = b1[t] - m * sc;
    for (int b = 0; b < 32; ++b) h1s[b * 256 + t] = h1s[b * 256 + t] * sc + sh;
  }
  __syncthreads();
  {
    int j = t & 31, bg = t >> 5;
    float acc[4];
    float bb = p2b[j];
    for (int i = 0; i < 4; ++i) acc[i] = bb;
    for (int c = 0; c < 256; ++c) {
      float w = p2w[j * 256 + c];
#pragma unroll
      for (int i = 0; i < 4; ++i) acc[i] += w * h1s[(bg * 4 + i) * 256 + c];
    }
    for (int i = 0; i < 4; ++i) {
      float v = acc[i];
      v = v > 0.f ? v : 0.1f * v;
      h2s[(bg * 4 + i) * 32 + j] = v;
    }
  }
  __syncthreads();
  if (t < 32) {
    float m = 0.f;
    for (int b = 0; b < 32; ++b) m += h2s[b * 32 + t];
    m *= (1.f / 32.f);
    float v = 0.f;
    for (int b = 0; b < 32; ++b) { float d = h2s[b * 32 + t] - m; v += d * d; }
    v *= (1.f / 32.f);
    float sc = g2[t] / sqrtf(v + 1e-5f);
    float sh = b2[t] - m * sc;
    for (int b = 0; b < 32; ++b) h2s[b * 32 + t] = h2s[b * 32 + t] * sc + sh;
  }
  __syncthreads();
  if (t < 32) {
    float best = -1e30f; int bi = 0;
    for (int r = 0; r < 3; ++r) {
      float l = p3b[r];
      for (int c = 0; c < 32; ++c) l += p3w[r * 32 + c] * h2s[t * 32 + c];
      l += gn[t * 3 + r];
      if (l > best) { best = l; bi = r; }
    }
    sel[t] = bi;
  }
}

// ----------------------------------------------------------------------------
// DCT stage over first axis of (64, 12288), in-place. grid (192, 32)
// ----------------------------------------------------------------------------
__global__ __launch_bounds__(256) void axis0_kernel(
    float* buf, const float* mat, const int* sel, int branch)
{
  int b = blockIdx.y;
  if (sel[b] != branch) return;
  int q0 = blockIdx.x * 64;
  __shared__ float mT[64][65];
  __shared__ float xs[64][65];
  int t = threadIdx.x;
  for (int i = t; i < 4096; i += 256) {
    int r = i >> 6, c = i & 63;
    mT[c][r] = mat[i];
    xs[r][c] = buf[(size_t)b * SLICE + r * 12288 + q0 + c];
  }
  __syncthreads();
  int tx = t & 15, ty = t >> 4;
  float acc[4][4] = {};
  for (int l = 0; l < 64; ++l) {
    float a[4], xv[4];
#pragma unroll
    for (int i = 0; i < 4; ++i) a[i] = mT[l][ty * 4 + i];
#pragma unroll
    for (int j = 0; j < 4; ++j) xv[j] = xs[l][tx * 4 + j];
#pragma unroll
    for (int i = 0; i < 4; ++i)
#pragma unroll
      for (int j = 0; j < 4; ++j) acc[i][j] += a[i] * xv[j];
  }
  float* ob = buf + (size_t)b * SLICE;
  for (int i = 0; i < 4; ++i)
    for (int j = 0; j < 4; ++j)
      ob[(ty * 4 + i) * 12288 + q0 + tx * 4 + j] = acc[i][j];
}

// DCT stage over middle axis, in-place, optional k multiply. grid (192, 32)
__global__ __launch_bounds__(256) void axis1_kernel(
    float* buf, const float* mat, const float* kmul, const int* sel, int branch)
{
  int b = blockIdx.y;
  if (sel[b] != branch) return;
  int n = blockIdx.x / 3;
  int ct = (blockIdx.x - n * 3) * 64;
  float* base = buf + (size_t)b * SLICE + n * (64 * 192) + ct;
  __shared__ float mT[64][65];
  __shared__ float xs[64][65];
  int t = threadIdx.x;
  for (int i = t; i < 4096; i += 256) {
    int r = i >> 6, c = i & 63;
    mT[c][r] = mat[i];
    xs[r][c] = base[r * 192 + c];
  }
  __syncthreads();
  int tx = t & 15, ty = t >> 4;
  float acc[4][4] = {};
  for (int l = 0; l < 64; ++l) {
    float a[4], xv[4];
#pragma unroll
    for (int i = 0; i < 4; ++i) a[i] = mT[l][ty * 4 + i];
#pragma unroll
    for (int j = 0; j < 4; ++j) xv[j] = xs[l][tx * 4 + j];
#pragma unroll
    for (int i = 0; i < 4; ++i)
#pragma unroll
      for (int j = 0; j < 4; ++j) acc[i][j] += a[i] * xv[j];
  }
  if (kmul) {
    for (int i = 0; i < 4; ++i)
      for (int j = 0; j < 4; ++j)
        acc[i][j] *= kmul[(size_t)(n * 64 + ty * 4 + i) * 192 + ct + tx * 4 + j];
  }
  for (int i = 0; i < 4; ++i)
    for (int j = 0; j < 4; ++j)
      base[(ty * 4 + i) * 192 + tx * 4 + j] = acc[i][j];
}

// ----------------------------------------------------------------------------
// FFT forward over h (real -> complex), real in-place into xh, imag -> Si
// ----------------------------------------------------------------------------
__global__ __launch_bounds__(256) void ffth_kernel(
    float* xh, float* Si, const float2* E64, const int* sel)
{
  int b = blockIdx.y;
  if (sel[b] != 1) return;
  int q0 = blockIdx.x * 64;
  __shared__ float er[64][65], ei[64][65], xs[64][65];
  int t = threadIdx.x;
  for (int i = t; i < 4096; i += 256) {
    int r = i >> 6, c = i & 63;
    float2 e = E64[i];
    er[r][c] = e.x; ei[r][c] = e.y;
    xs[r][c] = xh[(size_t)b * SLICE + r * 12288 + q0 + c];
  }
  __syncthreads();
  int tx = t & 15, ty = t >> 4;
  float ar[4][4] = {}, ai[4][4] = {};
  for (int l = 0; l < 64; ++l) {
    float e1[4], e2[4], xv[4];
#pragma unroll
    for (int i = 0; i < 4; ++i) { e1[i] = er[l][ty * 4 + i]; e2[i] = ei[l][ty * 4 + i]; }
#pragma unroll
    for (int j = 0; j < 4; ++j) xv[j] = xs[l][tx * 4 + j];
#pragma unroll
    for (int i = 0; i < 4; ++i)
#pragma unroll
      for (int j = 0; j < 4; ++j) { ar[i][j] += e1[i] * xv[j]; ai[i][j] += e2[i] * xv[j]; }
  }
  size_t ob = (size_t)b * SLICE;
  for (int i = 0; i < 4; ++i)
    for (int j = 0; j < 4; ++j) {
      size_t o = ob + (size_t)(ty * 4 + i) * 12288 + q0 + tx * 4 + j;
      xh[o] = ar[i][j];
      Si[o] = ai[i][j];
    }
}

// FFT over w (complex, in-place). grid (384, 32)
__global__ __launch_bounds__(256) void fftw_kernel(
    float* Sr, float* Si, const float2* E64, const int* sel, float s)
{
  int b = blockIdx.y;
  if (sel[b] != 1) return;
  int kh = blockIdx.x / 6;
  int ct = (blockIdx.x - kh * 6) * 32;
  float* br = Sr + (size_t)b * SLICE + kh * 12288 + ct;
  float* bi = Si + (size_t)b * SLICE + kh * 12288 + ct;
  __shared__ float er[64][65], ei[64][65];
  __shared__ float xr[64][33], xi[64][33];
  int t = threadIdx.x;
  for (int i = t; i < 4096; i += 256) {
    float2 e = E64[i];
    er[i >> 6][i & 63] = e.x;
    ei[i >> 6][i & 63] = s * e.y;
  }
  for (int i = t; i < 2048; i += 256) {
    int l = i >> 5, q = i & 31;
    xr[l][q] = br[l * 192 + q];
    xi[l][q] = bi[l * 192 + q];
  }
  __syncthreads();
  int tx = t & 7, ty = t >> 3;
  float ar[2][4] = {}, ac[2][4] = {};
  for (int l = 0; l < 64; ++l) {
    float e1a = er[l][ty],      e2a = ei[l][ty];
    float e1b = er[l][ty + 32], e2b = ei[l][ty + 32];
#pragma unroll
    for (int j = 0; j < 4; ++j) {
      float vr = xr[l][tx * 4 + j], vi = xi[l][tx * 4 + j];
      ar[0][j] += e1a * vr - e2a * vi;
      ac[0][j] += e1a * vi + e2a * vr;
      ar[1][j] += e1b * vr - e2b * vi;
      ac[1][j] += e1b * vi + e2b * vr;
    }
  }
  for (int r = 0; r < 2; ++r) {
    int kw = ty + r * 32;
    for (int j = 0; j < 4; ++j) {
      br[kw * 192 + tx * 4 + j] = ar[r][j];
      bi[kw * 192 + tx * 4 + j] = ac[r][j];
    }
  }
}

// ----------------------------------------------------------------------------
// Fused c-stage via Cooley-Tukey 3x64: S <- IDFT_c( DFT_c(S) * k*SCALE ),
// in-place per 32-row tile. Complex data LDS-interleaved: float2 T[c][row],
// row-stride 34 complex (272 B: 16B-aligned, b128-able).
// Forward: n = 3*n2+n1 -> three strided DFT-64 (one shared rotator since all
// three use identical omega64 twiddles) -> W192^{n1 m} twiddle -> radix-3
// combine (in registers). k-multiply. Inverse: radix-3 split (registers) ->
// conj twiddle -> LDS transpose -> three IDFT-64. ~2.9x fewer VALU ops than
// direct 192-pt DFT; LDS reads are 6 broadcast b128/step.
// Thread map: tx=t&31 -> m in {tx,tx+32}; ty=t>>5 -> rows 4*ty..4*ty+3.
// grid (128, 32). LDS 52224 B (3 blocks/CU).
// ----------------------------------------------------------------------------
__global__ __launch_bounds__(256, 3) void fftc_fused_kernel(
    float* Sr, float* Si, const float* kmap, const int* sel)
{
  int b = blockIdx.y;
  if (sel[b] != 1) return;
  int m0 = blockIdx.x * 32;
  float* gr = Sr + (size_t)b * SLICE + (size_t)m0 * 192;
  float* gi = Si + (size_t)b * SLICE + (size_t)m0 * 192;
  __shared__ __align__(16) float2 T[192][34];
  int t = threadIdx.x;
  for (int i = t; i < 6144; i += 256) {
    int row = i / 192, c = i - row * 192;
    T[c][row] = make_float2(gr[i], gi[i]);
  }
  int tx = t & 31, ty = t >> 5;
  int rbase = ty * 4;
  // per-thread constants (2 double sincos, everything else derived)
  double A = 2.0 * 3.14159265358979323846 * (double)tx;
  double sa, ca, sb, cb;
  sincos(A / 64.0, &sa, &ca);    // angle of omega64^tx
  sincos(A / 192.0, &sb, &cb);   // angle of W192^tx
  float c64 = (float)ca, s64 = (float)sa;
  float cw = (float)cb, sw = (float)sb;
  const float S3 = 0.86602540378443864676f;
  // forward rotator steps: omega64^{tx+32u} (u=1 is -u=0 since omega64^32=-1)
  float fsr[2], fsi[2];
  fsr[0] = c64;  fsi[0] = -s64;
  fsr[1] = -c64; fsi[1] = s64;
  // forward twiddles w1[u] = W192^{tx+32u} (W192^32 = (0.5, -S3)), w2 = w1^2
  float w1r[2], w1i[2], w2r[2], w2i[2];
  w1r[0] = cw;                   w1i[0] = -sw;
  w1r[1] = 0.5f * cw - S3 * sw;  w1i[1] = -S3 * cw - 0.5f * sw;
#pragma unroll
  for (int u = 0; u < 2; ++u) {
    w2r[u] = w1r[u] * w1r[u] - w1i[u] * w1i[u];
    w2i[u] = 2.f * w1r[u] * w1i[u];
  }
  __syncthreads();
  // ---- pass 1: Y_{n1}[m] = sum_{n2} x[3*n2+n1] * omega64^{n2 m} ----
  float ar[2][3][4], ai[2][3][4];
#pragma unroll
  for (int u = 0; u < 2; ++u)
#pragma unroll
    for (int n1 = 0; n1 < 3; ++n1)
#pragma unroll
      for (int r = 0; r < 4; ++r) { ar[u][n1][r] = 0.f; ai[u][n1][r] = 0.f; }
  {
    float pr[2], pq[2];
    pr[0] = 1.f; pr[1] = 1.f; pq[0] = 0.f; pq[1] = 0.f;
    for (int n2 = 0; n2 < 64; ++n2) {
      const float4* p0 = (const float4*)&T[3 * n2][rbase];
      const float4* p1 = (const float4*)&T[3 * n2 + 1][rbase];
      const float4* p2 = (const float4*)&T[3 * n2 + 2][rbase];
      float4 q00 = p0[0], q01 = p0[1];
      float4 q10 = p1[0], q11 = p1[1];
      float4 q20 = p2[0], q21 = p2[1];
      float xr[3][4], xi[3][4];
      xr[0][0] = q00.x; xi[0][0] = q00.y; xr[0][1] = q00.z; xi[0][1] = q00.w;
      xr[0][2] = q01.x; xi[0][2] = q01.y; xr[0][3] = q01.z; xi[0][3] = q01.w;
      xr[1][0] = q10.x; xi[1][0] = q10.y; xr[1][1] = q10.z; xi[1][1] = q10.w;
      xr[1][2] = q11.x; xi[1][2] = q11.y; xr[1][3] = q11.z; xi[1][3] = q11.w;
      xr[2][0] = q20.x; xi[2][0] = q20.y; xr[2][1] = q20.z; xi[2][1] = q20.w;
      xr[2][2] = q21.x; xi[2][2] = q21.y; xr[2][3] = q21.z; xi[2][3] = q21.w;
#pragma unroll
      for (int u = 0; u < 2; ++u) {
        float er = pr[u], ei = pq[u];
#pragma unroll
        for (int n1 = 0; n1 < 3; ++n1)
#pragma unroll
          for (int r = 0; r < 4; ++r) {
            ar[u][n1][r] += xr[n1][r] * er - xi[n1][r] * ei;
            ai[u][n1][r] += xr[n1][r] * ei + xi[n1][r] * er;
          }
        float nr = er * fsr[u] - ei * fsi[u];
        pq[u] = er * fsi[u] + ei * fsr[u];
        pr[u] = nr;
      }
    }
  }
  // ---- twiddle + radix-3 combine, k-multiply, radix-3 split + conj twiddle
  // (all in registers; result V_{n1}[m] overwrites ar/ai) ----
  const float SCALE = 1.0f / 786432.0f;
#pragma unroll
  for (int u = 0; u < 2; ++u) {
    int m = tx + 32 * u;
#pragma unroll
    for (int r = 0; r < 4; ++r) {
      int row = rbase + r;
      float Y0r = ar[u][0][r], Y0i = ai[u][0][r];
      float Y1r = ar[u][1][r], Y1i = ai[u][1][r];
      float Y2r = ar[u][2][r], Y2i = ai[u][2][r];
      float T1r = Y1r * w1r[u] - Y1i * w1i[u];
      float T1i = Y1r * w1i[u] + Y1i * w1r[u];
      float T2r = Y2r * w2r[u] - Y2i * w2i[u];
      float T2i = Y2r * w2i[u] + Y2i * w2r[u];
      // forward radix-3: X_j = sum_{n1} omega3^{n1 j} T_{n1}
      float aRr = T1r + T2r, aRi = T1i + T2i;
      float bRr = T1r - T2r, bRi = T1i - T2i;
      float X0r = Y0r + aRr, X0i = Y0i + aRi;
      float cfr = Y0r - 0.5f * aRr, cfi = Y0i - 0.5f * aRi;
      float X1r = cfr + S3 * bRi, X1i = cfi - S3 * bRr;
      float X2r = cfr - S3 * bRi, X2i = cfi + S3 * bRr;
      const float* kp = kmap + (size_t)(m0 + row) * 192 + m;
      float k0 = kp[0] * SCALE, k1 = kp[64] * SCALE, k2 = kp[128] * SCALE;
      X0r *= k0; X0i *= k0; X1r *= k1; X1i *= k1; X2r *= k2; X2i *= k2;
      // inverse radix-3: U_{n1} = sum_j omega3^{-n1 j} X'_j
      float a2r = X1r + X2r, a2i = X1i + X2i;
      float b2r = X1r - X2r, b2i = X1i - X2i;
      float U0r = X0r + a2r, U0i = X0i + a2i;
      float c2r = X0r - 0.5f * a2r, c2i = X0i - 0.5f * a2i;
      float U1r = c2r - S3 * b2i, U1i = c2i + S3 * b2r;
      float U2r = c2r + S3 * b2i, U2i = c2i - S3 * b2r;
      // V_{n1} = U_{n1} * conj(w_{n1})
      ar[u][0][r] = U0r;
      ai[u][0][r] = U0i;
      ar[u][1][r] = U1r * w1r[u] + U1i * w1i[u];
      ai[u][1][r] = U1i * w1r[u] - U1r * w1i[u];
      ar[u][2][r] = U2r * w2r[u] + U2i * w2i[u];
      ai[u][2][r] = U2i * w2r[u] - U2r * w2i[u];
    }
  }
  __syncthreads();   // all pass-1 reads of T done before overwriting with V
#pragma unroll
  for (int u = 0; u < 2; ++u)
#pragma unroll
    for (int n1 = 0; n1 < 3; ++n1)
#pragma unroll
      for (int r = 0; r < 4; ++r)
        T[n1 * 64 + tx + 32 * u][rbase + r] =
            make_float2(ar[u][n1][r], ai[u][n1][r]);
  __syncthreads();
  // ---- pass 2: x[3*n2+n1] = sum_m V_{n1}[m] * omega64^{-n2 m}, n2=tx+32u ----
  float qr_[2][3][4], qi_[2][3][4];
#pragma unroll
  for (int u = 0; u < 2; ++u)
#pragma unroll
    for (int n1 = 0; n1 < 3; ++n1)
#pragma unroll
      for (int r = 0; r < 4; ++r) { qr_[u][n1][r] = 0.f; qi_[u][n1][r] = 0.f; }
  {
    // inverse rotator steps: conj(omega64^{tx+32u})
    float isr[2], isi[2];
    isr[0] = c64;  isi[0] = s64;
    isr[1] = -c64; isi[1] = -s64;
    float pr[2], pq[2];
    pr[0] = 1.f; pr[1] = 1.f; pq[0] = 0.f; pq[1] = 0.f;
    for (int ms = 0; ms < 64; ++ms) {
      const float4* p0 = (const float4*)&T[ms][rbase];
      const float4* p1 = (const float4*)&T[64 + ms][rbase];
      const float4* p2 = (const float4*)&T[128 + ms][rbase];
      float4 q00 = p0[0], q01 = p0[1];
      float4 q10 = p1[0], q11 = p1[1];
      float4 q20 = p2[0], q21 = p2[1];
      float xr[3][4], xi[3][4];
      xr[0][0] = q00.x; xi[0][0] = q00.y; xr[0][1] = q00.z; xi[0][1] = q00.w;
      xr[0][2] = q01.x; xi[0][2] = q01.y; xr[0][3] = q01.z; xi[0][3] = q01.w;
      xr[1][0] = q10.x; xi[1][0] = q10.y; xr[1][1] = q10.z; xi[1][1] = q10.w;
      xr[1][2] = q11.x; xi[1][2] = q11.y; xr[1][3] = q11.z; xi[1][3] = q11.w;
      xr[2][0] = q20.x; xi[2][0] = q20.y; xr[2][1] = q20.z; xi[2][1] = q20.w;
      xr[2][2] = q21.x; xi[2][2] = q21.y; xr[2][3] = q21.z; xi[2][3] = q21.w;
#pragma unroll
      for (int u = 0; u < 2; ++u) {
        float er = pr[u], ei = pq[u];
#pragma unroll
        for (int n1 = 0; n1 < 3; ++n1)
#pragma unroll
          for (int r = 0; r < 4; ++r) {
            qr_[u][n1][r] += xr[n1][r] * er - xi[n1][r] * ei;
            qi_[u][n1][r] += xr[n1][r] * ei + xi[n1][r] * er;
          }
        float nr = er * isr[u] - ei * isi[u];
        pq[u] = er * isi[u] + ei * isr[u];
        pr[u] = nr;
      }
    }
  }
#pragma unroll
  for (int r = 0; r < 4; ++r) {
    int row = rbase + r;
#pragma unroll
    for (int u = 0; u < 2; ++u) {
      int c0 = 3 * (tx + 32 * u);
#pragma unroll
      for (int n1 = 0; n1 < 3; ++n1) {
        gr[(size_t)row * 192 + c0 + n1] = qr_[u][n1][r];
        gi[(size_t)row * 192 + c0 + n1] = qi_[u][n1][r];
      }
    }
  }
}

// inverse h-stage, real part only, in-place into xh. grid (384, 32)
__global__ __launch_bounds__(256) void ffthi_kernel(
    float* Sr, const float* Si, const float2* E64, const int* sel)
{
  int b = blockIdx.y;
  if (sel[b] != 1) return;
  int q0 = blockIdx.x * 32;
  __shared__ float er[64][65], ei[64][65];
  __shared__ float xr[64][33], xi[64][33];
  int t = threadIdx.x;
  for (int i = t; i < 4096; i += 256) {
    float2 e = E64[i];
    er[i >> 6][i & 63] = e.x;
    ei[i >> 6][i & 63] = e.y;
  }
  for (int i = t; i < 2048; i += 256) {
    int l = i >> 5, q = i & 31;
    size_t o = (size_t)b * SLICE + (size_t)l * 12288 + q0 + q;
    xr[l][q] = Sr[o];
    xi[l][q] = Si[o];
  }
  __syncthreads();
  int tx = t & 7, ty = t >> 3;
  float acc[2][4] = {};
  for (int l = 0; l < 64; ++l) {
    float e1a = er[l][ty],      e2a = ei[l][ty];
    float e1b = er[l][ty + 32], e2b = ei[l][ty + 32];
#pragma unroll
    for (int j = 0; j < 4; ++j) {
      float vr = xr[l][tx * 4 + j], vi = xi[l][tx * 4 + j];
      acc[0][j] += e1a * vr + e2a * vi;   // Re(e^{+i th} A), ei = -sin
      acc[1][j] += e1b * vr + e2b * vi;
    }
  }
  for (int r = 0; r < 2; ++r) {
    int h = ty + r * 32;
    for (int j = 0; j < 4; ++j)
      Sr[(size_t)b * SLICE + (size_t)h * 12288 + q0 + tx * 4 + j] = acc[r][j];
  }
}

// ----------------------------------------------------------------------------
// Haar branch, in-place on xh (haar along C: 64-chunks then full 192)
// grid (128, 32)
// ----------------------------------------------------------------------------
__global__ __launch_bounds__(256) void haar_kernel(
    float* xh, const float* kmap, const int* sel)
{
  int b = blockIdx.y;
  if (sel[b] != 2) return;
  int h = blockIdx.x >> 1;
  int w0 = (blockIdx.x & 1) * 32;
  size_t base = (size_t)b * SLICE + ((size_t)h * 64 + w0) * 192;
  __shared__ float A[32 * 192];
  __shared__ float Bf[32 * 192];
  int t = threadIdx.x;
  for (int i = t; i < 6144; i += 256) A[i] = xh[base + i];
  __syncthreads();
  for (int u = t; u < 32 * 96; u += 256) {
    int p = u / 96, r = u - p * 96;
    int ch = r >> 5, i = r & 31;
    float v0 = A[p * 192 + ch * 64 + 2 * i];
    float v1 = A[p * 192 + ch * 64 + 2 * i + 1];
    Bf[p * 192 + ch * 64 + i]      = (v0 + v1) * 0.5f;
    Bf[p * 192 + ch * 64 + 32 + i] = (v0 - v1) * 0.5f;
  }
  __syncthreads();
  for (int u = t; u < 32 * 96; u += 256) {
    int p = u / 96, i = u - p * 96;
    float v0 = Bf[p * 192 + 2 * i];
    float v1 = Bf[p * 192 + 2 * i + 1];
    A[p * 192 + i]      = (v0 + v1) * 0.5f;
    A[p * 192 + 96 + i] = (v0 - v1) * 0.5f;
  }
  __syncthreads();
  for (int i = t; i < 6144; i += 256)
    A[i] *= kmap[((size_t)h * 64 + w0) * 192 + i];
  __syncthreads();
  for (int u = t; u < 32 * 96; u += 256) {
    int p = u / 96, r = u - p * 96;
    int ch = r >> 5, i = r & 31;
    float a = A[p * 192 + ch * 64 + i];
    float d = A[p * 192 + ch * 64 + 32 + i];
    Bf[p * 192 + ch * 64 + 2 * i]     = a + d;
    Bf[p * 192 + ch * 64 + 2 * i + 1] = a - d;
  }
  __syncthreads();
  for (int u = t; u < 32 * 96; u += 256) {
    int p = u / 96, i = u - p * 96;
    float a = Bf[p * 192 + i];
    float d = Bf[p * 192 + 96 + i];
    A[p * 192 + 2 * i]     = a + d;
    A[p * 192 + 2 * i + 1] = a - d;
  }
  __syncthreads();
  for (int i = t; i < 6144; i += 256) xh[base + i] = A[i];
}

// ----------------------------------------------------------------------------
// final: LN(c) * silu(z) @ out_w^T + out_b, dual-dtype store. grid 2048
// ----------------------------------------------------------------------------
__global__ __launch_bounds__(256) void final_kernel(
    const float* comb, const bf16* zb, const float* lng, const float* lnb,
    const float* wT, const float* outb, void* outp, const int* flag)
{
  int flg = *flag;
  int bi = blockIdx.x;
  int b = bi >> 6, h = bi & 63;
  size_t base = ((size_t)b * 4096 + (size_t)h * 64) * 192;
  __shared__ float As[64 * 194];
  __shared__ float mu[64], rs[64];
  int t = threadIdx.x;
  for (int e = t; e < 12288; e += 256) {
    int p = e / 192, c = e - p * 192;
    As[p * 194 + c] = scrub(comb[base + e]);
  }
  __syncthreads();
  if (t < 64) {
    float s = 0.f;
    for (int c = 0; c < 192; ++c) s += As[t * 194 + c];
    float m = s * (1.f / 192.f);
    float v = 0.f;
    for (int c = 0; c < 192; ++c) { float d = As[t * 194 + c] - m; v += d * d; }
    v *= (1.f / 192.f);
    mu[t] = m;
    rs[t] = 1.f / sqrtf(v + 1e-5f);
  }
  __syncthreads();
  for (int e = t; e < 12288; e += 256) {
    int p = e / 192, c = e - p * 192;
    float v = (As[p * 194 + c] - mu[p]) * rs[p] * lng[c] + lnb[c];
    float zv = scrub(b2f(zb[base + e]));
    v *= zv / (1.f + expf(-zv));
    As[p * 194 + c] = v;
  }
  __syncthreads();
  int tx = t & 15, ty = t >> 4;
  float acc[4][12];
  for (int i = 0; i < 4; ++i)
    for (int j = 0; j < 12; ++j) acc[i][j] = 0.f;
  for (int c = 0; c < 192; ++c) {
    float av[4];
#pragma unroll
    for (int i = 0; i < 4; ++i) av[i] = As[(ty * 4 + i) * 194 + c];
    float wv[12];
#pragma unroll
    for (int j = 0; j < 12; ++j) wv[j] = wT[(size_t)c * 192 + tx * 12 + j];
#pragma unroll
    for (int i = 0; i < 4; ++i)
#pragma unroll
      for (int j = 0; j < 12; ++j) acc[i][j] += av[i] * wv[j];
  }
  __syncthreads();
  for (int i = 0; i < 4; ++i)
    for (int j = 0; j < 12; ++j) {
      int co = tx * 12 + j, p = ty * 4 + i;
      As[co * 64 + p] = acc[i][j] + outb[co];
    }
  __syncthreads();
  for (int e = t; e < 12288; e += 256) {
    int co = e >> 6, w = e & 63;
    size_t oi = (((size_t)b * 192 + co) * 64 + h) * 64 + w;
    if (flg) ((float*)outp)[oi] = As[e];
    else     ((bf16*)outp)[oi] = __float2bfloat16(As[e]);
  }
}

// ----------------------------------------------------------------------------
extern "C" void kernel_launch(void* const* d_in, const int* in_sizes, int n_in,
                              void* d_out, int out_size, void* d_ws, size_t ws_size,
                              hipStream_t stream) {
  (void)in_sizes; (void)n_in;
  if (ws_size < WS_NEEDED_BYTES) {
    fill_zero_kernel<<<(out_size + 255) / 256, 256, 0, stream>>>(
        (unsigned short*)d_out, out_size);
    return;
  }
  float* ws    = (float*)d_ws;
  float* xh    = ws + O_XH;
  float* Si    = ws + O_SI;
  bf16*  zb    = (bf16*)(ws + O_ZB);
  float* kmap  = ws + O_KMAP;
  float2* E64  = (float2*)(ws + O_E64);
  float* Dm    = ws + O_DM;
  float* DT    = ws + O_DT;
  float* wT    = ws + O_WT;
  float* pooled= ws + O_POOL;
  int*   sel   = (int*)(ws + O_SEL);
  int*   flag  = (int*)(ws + O_FLAG);

  sniff_kernel<<<1, 64, 0, stream>>>((const unsigned short*)d_in[0], flag);

  CvtArgs ca;
  const int srcidx[22] = {2,3,4,5,6,7,8,9,10,11,12,13,14,15,16,17,18,19,20,21,22,1};
  const int ns[22] = {96,1728,192,73728,384,49152,256,256,256,8192,32,32,32,96,3,
                      36864,192,192,192,36864,192,786432};
  const long long offs[22] = {
    (long long)W_GN,(long long)W_DWW,(long long)W_DWB,(long long)W_LINW,
    (long long)W_LINB,(long long)W_P1W,(long long)W_P1B,(long long)W_G1,
    (long long)W_B1,(long long)W_P2W,(long long)W_P2B,(long long)W_G2,
    (long long)W_B2,(long long)W_P3W,(long long)W_P3B,(long long)W_TOKW,
    (long long)W_TOKB,(long long)W_LNG,(long long)W_LNB,(long long)W_OUTW,
    (long long)W_OUTB,(long long)O_FREQ};
  for (int i = 0; i < 22; ++i) { ca.src[i] = d_in[srcidx[i]]; ca.n[i] = ns[i]; ca.off[i] = offs[i]; }
  cvt_kernel<<<64, 256, 0, stream>>>(ca, ws, flag);

  setup_kernel<<<64, 256, 0, stream>>>(Dm, DT, E64, wT, ws + W_OUTW);
  conv_kernel<<<dim3(6, 64, 32), 256, 0, stream>>>(d_in[0], flag, ws + W_DWW, ws + W_DWB, Si);
  linear_kernel<<<dim3(1024, 3), 256, 0, stream>>>(Si, ws + W_LINW, ws + W_LINB, xh, zb);
  pool_kernel<<<dim3(12, 32), 256, 0, stream>>>(xh, pooled);
  mlp_kernel<<<1, 256, 0, stream>>>(pooled, ws + W_GN,
      ws + W_P1W, ws + W_P1B, ws + W_G1, ws + W_B1,
      ws + W_P2W, ws + W_P2B, ws + W_G2, ws + W_B2,
      ws + W_P3W, ws + W_P3B, sel);
  kmap_kernel<<<dim3(64, 3), 256, 0, stream>>>(ws + O_FREQ, ws + W_TOKW, ws + W_TOKB, kmap);
  // DCT branch (sel==0), in-place on xh
  axis0_kernel<<<dim3(192, 32), 256, 0, stream>>>(xh, Dm, sel, 0);
  axis1_kernel<<<dim3(192, 32), 256, 0, stream>>>(xh, Dm, kmap, sel, 0);
  axis1_kernel<<<dim3(192, 32), 256, 0, stream>>>(xh, DT, nullptr, sel, 0);
  axis0_kernel<<<dim3(192, 32), 256, 0, stream>>>(xh, DT, sel, 0);
  // FFT branch (sel==1); b-axis FFT/IFFT cancels analytically; in-place (xh,Si)
  ffth_kernel<<<dim3(192, 32), 256, 0, stream>>>(xh, Si, E64, sel);
  fftw_kernel<<<dim3(384, 32), 256, 0, stream>>>(xh, Si, E64, sel, 1.f);
  fftc_fused_kernel<<<dim3(128, 32), 256, 0, stream>>>(xh, Si, kmap, sel);
  fftw_kernel<<<dim3(384, 32), 256, 0, stream>>>(xh, Si, E64, sel, -1.f);
  ffthi_kernel<<<dim3(384, 32), 256, 0, stream>>>(xh, Si, E64, sel);
  // Haar branch (sel==2), in-place on xh
  haar_kernel<<<dim3(128, 32), 256, 0, stream>>>(xh, kmap, sel);
  // epilogue
  final_kernel<<<2048, 256, 0, stream>>>(xh, zb, ws + W_LNG, ws + W_LNB,
                                         wT, ws + W_OUTB, d_out, flag);
}

// Round 3
// 1408.321 us; speedup vs baseline: 1.4176x; 1.1490x over previous
//
#include <hip/hip_runtime.h>
#include <hip/hip_bf16.h>
#include <math.h>

typedef __hip_bfloat16 bf16;
#define DEVI __device__ __forceinline__
static DEVI float b2f(bf16 v) { return __bfloat162float(v); }
static DEVI float scrub(float v) { return (v - v == 0.f) ? v : 0.f; }

typedef __attribute__((ext_vector_type(8))) short short8v;   // 8 bf16 (4 VGPR)
typedef __attribute__((ext_vector_type(4))) float float4v;   // MFMA acc

constexpr int SLICE = 64 * 64 * 192;           // per-b elements = 786432

// ws layout (float offsets). Total 64,755,812 floats = 259,023,248 B (~247 MiB)
constexpr size_t O_XH   = 0;          // 25165824
constexpr size_t O_SI   = 25165824;   // 25165824 (imag buffer for FFT branch)
constexpr size_t O_ZB   = 50331648;   // bf16 z (25165824 elems = 12582912 slots)
constexpr size_t O_KMAP = 62914560;   // 786432
constexpr size_t O_FREQ = 63700992;   // 786432 (converted fp32 freq_embed)
constexpr size_t O_E64  = 64487424;   // 8192 (4096 float2)
constexpr size_t O_DM   = 64495616;   // 4096
constexpr size_t O_DT   = 64499712;   // 4096
constexpr size_t O_WT   = 64503808;   // 36864
constexpr size_t O_POOL = 64540672;   // 6144
constexpr size_t O_SEL  = 64546816;   // 32
constexpr size_t O_FLAG = 64546848;   // 32 (flag int + pad)
constexpr size_t O_W    = 64546880;   // 208932 packed fp32 weights
constexpr size_t WS_NEEDED_BYTES = (size_t)64755812 * 4;

// transient aliases inside O_SI (dead before ffth writes Si):
constexpr size_t O_YB   = O_SI;             // bf16 y, 25165824 elems (12582912 slots)
constexpr size_t O_PART = O_SI + 12600000;  // fp32 partial pooled [32][64][192] = 393216
constexpr size_t O_WB   = O_SI + 13100000;  // bf16 lin_w, 73728 elems (36864 slots)

// packed-weight offsets (relative to ws base)
constexpr size_t W_GN   = O_W + 0;      // 96
constexpr size_t W_DWW  = O_W + 96;     // 1728
constexpr size_t W_DWB  = O_W + 1824;   // 192
constexpr size_t W_LINW = O_W + 2016;   // 73728
constexpr size_t W_LINB = O_W + 75744;  // 384
constexpr size_t W_P1W  = O_W + 76128;  // 49152
constexpr size_t W_P1B  = O_W + 125280; // 256
constexpr size_t W_G1   = O_W + 125536; // 256
constexpr size_t W_B1   = O_W + 125792; // 256
constexpr size_t W_P2W  = O_W + 126048; // 8192
constexpr size_t W_P2B  = O_W + 134240; // 32
constexpr size_t W_G2   = O_W + 134272; // 32
constexpr size_t W_B2   = O_W + 134304; // 32
constexpr size_t W_P3W  = O_W + 134336; // 96
constexpr size_t W_P3B  = O_W + 134432; // 4 (3 used)
constexpr size_t W_TOKW = O_W + 134436; // 36864
constexpr size_t W_TOKB = O_W + 171300; // 192
constexpr size_t W_LNG  = O_W + 171492; // 192
constexpr size_t W_LNB  = O_W + 171684; // 192
constexpr size_t W_OUTW = O_W + 171876; // 36864
constexpr size_t W_OUTB = O_W + 208740; // 192

struct CvtArgs {
  const void* src[22];
  int n[22];
  long long off[22];   // float offset into ws
};

// ----------------------------------------------------------------------------
// dtype sniff: bf16 array -> ~64/64 sane uint16 exponents; fp32 -> ~40/64
// flag: 0 = bf16 inputs, 1 = fp32 inputs
// ----------------------------------------------------------------------------
__global__ void sniff_kernel(const unsigned short* xu, int* flag) {
  __shared__ int cnt;
  if (threadIdx.x == 0) cnt = 0;
  __syncthreads();
  unsigned short u = xu[threadIdx.x];
  int e = (u >> 7) & 0xFF;
  int sane = ((e >= 97 && e <= 160) || (u & 0x7FFF) == 0) ? 1 : 0;
  atomicAdd(&cnt, sane);
  __syncthreads();
  if (threadIdx.x == 0) *flag = (cnt >= 56) ? 0 : 1;
}

// convert all small inputs (+freq) to fp32 in ws, per flag
__global__ __launch_bounds__(256) void cvt_kernel(CvtArgs a, float* ws, const int* flag) {
  int flg = *flag;
  int gt = blockIdx.x * 256 + threadIdx.x;
  int gs = gridDim.x * 256;
  for (int s = 0; s < 22; ++s) {
    const void* sp = a.src[s];
    int n = a.n[s];
    float* dst = ws + a.off[s];
    if (flg) {
      const float* f = (const float*)sp;
      for (int i = gt; i < n; i += gs) dst[i] = f[i];
    } else {
      const bf16* h = (const bf16*)sp;
      for (int i = gt; i < n; i += gs) dst[i] = b2f(h[i]);
    }
  }
}

// fallback: zero-fill (2 bytes/elem, safe under both out dtypes)
__global__ __launch_bounds__(256) void fill_zero_kernel(unsigned short* out, int n) {
  int i = blockIdx.x * 256 + threadIdx.x;
  if (i < n) out[i] = 0;
}

// ----------------------------------------------------------------------------
// setup: DCT matrices, E64 twiddles, wT = out_w^T, bf16 lin_w copy
// ----------------------------------------------------------------------------
__global__ __launch_bounds__(256) void setup_kernel(
    float* Dm, float* DT, float2* E64, float* wT, const float* out_w,
    bf16* Wb, const float* lin_w)
{
  int t = blockIdx.x * 256 + threadIdx.x;
  int NTH = gridDim.x * 256;
  const double PI = 3.14159265358979323846;
  for (int i = t; i < 64 * 64; i += NTH) {
    int n = i >> 6, x = i & 63;
    double v = cos((double)n * (((double)x + 0.5) / 64.0) * PI) * sqrt(2.0 / 64.0);
    if (n == 0) v *= 0.70710678118654752440;
    Dm[n * 64 + x] = (float)v;
    DT[x * 64 + n] = (float)v;
  }
  for (int i = t; i < 64 * 64; i += NTH) {
    int k = i >> 6, n = i & 63;
    int m = (k * n) & 63;
    double th = -2.0 * PI * (double)m / 64.0;
    E64[i] = make_float2((float)cos(th), (float)sin(th));
  }
  for (int i = t; i < 192 * 192; i += NTH) {
    int co = i / 192, c = i - co * 192;
    wT[c * 192 + co] = out_w[i];
  }
  for (int i = t; i < 384 * 192; i += NTH)
    Wb[i] = __float2bfloat16(lin_w[i]);
}

// ----------------------------------------------------------------------------
// depthwise 3x3 conv (NCHW in, NHWC bf16 out), pad 1. grid (6,64,32)
// also emits fp32 partial pooled sums over w: partial[b][h][c]
// ----------------------------------------------------------------------------
__global__ __launch_bounds__(256) void conv_kernel(
    const void* xin, const int* flag, const float* dww, const float* dwb,
    bf16* out, float* partial)
{
  int flg = *flag;
  const float* xf = (const float*)xin;
  const bf16*  xb = (const bf16*)xin;
  int c0 = blockIdx.x * 32;
  int h  = blockIdx.y;
  int b  = blockIdx.z;
  __shared__ float in_s[3][32][66];
  __shared__ float wg[32][10];
  __shared__ float bias[32];
  __shared__ float psum[8][33];
  int t = threadIdx.x;
  for (int idx = t; idx < 3 * 32 * 66; idx += 256) {
    int r = idx / (32 * 66);
    int rem = idx - r * (32 * 66);
    int ci = rem / 66, wi = rem - ci * 66;
    int hh = h + r - 1, wwi = wi - 1;
    float v = 0.f;
    if (hh >= 0 && hh < 64 && wwi >= 0 && wwi < 64) {
      size_t ix = (((size_t)b * 192 + c0 + ci) * 64 + hh) * 64 + wwi;
      v = flg ? xf[ix] : b2f(xb[ix]);
    }
    in_s[r][ci][wi] = v;
  }
  for (int idx = t; idx < 32 * 9; idx += 256) {
    int ci = idx / 9;
    wg[ci][idx - ci * 9] = dww[(c0 + ci) * 9 + (idx - ci * 9)];
  }
  if (t < 32) bias[t] = dwb[c0 + t];
  __syncthreads();
  int cc = t & 31, wq = t >> 5;
  float ls = 0.f;
  for (int j = 0; j < 8; ++j) {
    int w = wq + 8 * j;
    float acc = bias[cc];
#pragma unroll
    for (int r = 0; r < 3; ++r)
#pragma unroll
      for (int kw = 0; kw < 3; ++kw)
        acc += in_s[r][cc][w + kw] * wg[cc][r * 3 + kw];
    out[(((size_t)b * 64 + h) * 64 + w) * 192 + c0 + cc] = __float2bfloat16(acc);
    ls += scrub(acc);
  }
  psum[wq][cc] = ls;
  __syncthreads();
  if (t < 32) {
    float s = 0.f;
    for (int r = 0; r < 8; ++r) s += psum[r][t];
    partial[((size_t)b * 64 + h) * 192 + c0 + t] = s;
  }
}

// ----------------------------------------------------------------------------
// linear via bf16 MFMA: y(131072x192 bf16) @ Wb^T (384x192 bf16) + lin_b
// -> xh (fp32, n<192) | zb (bf16, n>=192).
// Block 256 thr = 4 waves, tile 128m x 128n, wave tile 64x64 (4x4 frags of
// 16x16x32). LDS [row][k] bf16, row stride 40 (80B: 2-way aliasing only).
// grid (1024, 3).
// ----------------------------------------------------------------------------
__global__ __launch_bounds__(256) void linear_mfma_kernel(
    const bf16* Yb, const bf16* Wb, const float* bias, float* xh, bf16* zb)
{
  __shared__ __align__(16) short Asm[128 * 40];
  __shared__ __align__(16) short Bsm[128 * 40];
  int m0 = blockIdx.x * 128, n0 = blockIdx.y * 128;
  int t = threadIdx.x;
  int wave = t >> 6, lane = t & 63;
  int wm = (wave & 1) * 64, wn = (wave >> 1) * 64;
  int lq = lane >> 4, lr = lane & 15;
  float4v acc[4][4];
#pragma unroll
  for (int i = 0; i < 4; ++i)
#pragma unroll
    for (int j = 0; j < 4; ++j) acc[i][j] = (float4v){0.f, 0.f, 0.f, 0.f};

  for (int k0 = 0; k0 < 192; k0 += 32) {
    // stage A (chunks 0..511) and B (512..1023): 16B per chunk
#pragma unroll
    for (int i = 0; i < 4; ++i) {
      int ch = t + 256 * i;
      int isB = ch >> 9, c = ch & 511;
      int r = c >> 2, kc = c & 3;
      const bf16* src = isB ? (Wb + (size_t)(n0 + r) * 192 + k0 + kc * 8)
                            : (Yb + (size_t)(m0 + r) * 192 + k0 + kc * 8);
      float4 v = *(const float4*)src;
      short* dst = (isB ? Bsm : Asm) + r * 40 + kc * 8;
      *(float4*)dst = v;
    }
    __syncthreads();
    short8v af[4], bfr[4];
#pragma unroll
    for (int f = 0; f < 4; ++f) {
      af[f]  = *(const short8v*)&Asm[(wm + f * 16 + lr) * 40 + lq * 8];
      bfr[f] = *(const short8v*)&Bsm[(wn + f * 16 + lr) * 40 + lq * 8];
    }
#pragma unroll
    for (int fm = 0; fm < 4; ++fm)
#pragma unroll
      for (int fn = 0; fn < 4; ++fn)
        acc[fm][fn] = __builtin_amdgcn_mfma_f32_16x16x32_bf16(
            af[fm], bfr[fn], acc[fm][fn], 0, 0, 0);
    __syncthreads();
  }
  // epilogue: D row = 4*(lane>>4)+e, col = lane&15
#pragma unroll
  for (int fm = 0; fm < 4; ++fm)
#pragma unroll
    for (int e = 0; e < 4; ++e) {
      int m = m0 + wm + fm * 16 + lq * 4 + e;
#pragma unroll
      for (int fn = 0; fn < 4; ++fn) {
        int n = n0 + wn + fn * 16 + lr;
        float v = acc[fm][fn][e] + bias[n];
        if (n < 192) xh[(size_t)m * 192 + n] = v;
        else         zb[(size_t)m * 192 + (n - 192)] = __float2bfloat16(v);
      }
    }
}

// ----------------------------------------------------------------------------
// pooled[b][c] = (1/4096)*sum_h partial[b][h][c'] contracted with lin_w:
// pooled = mean_hw(y) @ lin_w[0:192]^T + lin_b  (fp32-exact sel path)
// grid 12, block 256 (16 c x 16 b-pairs)
// ----------------------------------------------------------------------------
__global__ __launch_bounds__(256) void pooled_kernel(
    const float* partial, const float* linW, const float* linB, float* pooled)
{
  __shared__ float pcs[32 * 193];
  int t = threadIdx.x;
  int c0 = blockIdx.x * 16;
  for (int i = t; i < 6144; i += 256) {
    int b = i / 192, c = i - b * 192;
    float s = 0.f;
    const float* p = partial + (size_t)b * 64 * 192 + c;
    for (int h = 0; h < 64; ++h) s += p[h * 192];
    pcs[b * 193 + c] = s;
  }
  __syncthreads();
  int c = c0 + (t & 15), bp = t >> 4;
#pragma unroll
  for (int half = 0; half < 2; ++half) {
    int b = bp + 16 * half;
    float a = 0.f;
    for (int k = 0; k < 192; ++k) a += pcs[b * 193 + k] * linW[(size_t)c * 192 + k];
    pooled[b * 192 + c] = linB[c] + a * (1.f / 4096.f);
  }
}

// ----------------------------------------------------------------------------
// kmap: e = relu(freq @ tok_w^T + tok_b); k = exp(-((pi i/64)^2+(pi j/64)^2)*e)
// grid (64, 3)
// ----------------------------------------------------------------------------
__global__ __launch_bounds__(256) void kmap_kernel(
    const float* A, const float* Wt, const float* bias, float* kout)
{
  __shared__ float As[32][65];
  __shared__ float Bs[32][65];
  int m0 = blockIdx.x * 64, n0 = blockIdx.y * 64;
  int t = threadIdx.x, tx = t & 15, ty = t >> 4;
  float acc[4][4] = {};
  for (int k0 = 0; k0 < 192; k0 += 32) {
    int kk = t & 31, mm = t >> 5;
#pragma unroll
    for (int i = 0; i < 8; ++i) {
      As[kk][mm + 8 * i] = A[(size_t)(m0 + mm + 8 * i) * 192 + k0 + kk];
      Bs[kk][mm + 8 * i] = Wt[(size_t)(n0 + mm + 8 * i) * 192 + k0 + kk];
    }
    __syncthreads();
    for (int k = 0; k < 32; ++k) {
      float a[4], bb[4];
#pragma unroll
      for (int i = 0; i < 4; ++i) a[i] = As[k][ty * 4 + i];
#pragma unroll
      for (int j = 0; j < 4; ++j) bb[j] = Bs[k][tx * 4 + j];
#pragma unroll
      for (int i = 0; i < 4; ++i)
#pragma unroll
        for (int j = 0; j < 4; ++j) acc[i][j] += a[i] * bb[j];
    }
    __syncthreads();
  }
  const float PI2 = 9.86960440108935862f;
  for (int i = 0; i < 4; ++i) {
    int m = m0 + ty * 4 + i;
    int ii = m >> 6, jj = m & 63;
    float d2 = (PI2 / 4096.f) * (float)(ii * ii + jj * jj);
    for (int j = 0; j < 4; ++j) {
      int n = n0 + tx * 4 + j;
      float e = acc[i][j] + bias[n];
      e = e > 0.f ? e : 0.f;
      kout[(size_t)m * 192 + n] = expf(-d2 * e);
    }
  }
}

// ----------------------------------------------------------------------------
// MLP + batchnorms + gumbel argmax -> sel[32] ; 1 block
// ----------------------------------------------------------------------------
__global__ __launch_bounds__(256) void mlp_kernel(
    const float* pooled, const float* gn,
    const float* p1w, const float* p1b, const float* g1, const float* b1,
    const float* p2w, const float* p2b, const float* g2, const float* b2,
    const float* p3w, const float* p3b, int* sel)
{
  __shared__ float pl[32 * 192];
  __shared__ float h1s[32 * 256];
  __shared__ float h2s[32 * 32];
  int t = threadIdx.x;
  for (int i = t; i < 32 * 192; i += 256) pl[i] = pooled[i];
  __syncthreads();
  {
    float acc[32];
    float bb = p1b[t];
#pragma unroll
    for (int b = 0; b < 32; ++b) acc[b] = bb;
    for (int c = 0; c < 192; ++c) {
      float w = p1w[t * 192 + c];
#pragma unroll
      for (int b = 0; b < 32; ++b) acc[b] += w * pl[b * 192 + c];
    }
    for (int b = 0; b < 32; ++b) {
      float v = acc[b];
      v = v > 0.f ? v : 0.1f * v;
      h1s[b * 256 + t] = v;
    }
  }
  __syncthreads();
  {
    float m = 0.f;
    for (int b = 0; b < 32; ++b) m += h1s[b * 256 + t];
    m *= (1.f / 32.f);
    float v = 0.f;
    for (int b = 0; b < 32; ++b) { float d = h1s[b * 256 + t] - m; v += d * d; }
    v *= (1.f / 32.f);
    float sc = g1[t] / sqrtf(v + 1e-5f);
    float sh = b1[t] - m * sc;
    for (int b = 0; b < 32; ++b) h1s[b * 256 + t] = h1s[b * 256 + t] * sc + sh;
  }
  __syncthreads();
  {
    int j = t & 31, bg = t >> 5;
    float acc[4];
    float bb = p2b[j];
    for (int i = 0; i < 4; ++i) acc[i] = bb;
    for (int c = 0; c < 256; ++c) {
      float w = p2w[j * 256 + c];
#pragma unroll
      for (int i = 0; i < 4; ++i) acc[i] += w * h1s[(bg * 4 + i) * 256 + c];
    }
    for (int i = 0; i < 4; ++i) {
      float v = acc[i];
      v = v > 0.f ? v : 0.1f * v;
      h2s[(bg * 4 + i) * 32 + j] = v;
    }
  }
  __syncthreads();
  if (t < 32) {
    float m = 0.f;
    for (int b = 0; b < 32; ++b) m += h2s[b * 32 + t];
    m *= (1.f / 32.f);
    float v = 0.f;
    for (int b = 0; b < 32; ++b) { float d = h2s[b * 32 + t] - m; v += d * d; }
    v *= (1.f / 32.f);
    float sc = g2[t] / sqrtf(v + 1e-5f);
    float sh = b2[t] - m * sc;
    for (int b = 0; b < 32; ++b) h2s[b * 32 + t] = h2s[b * 32 + t] * sc + sh;
  }
  __syncthreads();
  if (t < 32) {
    float best = -1e30f; int bi = 0;
    for (int r = 0; r < 3; ++r) {
      float l = p3b[r];
      for (int c = 0; c < 32; ++c) l += p3w[r * 32 + c] * h2s[t * 32 + c];
      l += gn[t * 3 + r];
      if (l > best) { best = l; bi = r; }
    }
    sel[t] = bi;
  }
}

// ----------------------------------------------------------------------------
// DCT stage over first axis of (64, 12288), in-place. grid (192, 32)
// ----------------------------------------------------------------------------
__global__ __launch_bounds__(256) void axis0_kernel(
    float* buf, const float* mat, const int* sel, int branch)
{
  int b = blockIdx.y;
  if (sel[b] != branch) return;
  int q0 = blockIdx.x * 64;
  __shared__ float mT[64][65];
  __shared__ float xs[64][65];
  int t = threadIdx.x;
  for (int i = t; i < 4096; i += 256) {
    int r = i >> 6, c = i & 63;
    mT[c][r] = mat[i];
    xs[r][c] = buf[(size_t)b * SLICE + r * 12288 + q0 + c];
  }
  __syncthreads();
  int tx = t & 15, ty = t >> 4;
  float acc[4][4] = {};
  for (int l = 0; l < 64; ++l) {
    float a[4], xv[4];
#pragma unroll
    for (int i = 0; i < 4; ++i) a[i] = mT[l][ty * 4 + i];
#pragma unroll
    for (int j = 0; j < 4; ++j) xv[j] = xs[l][tx * 4 + j];
#pragma unroll
    for (int i = 0; i < 4; ++i)
#pragma unroll
      for (int j = 0; j < 4; ++j) acc[i][j] += a[i] * xv[j];
  }
  float* ob = buf + (size_t)b * SLICE;
  for (int i = 0; i < 4; ++i)
    for (int j = 0; j < 4; ++j)
      ob[(ty * 4 + i) * 12288 + q0 + tx * 4 + j] = acc[i][j];
}

// DCT stage over middle axis, in-place, optional k multiply. grid (192, 32)
__global__ __launch_bounds__(256) void axis1_kernel(
    float* buf, const float* mat, const float* kmul, const int* sel, int branch)
{
  int b = blockIdx.y;
  if (sel[b] != branch) return;
  int n = blockIdx.x / 3;
  int ct = (blockIdx.x - n * 3) * 64;
  float* base = buf + (size_t)b * SLICE + n * (64 * 192) + ct;
  __shared__ float mT[64][65];
  __shared__ float xs[64][65];
  int t = threadIdx.x;
  for (int i = t; i < 4096; i += 256) {
    int r = i >> 6, c = i & 63;
    mT[c][r] = mat[i];
    xs[r][c] = base[r * 192 + c];
  }
  __syncthreads();
  int tx = t & 15, ty = t >> 4;
  float acc[4][4] = {};
  for (int l = 0; l < 64; ++l) {
    float a[4], xv[4];
#pragma unroll
    for (int i = 0; i < 4; ++i) a[i] = mT[l][ty * 4 + i];
#pragma unroll
    for (int j = 0; j < 4; ++j) xv[j] = xs[l][tx * 4 + j];
#pragma unroll
    for (int i = 0; i < 4; ++i)
#pragma unroll
      for (int j = 0; j < 4; ++j) acc[i][j] += a[i] * xv[j];
  }
  if (kmul) {
    for (int i = 0; i < 4; ++i)
      for (int j = 0; j < 4; ++j)
        acc[i][j] *= kmul[(size_t)(n * 64 + ty * 4 + i) * 192 + ct + tx * 4 + j];
  }
  for (int i = 0; i < 4; ++i)
    for (int j = 0; j < 4; ++j)
      base[(ty * 4 + i) * 192 + tx * 4 + j] = acc[i][j];
}

// ----------------------------------------------------------------------------
// FFT forward over h (real -> complex), real in-place into xh, imag -> Si
// ----------------------------------------------------------------------------
__global__ __launch_bounds__(256) void ffth_kernel(
    float* xh, float* Si, const float2* E64, const int* sel)
{
  int b = blockIdx.y;
  if (sel[b] != 1) return;
  int q0 = blockIdx.x * 64;
  __shared__ float er[64][65], ei[64][65], xs[64][65];
  int t = threadIdx.x;
  for (int i = t; i < 4096; i += 256) {
    int r = i >> 6, c = i & 63;
    float2 e = E64[i];
    er[r][c] = e.x; ei[r][c] = e.y;
    xs[r][c] = xh[(size_t)b * SLICE + r * 12288 + q0 + c];
  }
  __syncthreads();
  int tx = t & 15, ty = t >> 4;
  float ar[4][4] = {}, ai[4][4] = {};
  for (int l = 0; l < 64; ++l) {
    float e1[4], e2[4], xv[4];
#pragma unroll
    for (int i = 0; i < 4; ++i) { e1[i] = er[l][ty * 4 + i]; e2[i] = ei[l][ty * 4 + i]; }
#pragma unroll
    for (int j = 0; j < 4; ++j) xv[j] = xs[l][tx * 4 + j];
#pragma unroll
    for (int i = 0; i < 4; ++i)
#pragma unroll
      for (int j = 0; j < 4; ++j) { ar[i][j] += e1[i] * xv[j]; ai[i][j] += e2[i] * xv[j]; }
  }
  size_t ob = (size_t)b * SLICE;
  for (int i = 0; i < 4; ++i)
    for (int j = 0; j < 4; ++j) {
      size_t o = ob + (size_t)(ty * 4 + i) * 12288 + q0 + tx * 4 + j;
      xh[o] = ar[i][j];
      Si[o] = ai[i][j];
    }
}

// FFT over w (complex, in-place). grid (384, 32)
__global__ __launch_bounds__(256) void fftw_kernel(
    float* Sr, float* Si, const float2* E64, const int* sel, float s)
{
  int b = blockIdx.y;
  if (sel[b] != 1) return;
  int kh = blockIdx.x / 6;
  int ct = (blockIdx.x - kh * 6) * 32;
  float* br = Sr + (size_t)b * SLICE + kh * 12288 + ct;
  float* bi = Si + (size_t)b * SLICE + kh * 12288 + ct;
  __shared__ float er[64][65], ei[64][65];
  __shared__ float xr[64][33], xi[64][33];
  int t = threadIdx.x;
  for (int i = t; i < 4096; i += 256) {
    float2 e = E64[i];
    er[i >> 6][i & 63] = e.x;
    ei[i >> 6][i & 63] = s * e.y;
  }
  for (int i = t; i < 2048; i += 256) {
    int l = i >> 5, q = i & 31;
    xr[l][q] = br[l * 192 + q];
    xi[l][q] = bi[l * 192 + q];
  }
  __syncthreads();
  int tx = t & 7, ty = t >> 3;
  float ar[2][4] = {}, ac[2][4] = {};
  for (int l = 0; l < 64; ++l) {
    float e1a = er[l][ty],      e2a = ei[l][ty];
    float e1b = er[l][ty + 32], e2b = ei[l][ty + 32];
#pragma unroll
    for (int j = 0; j < 4; ++j) {
      float vr = xr[l][tx * 4 + j], vi = xi[l][tx * 4 + j];
      ar[0][j] += e1a * vr - e2a * vi;
      ac[0][j] += e1a * vi + e2a * vr;
      ar[1][j] += e1b * vr - e2b * vi;
      ac[1][j] += e1b * vi + e2b * vr;
    }
  }
  for (int r = 0; r < 2; ++r) {
    int kw = ty + r * 32;
    for (int j = 0; j < 4; ++j) {
      br[kw * 192 + tx * 4 + j] = ar[r][j];
      bi[kw * 192 + tx * 4 + j] = ac[r][j];
    }
  }
}

// ----------------------------------------------------------------------------
// Fused c-stage via Cooley-Tukey 3x64 (see r1 notes). grid (128, 32).
// ----------------------------------------------------------------------------
__global__ __launch_bounds__(256, 3) void fftc_fused_kernel(
    float* Sr, float* Si, const float* kmap, const int* sel)
{
  int b = blockIdx.y;
  if (sel[b] != 1) return;
  int m0 = blockIdx.x * 32;
  float* gr = Sr + (size_t)b * SLICE + (size_t)m0 * 192;
  float* gi = Si + (size_t)b * SLICE + (size_t)m0 * 192;
  __shared__ __align__(16) float2 T[192][34];
  int t = threadIdx.x;
  for (int i = t; i < 6144; i += 256) {
    int row = i / 192, c = i - row * 192;
    T[c][row] = make_float2(gr[i], gi[i]);
  }
  int tx = t & 31, ty = t >> 5;
  int rbase = ty * 4;
  double A = 2.0 * 3.14159265358979323846 * (double)tx;
  double sa, ca, sb, cb;
  sincos(A / 64.0, &sa, &ca);
  sincos(A / 192.0, &sb, &cb);
  float c64 = (float)ca, s64 = (float)sa;
  float cw = (float)cb, sw = (float)sb;
  const float S3 = 0.86602540378443864676f;
  float fsr[2], fsi[2];
  fsr[0] = c64;  fsi[0] = -s64;
  fsr[1] = -c64; fsi[1] = s64;
  float w1r[2], w1i[2], w2r[2], w2i[2];
  w1r[0] = cw;                   w1i[0] = -sw;
  w1r[1] = 0.5f * cw - S3 * sw;  w1i[1] = -S3 * cw - 0.5f * sw;
#pragma unroll
  for (int u = 0; u < 2; ++u) {
    w2r[u] = w1r[u] * w1r[u] - w1i[u] * w1i[u];
    w2i[u] = 2.f * w1r[u] * w1i[u];
  }
  __syncthreads();
  float ar[2][3][4], ai[2][3][4];
#pragma unroll
  for (int u = 0; u < 2; ++u)
#pragma unroll
    for (int n1 = 0; n1 < 3; ++n1)
#pragma unroll
      for (int r = 0; r < 4; ++r) { ar[u][n1][r] = 0.f; ai[u][n1][r] = 0.f; }
  {
    float pr[2], pq[2];
    pr[0] = 1.f; pr[1] = 1.f; pq[0] = 0.f; pq[1] = 0.f;
    for (int n2 = 0; n2 < 64; ++n2) {
      const float4* p0 = (const float4*)&T[3 * n2][rbase];
      const float4* p1 = (const float4*)&T[3 * n2 + 1][rbase];
      const float4* p2 = (const float4*)&T[3 * n2 + 2][rbase];
      float4 q00 = p0[0], q01 = p0[1];
      float4 q10 = p1[0], q11 = p1[1];
      float4 q20 = p2[0], q21 = p2[1];
      float xr[3][4], xi[3][4];
      xr[0][0] = q00.x; xi[0][0] = q00.y; xr[0][1] = q00.z; xi[0][1] = q00.w;
      xr[0][2] = q01.x; xi[0][2] = q01.y; xr[0][3] = q01.z; xi[0][3] = q01.w;
      xr[1][0] = q10.x; xi[1][0] = q10.y; xr[1][1] = q10.z; xi[1][1] = q10.w;
      xr[1][2] = q11.x; xi[1][2] = q11.y; xr[1][3] = q11.z; xi[1][3] = q11.w;
      xr[2][0] = q20.x; xi[2][0] = q20.y; xr[2][1] = q20.z; xi[2][1] = q20.w;
      xr[2][2] = q21.x; xi[2][2] = q21.y; xr[2][3] = q21.z; xi[2][3] = q21.w;
#pragma unroll
      for (int u = 0; u < 2; ++u) {
        float er = pr[u], ei = pq[u];
#pragma unroll
        for (int n1 = 0; n1 < 3; ++n1)
#pragma unroll
          for (int r = 0; r < 4; ++r) {
            ar[u][n1][r] += xr[n1][r] * er - xi[n1][r] * ei;
            ai[u][n1][r] += xr[n1][r] * ei + xi[n1][r] * er;
          }
        float nr = er * fsr[u] - ei * fsi[u];
        pq[u] = er * fsi[u] + ei * fsr[u];
        pr[u] = nr;
      }
    }
  }
  const float SCALE = 1.0f / 786432.0f;
#pragma unroll
  for (int u = 0; u < 2; ++u) {
    int m = tx + 32 * u;
#pragma unroll
    for (int r = 0; r < 4; ++r) {
      int row = rbase + r;
      float Y0r = ar[u][0][r], Y0i = ai[u][0][r];
      float Y1r = ar[u][1][r], Y1i = ai[u][1][r];
      float Y2r = ar[u][2][r], Y2i = ai[u][2][r];
      float T1r = Y1r * w1r[u] - Y1i * w1i[u];
      float T1i = Y1r * w1i[u] + Y1i * w1r[u];
      float T2r = Y2r * w2r[u] - Y2i * w2i[u];
      float T2i = Y2r * w2i[u] + Y2i * w2r[u];
      float aRr = T1r + T2r, aRi = T1i + T2i;
      float bRr = T1r - T2r, bRi = T1i - T2i;
      float X0r = Y0r + aRr, X0i = Y0i + aRi;
      float cfr = Y0r - 0.5f * aRr, cfi = Y0i - 0.5f * aRi;
      float X1r = cfr + S3 * bRi, X1i = cfi - S3 * bRr;
      float X2r = cfr - S3 * bRi, X2i = cfi + S3 * bRr;
      const float* kp = kmap + (size_t)(m0 + row) * 192 + m;
      float k0 = kp[0] * SCALE, k1 = kp[64] * SCALE, k2 = kp[128] * SCALE;
      X0r *= k0; X0i *= k0; X1r *= k1; X1i *= k1; X2r *= k2; X2i *= k2;
      float a2r = X1r + X2r, a2i = X1i + X2i;
      float b2r = X1r - X2r, b2i = X1i - X2i;
      float U0r = X0r + a2r, U0i = X0i + a2i;
      float c2r = X0r - 0.5f * a2r, c2i = X0i - 0.5f * a2i;
      float U1r = c2r - S3 * b2i, U1i = c2i + S3 * b2r;
      float U2r = c2r + S3 * b2i, U2i = c2i - S3 * b2r;
      ar[u][0][r] = U0r;
      ai[u][0][r] = U0i;
      ar[u][1][r] = U1r * w1r[u] + U1i * w1i[u];
      ai[u][1][r] = U1i * w1r[u] - U1r * w1i[u];
      ar[u][2][r] = U2r * w2r[u] + U2i * w2i[u];
      ai[u][2][r] = U2i * w2r[u] - U2r * w2i[u];
    }
  }
  __syncthreads();
#pragma unroll
  for (int u = 0; u < 2; ++u)
#pragma unroll
    for (int n1 = 0; n1 < 3; ++n1)
#pragma unroll
      for (int r = 0; r < 4; ++r)
        T[n1 * 64 + tx + 32 * u][rbase + r] =
            make_float2(ar[u][n1][r], ai[u][n1][r]);
  __syncthreads();
  float qr_[2][3][4], qi_[2][3][4];
#pragma unroll
  for (int u = 0; u < 2; ++u)
#pragma unroll
    for (int n1 = 0; n1 < 3; ++n1)
#pragma unroll
      for (int r = 0; r < 4; ++r) { qr_[u][n1][r] = 0.f; qi_[u][n1][r] = 0.f; }
  {
    float isr[2], isi[2];
    isr[0] = c64;  isi[0] = s64;
    isr[1] = -c64; isi[1] = -s64;
    float pr[2], pq[2];
    pr[0] = 1.f; pr[1] = 1.f; pq[0] = 0.f; pq[1] = 0.f;
    for (int ms = 0; ms < 64; ++ms) {
      const float4* p0 = (const float4*)&T[ms][rbase];
      const float4* p1 = (const float4*)&T[64 + ms][rbase];
      const float4* p2 = (const float4*)&T[128 + ms][rbase];
      float4 q00 = p0[0], q01 = p0[1];
      float4 q10 = p1[0], q11 = p1[1];
      float4 q20 = p2[0], q21 = p2[1];
      float xr[3][4], xi[3][4];
      xr[0][0] = q00.x; xi[0][0] = q00.y; xr[0][1] = q00.z; xi[0][1] = q00.w;
      xr[0][2] = q01.x; xi[0][2] = q01.y; xr[0][3] = q01.z; xi[0][3] = q01.w;
      xr[1][0] = q10.x; xi[1][0] = q10.y; xr[1][1] = q10.z; xi[1][1] = q10.w;
      xr[1][2] = q11.x; xi[1][2] = q11.y; xr[1][3] = q11.z; xi[1][3] = q11.w;
      xr[2][0] = q20.x; xi[2][0] = q20.y; xr[2][1] = q20.z; xi[2][1] = q20.w;
      xr[2][2] = q21.x; xi[2][2] = q21.y; xr[2][3] = q21.z; xi[2][3] = q21.w;
#pragma unroll
      for (int u = 0; u < 2; ++u) {
        float er = pr[u], ei = pq[u];
#pragma unroll
        for (int n1 = 0; n1 < 3; ++n1)
#pragma unroll
          for (int r = 0; r < 4; ++r) {
            qr_[u][n1][r] += xr[n1][r] * er - xi[n1][r] * ei;
            qi_[u][n1][r] += xr[n1][r] * ei + xi[n1][r] * er;
          }
        float nr = er * isr[u] - ei * isi[u];
        pq[u] = er * isi[u] + ei * isr[u];
        pr[u] = nr;
      }
    }
  }
#pragma unroll
  for (int r = 0; r < 4; ++r) {
    int row = rbase + r;
#pragma unroll
    for (int u = 0; u < 2; ++u) {
      int c0 = 3 * (tx + 32 * u);
#pragma unroll
      for (int n1 = 0; n1 < 3; ++n1) {
        gr[(size_t)row * 192 + c0 + n1] = qr_[u][n1][r];
        gi[(size_t)row * 192 + c0 + n1] = qi_[u][n1][r];
      }
    }
  }
}

// inverse h-stage, real part only, in-place into xh. grid (384, 32)
__global__ __launch_bounds__(256) void ffthi_kernel(
    float* Sr, const float* Si, const float2* E64, const int* sel)
{
  int b = blockIdx.y;
  if (sel[b] != 1) return;
  int q0 = blockIdx.x * 32;
  __shared__ float er[64][65], ei[64][65];
  __shared__ float xr[64][33], xi[64][33];
  int t = threadIdx.x;
  for (int i = t; i < 4096; i += 256) {
    float2 e = E64[i];
    er[i >> 6][i & 63] = e.x;
    ei[i >> 6][i & 63] = e.y;
  }
  for (int i = t; i < 2048; i += 256) {
    int l = i >> 5, q = i & 31;
    size_t o = (size_t)b * SLICE + (size_t)l * 12288 + q0 + q;
    xr[l][q] = Sr[o];
    xi[l][q] = Si[o];
  }
  __syncthreads();
  int tx = t & 7, ty = t >> 3;
  float acc[2][4] = {};
  for (int l = 0; l < 64; ++l) {
    float e1a = er[l][ty],      e2a = ei[l][ty];
    float e1b = er[l][ty + 32], e2b = ei[l][ty + 32];
#pragma unroll
    for (int j = 0; j < 4; ++j) {
      float vr = xr[l][tx * 4 + j], vi = xi[l][tx * 4 + j];
      acc[0][j] += e1a * vr + e2a * vi;
      acc[1][j] += e1b * vr + e2b * vi;
    }
  }
  for (int r = 0; r < 2; ++r) {
    int h = ty + r * 32;
    for (int j = 0; j < 4; ++j)
      Sr[(size_t)b * SLICE + (size_t)h * 12288 + q0 + tx * 4 + j] = acc[r][j];
  }
}

// ----------------------------------------------------------------------------
// Haar branch, in-place on xh. grid (128, 32)
// ----------------------------------------------------------------------------
__global__ __launch_bounds__(256) void haar_kernel(
    float* xh, const float* kmap, const int* sel)
{
  int b = blockIdx.y;
  if (sel[b] != 2) return;
  int h = blockIdx.x >> 1;
  int w0 = (blockIdx.x & 1) * 32;
  size_t base = (size_t)b * SLICE + ((size_t)h * 64 + w0) * 192;
  __shared__ float A[32 * 192];
  __shared__ float Bf[32 * 192];
  int t = threadIdx.x;
  for (int i = t; i < 6144; i += 256) A[i] = xh[base + i];
  __syncthreads();
  for (int u = t; u < 32 * 96; u += 256) {
    int p = u / 96, r = u - p * 96;
    int ch = r >> 5, i = r & 31;
    float v0 = A[p * 192 + ch * 64 + 2 * i];
    float v1 = A[p * 192 + ch * 64 + 2 * i + 1];
    Bf[p * 192 + ch * 64 + i]      = (v0 + v1) * 0.5f;
    Bf[p * 192 + ch * 64 + 32 + i] = (v0 - v1) * 0.5f;
  }
  __syncthreads();
  for (int u = t; u < 32 * 96; u += 256) {
    int p = u / 96, i = u - p * 96;
    float v0 = Bf[p * 192 + 2 * i];
    float v1 = Bf[p * 192 + 2 * i + 1];
    A[p * 192 + i]      = (v0 + v1) * 0.5f;
    A[p * 192 + 96 + i] = (v0 - v1) * 0.5f;
  }
  __syncthreads();
  for (int i = t; i < 6144; i += 256)
    A[i] *= kmap[((size_t)h * 64 + w0) * 192 + i];
  __syncthreads();
  for (int u = t; u < 32 * 96; u += 256) {
    int p = u / 96, r = u - p * 96;
    int ch = r >> 5, i = r & 31;
    float a = A[p * 192 + ch * 64 + i];
    float d = A[p * 192 + ch * 64 + 32 + i];
    Bf[p * 192 + ch * 64 + 2 * i]     = a + d;
    Bf[p * 192 + ch * 64 + 2 * i + 1] = a - d;
  }
  __syncthreads();
  for (int u = t; u < 32 * 96; u += 256) {
    int p = u / 96, i = u - p * 96;
    float a = Bf[p * 192 + i];
    float d = Bf[p * 192 + 96 + i];
    A[p * 192 + 2 * i]     = a + d;
    A[p * 192 + 2 * i + 1] = a - d;
  }
  __syncthreads();
  for (int i = t; i < 6144; i += 256) xh[base + i] = A[i];
}

// ----------------------------------------------------------------------------
// final: LN(c) * silu(z) @ out_w^T + out_b, dual-dtype store. grid 2048
// ----------------------------------------------------------------------------
__global__ __launch_bounds__(256) void final_kernel(
    const float* comb, const bf16* zb, const float* lng, const float* lnb,
    const float* wT, const float* outb, void* outp, const int* flag)
{
  int flg = *flag;
  int bi = blockIdx.x;
  int b = bi >> 6, h = bi & 63;
  size_t base = ((size_t)b * 4096 + (size_t)h * 64) * 192;
  __shared__ float As[64 * 194];
  __shared__ float mu[64], rs[64];
  int t = threadIdx.x;
  for (int e = t; e < 12288; e += 256) {
    int p = e / 192, c = e - p * 192;
    As[p * 194 + c] = scrub(comb[base + e]);
  }
  __syncthreads();
  if (t < 64) {
    float s = 0.f;
    for (int c = 0; c < 192; ++c) s += As[t * 194 + c];
    float m = s * (1.f / 192.f);
    float v = 0.f;
    for (int c = 0; c < 192; ++c) { float d = As[t * 194 + c] - m; v += d * d; }
    v *= (1.f / 192.f);
    mu[t] = m;
    rs[t] = 1.f / sqrtf(v + 1e-5f);
  }
  __syncthreads();
  for (int e = t; e < 12288; e += 256) {
    int p = e / 192, c = e - p * 192;
    float v = (As[p * 194 + c] - mu[p]) * rs[p] * lng[c] + lnb[c];
    float zv = scrub(b2f(zb[base + e]));
    v *= zv / (1.f + expf(-zv));
    As[p * 194 + c] = v;
  }
  __syncthreads();
  int tx = t & 15, ty = t >> 4;
  float acc[4][12];
  for (int i = 0; i < 4; ++i)
    for (int j = 0; j < 12; ++j) acc[i][j] = 0.f;
  for (int c = 0; c < 192; ++c) {
    float av[4];
#pragma unroll
    for (int i = 0; i < 4; ++i) av[i] = As[(ty * 4 + i) * 194 + c];
    float wv[12];
#pragma unroll
    for (int j = 0; j < 12; ++j) wv[j] = wT[(size_t)c * 192 + tx * 12 + j];
#pragma unroll
    for (int i = 0; i < 4; ++i)
#pragma unroll
      for (int j = 0; j < 12; ++j) acc[i][j] += av[i] * wv[j];
  }
  __syncthreads();
  for (int i = 0; i < 4; ++i)
    for (int j = 0; j < 12; ++j) {
      int co = tx * 12 + j, p = ty * 4 + i;
      As[co * 64 + p] = acc[i][j] + outb[co];
    }
  __syncthreads();
  for (int e = t; e < 12288; e += 256) {
    int co = e >> 6, w = e & 63;
    size_t oi = (((size_t)b * 192 + co) * 64 + h) * 64 + w;
    if (flg) ((float*)outp)[oi] = As[e];
    else     ((bf16*)outp)[oi] = __float2bfloat16(As[e]);
  }
}

// ----------------------------------------------------------------------------
extern "C" void kernel_launch(void* const* d_in, const int* in_sizes, int n_in,
                              void* d_out, int out_size, void* d_ws, size_t ws_size,
                              hipStream_t stream) {
  (void)in_sizes; (void)n_in;
  if (ws_size < WS_NEEDED_BYTES) {
    fill_zero_kernel<<<(out_size + 255) / 256, 256, 0, stream>>>(
        (unsigned short*)d_out, out_size);
    return;
  }
  float* ws    = (float*)d_ws;
  float* xh    = ws + O_XH;
  float* Si    = ws + O_SI;
  bf16*  Yb    = (bf16*)(ws + O_YB);
  float* part  = ws + O_PART;
  bf16*  Wb    = (bf16*)(ws + O_WB);
  bf16*  zb    = (bf16*)(ws + O_ZB);
  float* kmap  = ws + O_KMAP;
  float2* E64  = (float2*)(ws + O_E64);
  float* Dm    = ws + O_DM;
  float* DT    = ws + O_DT;
  float* wT    = ws + O_WT;
  float* pooled= ws + O_POOL;
  int*   sel   = (int*)(ws + O_SEL);
  int*   flag  = (int*)(ws + O_FLAG);

  sniff_kernel<<<1, 64, 0, stream>>>((const unsigned short*)d_in[0], flag);

  CvtArgs ca;
  const int srcidx[22] = {2,3,4,5,6,7,8,9,10,11,12,13,14,15,16,17,18,19,20,21,22,1};
  const int ns[22] = {96,1728,192,73728,384,49152,256,256,256,8192,32,32,32,96,3,
                      36864,192,192,192,36864,192,786432};
  const long long offs[22] = {
    (long long)W_GN,(long long)W_DWW,(long long)W_DWB,(long long)W_LINW,
    (long long)W_LINB,(long long)W_P1W,(long long)W_P1B,(long long)W_G1,
    (long long)W_B1,(long long)W_P2W,(long long)W_P2B,(long long)W_G2,
    (long long)W_B2,(long long)W_P3W,(long long)W_P3B,(long long)W_TOKW,
    (long long)W_TOKB,(long long)W_LNG,(long long)W_LNB,(long long)W_OUTW,
    (long long)W_OUTB,(long long)O_FREQ};
  for (int i = 0; i < 22; ++i) { ca.src[i] = d_in[srcidx[i]]; ca.n[i] = ns[i]; ca.off[i] = offs[i]; }
  cvt_kernel<<<64, 256, 0, stream>>>(ca, ws, flag);

  setup_kernel<<<64, 256, 0, stream>>>(Dm, DT, E64, wT, ws + W_OUTW, Wb, ws + W_LINW);
  conv_kernel<<<dim3(6, 64, 32), 256, 0, stream>>>(d_in[0], flag, ws + W_DWW, ws + W_DWB,
                                                   Yb, part);
  linear_mfma_kernel<<<dim3(1024, 3), 256, 0, stream>>>(Yb, Wb, ws + W_LINB, xh, zb);
  pooled_kernel<<<12, 256, 0, stream>>>(part, ws + W_LINW, ws + W_LINB, pooled);
  mlp_kernel<<<1, 256, 0, stream>>>(pooled, ws + W_GN,
      ws + W_P1W, ws + W_P1B, ws + W_G1, ws + W_B1,
      ws + W_P2W, ws + W_P2B, ws + W_G2, ws + W_B2,
      ws + W_P3W, ws + W_P3B, sel);
  kmap_kernel<<<dim3(64, 3), 256, 0, stream>>>(ws + O_FREQ, ws + W_TOKW, ws + W_TOKB, kmap);
  // DCT branch (sel==0), in-place on xh
  axis0_kernel<<<dim3(192, 32), 256, 0, stream>>>(xh, Dm, sel, 0);
  axis1_kernel<<<dim3(192, 32), 256, 0, stream>>>(xh, Dm, kmap, sel, 0);
  axis1_kernel<<<dim3(192, 32), 256, 0, stream>>>(xh, DT, nullptr, sel, 0);
  axis0_kernel<<<dim3(192, 32), 256, 0, stream>>>(xh, DT, sel, 0);
  // FFT branch (sel==1); b-axis FFT/IFFT cancels analytically; in-place (xh,Si)
  ffth_kernel<<<dim3(192, 32), 256, 0, stream>>>(xh, Si, E64, sel);
  fftw_kernel<<<dim3(384, 32), 256, 0, stream>>>(xh, Si, E64, sel, 1.f);
  fftc_fused_kernel<<<dim3(128, 32), 256, 0, stream>>>(xh, Si, kmap, sel);
  fftw_kernel<<<dim3(384, 32), 256, 0, stream>>>(xh, Si, E64, sel, -1.f);
  ffthi_kernel<<<dim3(384, 32), 256, 0, stream>>>(xh, Si, E64, sel);
  // Haar branch (sel==2), in-place on xh
  haar_kernel<<<dim3(128, 32), 256, 0, stream>>>(xh, kmap, sel);
  // epilogue
  final_kernel<<<2048, 256, 0, stream>>>(xh, zb, ws + W_LNG, ws + W_LNB,
                                         wT, ws + W_OUTB, d_out, flag);
}

// Round 4
// 1286.607 us; speedup vs baseline: 1.5517x; 1.0946x over previous
//
#include <hip/hip_runtime.h>
#include <hip/hip_bf16.h>
#include <math.h>

typedef __hip_bfloat16 bf16;
#define DEVI __device__ __forceinline__
static DEVI float b2f(bf16 v) { return __bfloat162float(v); }
static DEVI float scrub(float v) { return (v - v == 0.f) ? v : 0.f; }
static DEVI float bitsbf(unsigned short u) {
  union { unsigned int i; float f; } x; x.i = ((unsigned int)u) << 16; return x.f;
}
static DEVI short f2bs(float v) {
  bf16 h = __float2bfloat16(v); return *(short*)&h;
}

typedef __attribute__((ext_vector_type(8))) short short8v;   // 8 bf16 (4 VGPR)
typedef __attribute__((ext_vector_type(4))) float float4v;   // MFMA acc

constexpr int SLICE = 64 * 64 * 192;           // per-b elements = 786432

// ws layout (float offsets). Total 64,755,812 floats = 259,023,248 B (~247 MiB)
constexpr size_t O_XH   = 0;          // 25165824
constexpr size_t O_SI   = 25165824;   // 25165824 (imag buffer for FFT branch)
constexpr size_t O_ZB   = 50331648;   // bf16 z (25165824 elems = 12582912 slots)
constexpr size_t O_KMAP = 62914560;   // 786432
constexpr size_t O_FREQ = 63700992;   // 786432 (converted fp32 freq_embed)
constexpr size_t O_E64  = 64487424;   // 8192 (4096 float2)
constexpr size_t O_DM   = 64495616;   // 4096
constexpr size_t O_DT   = 64499712;   // 4096
constexpr size_t O_WT   = 64503808;   // 36864 (now: bf16 out_w, 36864 elems = 18432 slots)
constexpr size_t O_POOL = 64540672;   // 6144
constexpr size_t O_SEL  = 64546816;   // 32
constexpr size_t O_FLAG = 64546848;   // 32 (flag int + pad)
constexpr size_t O_W    = 64546880;   // 208932 packed fp32 weights
constexpr size_t WS_NEEDED_BYTES = (size_t)64755812 * 4;

// transient aliases inside O_SI (dead before ffth writes Si):
constexpr size_t O_YB   = O_SI;             // bf16 y, 25165824 elems (12582912 slots)
constexpr size_t O_PART = O_SI + 12600000;  // fp32 partial pooled [32][64][192] = 393216
constexpr size_t O_WB   = O_SI + 13100000;  // bf16 lin_w, 73728 elems (36864 slots)

// packed-weight offsets (relative to ws base)
constexpr size_t W_GN   = O_W + 0;      // 96
constexpr size_t W_DWW  = O_W + 96;     // 1728
constexpr size_t W_DWB  = O_W + 1824;   // 192
constexpr size_t W_LINW = O_W + 2016;   // 73728
constexpr size_t W_LINB = O_W + 75744;  // 384
constexpr size_t W_P1W  = O_W + 76128;  // 49152
constexpr size_t W_P1B  = O_W + 125280; // 256
constexpr size_t W_G1   = O_W + 125536; // 256
constexpr size_t W_B1   = O_W + 125792; // 256
constexpr size_t W_P2W  = O_W + 126048; // 8192
constexpr size_t W_P2B  = O_W + 134240; // 32
constexpr size_t W_G2   = O_W + 134272; // 32
constexpr size_t W_B2   = O_W + 134304; // 32
constexpr size_t W_P3W  = O_W + 134336; // 96
constexpr size_t W_P3B  = O_W + 134432; // 4 (3 used)
constexpr size_t W_TOKW = O_W + 134436; // 36864
constexpr size_t W_TOKB = O_W + 171300; // 192
constexpr size_t W_LNG  = O_W + 171492; // 192
constexpr size_t W_LNB  = O_W + 171684; // 192
constexpr size_t W_OUTW = O_W + 171876; // 36864
constexpr size_t W_OUTB = O_W + 208740; // 192

struct CvtArgs {
  const void* src[22];
  int n[22];
  long long off[22];   // float offset into ws
};

// ----------------------------------------------------------------------------
// dtype sniff: bf16 array -> ~64/64 sane uint16 exponents; fp32 -> ~40/64
// flag: 0 = bf16 inputs, 1 = fp32 inputs
// ----------------------------------------------------------------------------
__global__ void sniff_kernel(const unsigned short* xu, int* flag) {
  __shared__ int cnt;
  if (threadIdx.x == 0) cnt = 0;
  __syncthreads();
  unsigned short u = xu[threadIdx.x];
  int e = (u >> 7) & 0xFF;
  int sane = ((e >= 97 && e <= 160) || (u & 0x7FFF) == 0) ? 1 : 0;
  atomicAdd(&cnt, sane);
  __syncthreads();
  if (threadIdx.x == 0) *flag = (cnt >= 56) ? 0 : 1;
}

// convert all small inputs (+freq) to fp32 in ws, per flag
__global__ __launch_bounds__(256) void cvt_kernel(CvtArgs a, float* ws, const int* flag) {
  int flg = *flag;
  int gt = blockIdx.x * 256 + threadIdx.x;
  int gs = gridDim.x * 256;
  for (int s = 0; s < 22; ++s) {
    const void* sp = a.src[s];
    int n = a.n[s];
    float* dst = ws + a.off[s];
    if (flg) {
      const float* f = (const float*)sp;
      for (int i = gt; i < n; i += gs) dst[i] = f[i];
    } else {
      const bf16* h = (const bf16*)sp;
      for (int i = gt; i < n; i += gs) dst[i] = b2f(h[i]);
    }
  }
}

// fallback: zero-fill (2 bytes/elem, safe under both out dtypes)
__global__ __launch_bounds__(256) void fill_zero_kernel(unsigned short* out, int n) {
  int i = blockIdx.x * 256 + threadIdx.x;
  if (i < n) out[i] = 0;
}

// ----------------------------------------------------------------------------
// setup: DCT matrices, E64 twiddles, bf16 out_w copy, bf16 lin_w copy
// ----------------------------------------------------------------------------
__global__ __launch_bounds__(256) void setup_kernel(
    float* Dm, float* DT, float2* E64, bf16* Ob, const float* out_w,
    bf16* Wb, const float* lin_w)
{
  int t = blockIdx.x * 256 + threadIdx.x;
  int NTH = gridDim.x * 256;
  const double PI = 3.14159265358979323846;
  for (int i = t; i < 64 * 64; i += NTH) {
    int n = i >> 6, x = i & 63;
    double v = cos((double)n * (((double)x + 0.5) / 64.0) * PI) * sqrt(2.0 / 64.0);
    if (n == 0) v *= 0.70710678118654752440;
    Dm[n * 64 + x] = (float)v;
    DT[x * 64 + n] = (float)v;
  }
  for (int i = t; i < 64 * 64; i += NTH) {
    int k = i >> 6, n = i & 63;
    int m = (k * n) & 63;
    double th = -2.0 * PI * (double)m / 64.0;
    E64[i] = make_float2((float)cos(th), (float)sin(th));
  }
  for (int i = t; i < 192 * 192; i += NTH)
    Ob[i] = __float2bfloat16(out_w[i]);
  for (int i = t; i < 384 * 192; i += NTH)
    Wb[i] = __float2bfloat16(lin_w[i]);
}

// ----------------------------------------------------------------------------
// depthwise 3x3 conv (NCHW in, NHWC bf16 out), pad 1. grid (6,64,32)
// also emits fp32 partial pooled sums over w: partial[b][h][c]
// ----------------------------------------------------------------------------
__global__ __launch_bounds__(256) void conv_kernel(
    const void* xin, const int* flag, const float* dww, const float* dwb,
    bf16* out, float* partial)
{
  int flg = *flag;
  const float* xf = (const float*)xin;
  const bf16*  xb = (const bf16*)xin;
  int c0 = blockIdx.x * 32;
  int h  = blockIdx.y;
  int b  = blockIdx.z;
  __shared__ float in_s[3][32][66];
  __shared__ float wg[32][10];
  __shared__ float bias[32];
  __shared__ float psum[8][33];
  int t = threadIdx.x;
  for (int idx = t; idx < 3 * 32 * 66; idx += 256) {
    int r = idx / (32 * 66);
    int rem = idx - r * (32 * 66);
    int ci = rem / 66, wi = rem - ci * 66;
    int hh = h + r - 1, wwi = wi - 1;
    float v = 0.f;
    if (hh >= 0 && hh < 64 && wwi >= 0 && wwi < 64) {
      size_t ix = (((size_t)b * 192 + c0 + ci) * 64 + hh) * 64 + wwi;
      v = flg ? xf[ix] : b2f(xb[ix]);
    }
    in_s[r][ci][wi] = v;
  }
  for (int idx = t; idx < 32 * 9; idx += 256) {
    int ci = idx / 9;
    wg[ci][idx - ci * 9] = dww[(c0 + ci) * 9 + (idx - ci * 9)];
  }
  if (t < 32) bias[t] = dwb[c0 + t];
  __syncthreads();
  int cc = t & 31, wq = t >> 5;
  float ls = 0.f;
  for (int j = 0; j < 8; ++j) {
    int w = wq + 8 * j;
    float acc = bias[cc];
#pragma unroll
    for (int r = 0; r < 3; ++r)
#pragma unroll
      for (int kw = 0; kw < 3; ++kw)
        acc += in_s[r][cc][w + kw] * wg[cc][r * 3 + kw];
    out[(((size_t)b * 64 + h) * 64 + w) * 192 + c0 + cc] = __float2bfloat16(acc);
    ls += scrub(acc);
  }
  psum[wq][cc] = ls;
  __syncthreads();
  if (t < 32) {
    float s = 0.f;
    for (int r = 0; r < 8; ++r) s += psum[r][t];
    partial[((size_t)b * 64 + h) * 192 + c0 + t] = s;
  }
}

// ----------------------------------------------------------------------------
// linear via bf16 MFMA: y(131072x192 bf16) @ Wb^T (384x192 bf16) + lin_b
// -> xh (fp32, n<192) | zb (bf16, n>=192). grid (1024, 3).
// ----------------------------------------------------------------------------
__global__ __launch_bounds__(256) void linear_mfma_kernel(
    const bf16* Yb, const bf16* Wb, const float* bias, float* xh, bf16* zb)
{
  __shared__ __align__(16) short Asm[128 * 40];
  __shared__ __align__(16) short Bsm[128 * 40];
  int m0 = blockIdx.x * 128, n0 = blockIdx.y * 128;
  int t = threadIdx.x;
  int wave = t >> 6, lane = t & 63;
  int wm = (wave & 1) * 64, wn = (wave >> 1) * 64;
  int lq = lane >> 4, lr = lane & 15;
  float4v acc[4][4];
#pragma unroll
  for (int i = 0; i < 4; ++i)
#pragma unroll
    for (int j = 0; j < 4; ++j) acc[i][j] = (float4v){0.f, 0.f, 0.f, 0.f};

  for (int k0 = 0; k0 < 192; k0 += 32) {
#pragma unroll
    for (int i = 0; i < 4; ++i) {
      int ch = t + 256 * i;
      int isB = ch >> 9, c = ch & 511;
      int r = c >> 2, kc = c & 3;
      const bf16* src = isB ? (Wb + (size_t)(n0 + r) * 192 + k0 + kc * 8)
                            : (Yb + (size_t)(m0 + r) * 192 + k0 + kc * 8);
      float4 v = *(const float4*)src;
      short* dst = (isB ? Bsm : Asm) + r * 40 + kc * 8;
      *(float4*)dst = v;
    }
    __syncthreads();
    short8v af[4], bfr[4];
#pragma unroll
    for (int f = 0; f < 4; ++f) {
      af[f]  = *(const short8v*)&Asm[(wm + f * 16 + lr) * 40 + lq * 8];
      bfr[f] = *(const short8v*)&Bsm[(wn + f * 16 + lr) * 40 + lq * 8];
    }
#pragma unroll
    for (int fm = 0; fm < 4; ++fm)
#pragma unroll
      for (int fn = 0; fn < 4; ++fn)
        acc[fm][fn] = __builtin_amdgcn_mfma_f32_16x16x32_bf16(
            af[fm], bfr[fn], acc[fm][fn], 0, 0, 0);
    __syncthreads();
  }
#pragma unroll
  for (int fm = 0; fm < 4; ++fm)
#pragma unroll
    for (int e = 0; e < 4; ++e) {
      int m = m0 + wm + fm * 16 + lq * 4 + e;
#pragma unroll
      for (int fn = 0; fn < 4; ++fn) {
        int n = n0 + wn + fn * 16 + lr;
        float v = acc[fm][fn][e] + bias[n];
        if (n < 192) xh[(size_t)m * 192 + n] = v;
        else         zb[(size_t)m * 192 + (n - 192)] = __float2bfloat16(v);
      }
    }
}

// ----------------------------------------------------------------------------
// pooled = mean_hw(y) @ lin_w[0:192]^T + lin_b  (fp32-exact sel path)
// grid 12, block 256
// ----------------------------------------------------------------------------
__global__ __launch_bounds__(256) void pooled_kernel(
    const float* partial, const float* linW, const float* linB, float* pooled)
{
  __shared__ float pcs[32 * 193];
  int t = threadIdx.x;
  int c0 = blockIdx.x * 16;
  for (int i = t; i < 6144; i += 256) {
    int b = i / 192, c = i - b * 192;
    float s = 0.f;
    const float* p = partial + (size_t)b * 64 * 192 + c;
    for (int h = 0; h < 64; ++h) s += p[h * 192];
    pcs[b * 193 + c] = s;
  }
  __syncthreads();
  int c = c0 + (t & 15), bp = t >> 4;
#pragma unroll
  for (int half = 0; half < 2; ++half) {
    int b = bp + 16 * half;
    float a = 0.f;
    for (int k = 0; k < 192; ++k) a += pcs[b * 193 + k] * linW[(size_t)c * 192 + k];
    pooled[b * 192 + c] = linB[c] + a * (1.f / 4096.f);
  }
}

// ----------------------------------------------------------------------------
// kmap: e = relu(freq @ tok_w^T + tok_b); k = exp(-((pi i/64)^2+(pi j/64)^2)*e)
// grid (64, 3)
// ----------------------------------------------------------------------------
__global__ __launch_bounds__(256) void kmap_kernel(
    const float* A, const float* Wt, const float* bias, float* kout)
{
  __shared__ float As[32][65];
  __shared__ float Bs[32][65];
  int m0 = blockIdx.x * 64, n0 = blockIdx.y * 64;
  int t = threadIdx.x, tx = t & 15, ty = t >> 4;
  float acc[4][4] = {};
  for (int k0 = 0; k0 < 192; k0 += 32) {
    int kk = t & 31, mm = t >> 5;
#pragma unroll
    for (int i = 0; i < 8; ++i) {
      As[kk][mm + 8 * i] = A[(size_t)(m0 + mm + 8 * i) * 192 + k0 + kk];
      Bs[kk][mm + 8 * i] = Wt[(size_t)(n0 + mm + 8 * i) * 192 + k0 + kk];
    }
    __syncthreads();
    for (int k = 0; k < 32; ++k) {
      float a[4], bb[4];
#pragma unroll
      for (int i = 0; i < 4; ++i) a[i] = As[k][ty * 4 + i];
#pragma unroll
      for (int j = 0; j < 4; ++j) bb[j] = Bs[k][tx * 4 + j];
#pragma unroll
      for (int i = 0; i < 4; ++i)
#pragma unroll
        for (int j = 0; j < 4; ++j) acc[i][j] += a[i] * bb[j];
    }
    __syncthreads();
  }
  const float PI2 = 9.86960440108935862f;
  for (int i = 0; i < 4; ++i) {
    int m = m0 + ty * 4 + i;
    int ii = m >> 6, jj = m & 63;
    float d2 = (PI2 / 4096.f) * (float)(ii * ii + jj * jj);
    for (int j = 0; j < 4; ++j) {
      int n = n0 + tx * 4 + j;
      float e = acc[i][j] + bias[n];
      e = e > 0.f ? e : 0.f;
      kout[(size_t)m * 192 + n] = expf(-d2 * e);
    }
  }
}

// ----------------------------------------------------------------------------
// MLP + batchnorms + gumbel argmax -> sel[32] ; 1 block
// ----------------------------------------------------------------------------
__global__ __launch_bounds__(256) void mlp_kernel(
    const float* pooled, const float* gn,
    const float* p1w, const float* p1b, const float* g1, const float* b1,
    const float* p2w, const float* p2b, const float* g2, const float* b2,
    const float* p3w, const float* p3b, int* sel)
{
  __shared__ float pl[32 * 192];
  __shared__ float h1s[32 * 256];
  __shared__ float h2s[32 * 32];
  int t = threadIdx.x;
  for (int i = t; i < 32 * 192; i += 256) pl[i] = pooled[i];
  __syncthreads();
  {
    float acc[32];
    float bb = p1b[t];
#pragma unroll
    for (int b = 0; b < 32; ++b) acc[b] = bb;
    for (int c = 0; c < 192; ++c) {
      float w = p1w[t * 192 + c];
#pragma unroll
      for (int b = 0; b < 32; ++b) acc[b] += w * pl[b * 192 + c];
    }
    for (int b = 0; b < 32; ++b) {
      float v = acc[b];
      v = v > 0.f ? v : 0.1f * v;
      h1s[b * 256 + t] = v;
    }
  }
  __syncthreads();
  {
    float m = 0.f;
    for (int b = 0; b < 32; ++b) m += h1s[b * 256 + t];
    m *= (1.f / 32.f);
    float v = 0.f;
    for (int b = 0; b < 32; ++b) { float d = h1s[b * 256 + t] - m; v += d * d; }
    v *= (1.f / 32.f);
    float sc = g1[t] / sqrtf(v + 1e-5f);
    float sh = b1[t] - m * sc;
    for (int b = 0; b < 32; ++b) h1s[b * 256 + t] = h1s[b * 256 + t] * sc + sh;
  }
  __syncthreads();
  {
    int j = t & 31, bg = t >> 5;
    float acc[4];
    float bb = p2b[j];
    for (int i = 0; i < 4; ++i) acc[i] = bb;
    for (int c = 0; c < 256; ++c) {
      float w = p2w[j * 256 + c];
#pragma unroll
      for (int i = 0; i < 4; ++i) acc[i] += w * h1s[(bg * 4 + i) * 256 + c];
    }
    for (int i = 0; i < 4; ++i) {
      float v = acc[i];
      v = v > 0.f ? v : 0.1f * v;
      h2s[(bg * 4 + i) * 32 + j] = v;
    }
  }
  __syncthreads();
  if (t < 32) {
    float m = 0.f;
    for (int b = 0; b < 32; ++b) m += h2s[b * 32 + t];
    m *= (1.f / 32.f);
    float v = 0.f;
    for (int b = 0; b < 32; ++b) { float d = h2s[b * 32 + t] - m; v += d * d; }
    v *= (1.f / 32.f);
    float sc = g2[t] / sqrtf(v + 1e-5f);
    float sh = b2[t] - m * sc;
    for (int b = 0; b < 32; ++b) h2s[b * 32 + t] = h2s[b * 32 + t] * sc + sh;
  }
  __syncthreads();
  if (t < 32) {
    float best = -1e30f; int bi = 0;
    for (int r = 0; r < 3; ++r) {
      float l = p3b[r];
      for (int c = 0; c < 32; ++c) l += p3w[r * 32 + c] * h2s[t * 32 + c];
      l += gn[t * 3 + r];
      if (l > best) { best = l; bi = r; }
    }
    sel[t] = bi;
  }
}

// ----------------------------------------------------------------------------
// DCT stage over first axis of (64, 12288), in-place. grid (192, 32)
// ----------------------------------------------------------------------------
__global__ __launch_bounds__(256) void axis0_kernel(
    float* buf, const float* mat, const int* sel, int branch)
{
  int b = blockIdx.y;
  if (sel[b] != branch) return;
  int q0 = blockIdx.x * 64;
  __shared__ float mT[64][65];
  __shared__ float xs[64][65];
  int t = threadIdx.x;
  for (int i = t; i < 4096; i += 256) {
    int r = i >> 6, c = i & 63;
    mT[c][r] = mat[i];
    xs[r][c] = buf[(size_t)b * SLICE + r * 12288 + q0 + c];
  }
  __syncthreads();
  int tx = t & 15, ty = t >> 4;
  float acc[4][4] = {};
  for (int l = 0; l < 64; ++l) {
    float a[4], xv[4];
#pragma unroll
    for (int i = 0; i < 4; ++i) a[i] = mT[l][ty * 4 + i];
#pragma unroll
    for (int j = 0; j < 4; ++j) xv[j] = xs[l][tx * 4 + j];
#pragma unroll
    for (int i = 0; i < 4; ++i)
#pragma unroll
      for (int j = 0; j < 4; ++j) acc[i][j] += a[i] * xv[j];
  }
  float* ob = buf + (size_t)b * SLICE;
  for (int i = 0; i < 4; ++i)
    for (int j = 0; j < 4; ++j)
      ob[(ty * 4 + i) * 12288 + q0 + tx * 4 + j] = acc[i][j];
}

// DCT stage over middle axis, in-place, optional k multiply. grid (192, 32)
__global__ __launch_bounds__(256) void axis1_kernel(
    float* buf, const float* mat, const float* kmul, const int* sel, int branch)
{
  int b = blockIdx.y;
  if (sel[b] != branch) return;
  int n = blockIdx.x / 3;
  int ct = (blockIdx.x - n * 3) * 64;
  float* base = buf + (size_t)b * SLICE + n * (64 * 192) + ct;
  __shared__ float mT[64][65];
  __shared__ float xs[64][65];
  int t = threadIdx.x;
  for (int i = t; i < 4096; i += 256) {
    int r = i >> 6, c = i & 63;
    mT[c][r] = mat[i];
    xs[r][c] = base[r * 192 + c];
  }
  __syncthreads();
  int tx = t & 15, ty = t >> 4;
  float acc[4][4] = {};
  for (int l = 0; l < 64; ++l) {
    float a[4], xv[4];
#pragma unroll
    for (int i = 0; i < 4; ++i) a[i] = mT[l][ty * 4 + i];
#pragma unroll
    for (int j = 0; j < 4; ++j) xv[j] = xs[l][tx * 4 + j];
#pragma unroll
    for (int i = 0; i < 4; ++i)
#pragma unroll
      for (int j = 0; j < 4; ++j) acc[i][j] += a[i] * xv[j];
  }
  if (kmul) {
    for (int i = 0; i < 4; ++i)
      for (int j = 0; j < 4; ++j)
        acc[i][j] *= kmul[(size_t)(n * 64 + ty * 4 + i) * 192 + ct + tx * 4 + j];
  }
  for (int i = 0; i < 4; ++i)
    for (int j = 0; j < 4; ++j)
      base[(ty * 4 + i) * 192 + tx * 4 + j] = acc[i][j];
}

// ----------------------------------------------------------------------------
// FFT forward over h (real -> complex), real in-place into xh, imag -> Si
// ----------------------------------------------------------------------------
__global__ __launch_bounds__(256) void ffth_kernel(
    float* xh, float* Si, const float2* E64, const int* sel)
{
  int b = blockIdx.y;
  if (sel[b] != 1) return;
  int q0 = blockIdx.x * 64;
  __shared__ float er[64][65], ei[64][65], xs[64][65];
  int t = threadIdx.x;
  for (int i = t; i < 4096; i += 256) {
    int r = i >> 6, c = i & 63;
    float2 e = E64[i];
    er[r][c] = e.x; ei[r][c] = e.y;
    xs[r][c] = xh[(size_t)b * SLICE + r * 12288 + q0 + c];
  }
  __syncthreads();
  int tx = t & 15, ty = t >> 4;
  float ar[4][4] = {}, ai[4][4] = {};
  for (int l = 0; l < 64; ++l) {
    float e1[4], e2[4], xv[4];
#pragma unroll
    for (int i = 0; i < 4; ++i) { e1[i] = er[l][ty * 4 + i]; e2[i] = ei[l][ty * 4 + i]; }
#pragma unroll
    for (int j = 0; j < 4; ++j) xv[j] = xs[l][tx * 4 + j];
#pragma unroll
    for (int i = 0; i < 4; ++i)
#pragma unroll
      for (int j = 0; j < 4; ++j) { ar[i][j] += e1[i] * xv[j]; ai[i][j] += e2[i] * xv[j]; }
  }
  size_t ob = (size_t)b * SLICE;
  for (int i = 0; i < 4; ++i)
    for (int j = 0; j < 4; ++j) {
      size_t o = ob + (size_t)(ty * 4 + i) * 12288 + q0 + tx * 4 + j;
      xh[o] = ar[i][j];
      Si[o] = ai[i][j];
    }
}

// FFT over w (complex, in-place). grid (384, 32)
__global__ __launch_bounds__(256) void fftw_kernel(
    float* Sr, float* Si, const float2* E64, const int* sel, float s)
{
  int b = blockIdx.y;
  if (sel[b] != 1) return;
  int kh = blockIdx.x / 6;
  int ct = (blockIdx.x - kh * 6) * 32;
  float* br = Sr + (size_t)b * SLICE + kh * 12288 + ct;
  float* bi = Si + (size_t)b * SLICE + kh * 12288 + ct;
  __shared__ float er[64][65], ei[64][65];
  __shared__ float xr[64][33], xi[64][33];
  int t = threadIdx.x;
  for (int i = t; i < 4096; i += 256) {
    float2 e = E64[i];
    er[i >> 6][i & 63] = e.x;
    ei[i >> 6][i & 63] = s * e.y;
  }
  for (int i = t; i < 2048; i += 256) {
    int l = i >> 5, q = i & 31;
    xr[l][q] = br[l * 192 + q];
    xi[l][q] = bi[l * 192 + q];
  }
  __syncthreads();
  int tx = t & 7, ty = t >> 3;
  float ar[2][4] = {}, ac[2][4] = {};
  for (int l = 0; l < 64; ++l) {
    float e1a = er[l][ty],      e2a = ei[l][ty];
    float e1b = er[l][ty + 32], e2b = ei[l][ty + 32];
#pragma unroll
    for (int j = 0; j < 4; ++j) {
      float vr = xr[l][tx * 4 + j], vi = xi[l][tx * 4 + j];
      ar[0][j] += e1a * vr - e2a * vi;
      ac[0][j] += e1a * vi + e2a * vr;
      ar[1][j] += e1b * vr - e2b * vi;
      ac[1][j] += e1b * vi + e2b * vr;
    }
  }
  for (int r = 0; r < 2; ++r) {
    int kw = ty + r * 32;
    for (int j = 0; j < 4; ++j) {
      br[kw * 192 + tx * 4 + j] = ar[r][j];
      bi[kw * 192 + tx * 4 + j] = ac[r][j];
    }
  }
}

// ----------------------------------------------------------------------------
// Fused c-stage via Cooley-Tukey 3x64 (see r1 notes). grid (128, 32).
// ----------------------------------------------------------------------------
__global__ __launch_bounds__(256, 3) void fftc_fused_kernel(
    float* Sr, float* Si, const float* kmap, const int* sel)
{
  int b = blockIdx.y;
  if (sel[b] != 1) return;
  int m0 = blockIdx.x * 32;
  float* gr = Sr + (size_t)b * SLICE + (size_t)m0 * 192;
  float* gi = Si + (size_t)b * SLICE + (size_t)m0 * 192;
  __shared__ __align__(16) float2 T[192][34];
  int t = threadIdx.x;
  for (int i = t; i < 6144; i += 256) {
    int row = i / 192, c = i - row * 192;
    T[c][row] = make_float2(gr[i], gi[i]);
  }
  int tx = t & 31, ty = t >> 5;
  int rbase = ty * 4;
  double A = 2.0 * 3.14159265358979323846 * (double)tx;
  double sa, ca, sb, cb;
  sincos(A / 64.0, &sa, &ca);
  sincos(A / 192.0, &sb, &cb);
  float c64 = (float)ca, s64 = (float)sa;
  float cw = (float)cb, sw = (float)sb;
  const float S3 = 0.86602540378443864676f;
  float fsr[2], fsi[2];
  fsr[0] = c64;  fsi[0] = -s64;
  fsr[1] = -c64; fsi[1] = s64;
  float w1r[2], w1i[2], w2r[2], w2i[2];
  w1r[0] = cw;                   w1i[0] = -sw;
  w1r[1] = 0.5f * cw - S3 * sw;  w1i[1] = -S3 * cw - 0.5f * sw;
#pragma unroll
  for (int u = 0; u < 2; ++u) {
    w2r[u] = w1r[u] * w1r[u] - w1i[u] * w1i[u];
    w2i[u] = 2.f * w1r[u] * w1i[u];
  }
  __syncthreads();
  float ar[2][3][4], ai[2][3][4];
#pragma unroll
  for (int u = 0; u < 2; ++u)
#pragma unroll
    for (int n1 = 0; n1 < 3; ++n1)
#pragma unroll
      for (int r = 0; r < 4; ++r) { ar[u][n1][r] = 0.f; ai[u][n1][r] = 0.f; }
  {
    float pr[2], pq[2];
    pr[0] = 1.f; pr[1] = 1.f; pq[0] = 0.f; pq[1] = 0.f;
    for (int n2 = 0; n2 < 64; ++n2) {
      const float4* p0 = (const float4*)&T[3 * n2][rbase];
      const float4* p1 = (const float4*)&T[3 * n2 + 1][rbase];
      const float4* p2 = (const float4*)&T[3 * n2 + 2][rbase];
      float4 q00 = p0[0], q01 = p0[1];
      float4 q10 = p1[0], q11 = p1[1];
      float4 q20 = p2[0], q21 = p2[1];
      float xr[3][4], xi[3][4];
      xr[0][0] = q00.x; xi[0][0] = q00.y; xr[0][1] = q00.z; xi[0][1] = q00.w;
      xr[0][2] = q01.x; xi[0][2] = q01.y; xr[0][3] = q01.z; xi[0][3] = q01.w;
      xr[1][0] = q10.x; xi[1][0] = q10.y; xr[1][1] = q10.z; xi[1][1] = q10.w;
      xr[1][2] = q11.x; xi[1][2] = q11.y; xr[1][3] = q11.z; xi[1][3] = q11.w;
      xr[2][0] = q20.x; xi[2][0] = q20.y; xr[2][1] = q20.z; xi[2][1] = q20.w;
      xr[2][2] = q21.x; xi[2][2] = q21.y; xr[2][3] = q21.z; xi[2][3] = q21.w;
#pragma unroll
      for (int u = 0; u < 2; ++u) {
        float er = pr[u], ei = pq[u];
#pragma unroll
        for (int n1 = 0; n1 < 3; ++n1)
#pragma unroll
          for (int r = 0; r < 4; ++r) {
            ar[u][n1][r] += xr[n1][r] * er - xi[n1][r] * ei;
            ai[u][n1][r] += xr[n1][r] * ei + xi[n1][r] * er;
          }
        float nr = er * fsr[u] - ei * fsi[u];
        pq[u] = er * fsi[u] + ei * fsr[u];
        pr[u] = nr;
      }
    }
  }
  const float SCALE = 1.0f / 786432.0f;
#pragma unroll
  for (int u = 0; u < 2; ++u) {
    int m = tx + 32 * u;
#pragma unroll
    for (int r = 0; r < 4; ++r) {
      int row = rbase + r;
      float Y0r = ar[u][0][r], Y0i = ai[u][0][r];
      float Y1r = ar[u][1][r], Y1i = ai[u][1][r];
      float Y2r = ar[u][2][r], Y2i = ai[u][2][r];
      float T1r = Y1r * w1r[u] - Y1i * w1i[u];
      float T1i = Y1r * w1i[u] + Y1i * w1r[u];
      float T2r = Y2r * w2r[u] - Y2i * w2i[u];
      float T2i = Y2r * w2i[u] + Y2i * w2r[u];
      float aRr = T1r + T2r, aRi = T1i + T2i;
      float bRr = T1r - T2r, bRi = T1i - T2i;
      float X0r = Y0r + aRr, X0i = Y0i + aRi;
      float cfr = Y0r - 0.5f * aRr, cfi = Y0i - 0.5f * aRi;
      float X1r = cfr + S3 * bRi, X1i = cfi - S3 * bRr;
      float X2r = cfr - S3 * bRi, X2i = cfi + S3 * bRr;
      const float* kp = kmap + (size_t)(m0 + row) * 192 + m;
      float k0 = kp[0] * SCALE, k1 = kp[64] * SCALE, k2 = kp[128] * SCALE;
      X0r *= k0; X0i *= k0; X1r *= k1; X1i *= k1; X2r *= k2; X2i *= k2;
      float a2r = X1r + X2r, a2i = X1i + X2i;
      float b2r = X1r - X2r, b2i = X1i - X2i;
      float U0r = X0r + a2r, U0i = X0i + a2i;
      float c2r = X0r - 0.5f * a2r, c2i = X0i - 0.5f * a2i;
      float U1r = c2r - S3 * b2i, U1i = c2i + S3 * b2r;
      float U2r = c2r + S3 * b2i, U2i = c2i - S3 * b2r;
      ar[u][0][r] = U0r;
      ai[u][0][r] = U0i;
      ar[u][1][r] = U1r * w1r[u] + U1i * w1i[u];
      ai[u][1][r] = U1i * w1r[u] - U1r * w1i[u];
      ar[u][2][r] = U2r * w2r[u] + U2i * w2i[u];
      ai[u][2][r] = U2i * w2r[u] - U2r * w2i[u];
    }
  }
  __syncthreads();
#pragma unroll
  for (int u = 0; u < 2; ++u)
#pragma unroll
    for (int n1 = 0; n1 < 3; ++n1)
#pragma unroll
      for (int r = 0; r < 4; ++r)
        T[n1 * 64 + tx + 32 * u][rbase + r] =
            make_float2(ar[u][n1][r], ai[u][n1][r]);
  __syncthreads();
  float qr_[2][3][4], qi_[2][3][4];
#pragma unroll
  for (int u = 0; u < 2; ++u)
#pragma unroll
    for (int n1 = 0; n1 < 3; ++n1)
#pragma unroll
      for (int r = 0; r < 4; ++r) { qr_[u][n1][r] = 0.f; qi_[u][n1][r] = 0.f; }
  {
    float isr[2], isi[2];
    isr[0] = c64;  isi[0] = s64;
    isr[1] = -c64; isi[1] = -s64;
    float pr[2], pq[2];
    pr[0] = 1.f; pr[1] = 1.f; pq[0] = 0.f; pq[1] = 0.f;
    for (int ms = 0; ms < 64; ++ms) {
      const float4* p0 = (const float4*)&T[ms][rbase];
      const float4* p1 = (const float4*)&T[64 + ms][rbase];
      const float4* p2 = (const float4*)&T[128 + ms][rbase];
      float4 q00 = p0[0], q01 = p0[1];
      float4 q10 = p1[0], q11 = p1[1];
      float4 q20 = p2[0], q21 = p2[1];
      float xr[3][4], xi[3][4];
      xr[0][0] = q00.x; xi[0][0] = q00.y; xr[0][1] = q00.z; xi[0][1] = q00.w;
      xr[0][2] = q01.x; xi[0][2] = q01.y; xr[0][3] = q01.z; xi[0][3] = q01.w;
      xr[1][0] = q10.x; xi[1][0] = q10.y; xr[1][1] = q10.z; xi[1][1] = q10.w;
      xr[1][2] = q11.x; xi[1][2] = q11.y; xr[1][3] = q11.z; xi[1][3] = q11.w;
      xr[2][0] = q20.x; xi[2][0] = q20.y; xr[2][1] = q20.z; xi[2][1] = q20.w;
      xr[2][2] = q21.x; xi[2][2] = q21.y; xr[2][3] = q21.z; xi[2][3] = q21.w;
#pragma unroll
      for (int u = 0; u < 2; ++u) {
        float er = pr[u], ei = pq[u];
#pragma unroll
        for (int n1 = 0; n1 < 3; ++n1)
#pragma unroll
          for (int r = 0; r < 4; ++r) {
            qr_[u][n1][r] += xr[n1][r] * er - xi[n1][r] * ei;
            qi_[u][n1][r] += xr[n1][r] * ei + xi[n1][r] * er;
          }
        float nr = er * isr[u] - ei * isi[u];
        pq[u] = er * isi[u] + ei * isr[u];
        pr[u] = nr;
      }
    }
  }
#pragma unroll
  for (int r = 0; r < 4; ++r) {
    int row = rbase + r;
#pragma unroll
    for (int u = 0; u < 2; ++u) {
      int c0 = 3 * (tx + 32 * u);
#pragma unroll
      for (int n1 = 0; n1 < 3; ++n1) {
        gr[(size_t)row * 192 + c0 + n1] = qr_[u][n1][r];
        gi[(size_t)row * 192 + c0 + n1] = qi_[u][n1][r];
      }
    }
  }
}

// inverse h-stage, real part only, in-place into xh. grid (384, 32)
__global__ __launch_bounds__(256) void ffthi_kernel(
    float* Sr, const float* Si, const float2* E64, const int* sel)
{
  int b = blockIdx.y;
  if (sel[b] != 1) return;
  int q0 = blockIdx.x * 32;
  __shared__ float er[64][65], ei[64][65];
  __shared__ float xr[64][33], xi[64][33];
  int t = threadIdx.x;
  for (int i = t; i < 4096; i += 256) {
    float2 e = E64[i];
    er[i >> 6][i & 63] = e.x;
    ei[i >> 6][i & 63] = e.y;
  }
  for (int i = t; i < 2048; i += 256) {
    int l = i >> 5, q = i & 31;
    size_t o = (size_t)b * SLICE + (size_t)l * 12288 + q0 + q;
    xr[l][q] = Sr[o];
    xi[l][q] = Si[o];
  }
  __syncthreads();
  int tx = t & 7, ty = t >> 3;
  float acc[2][4] = {};
  for (int l = 0; l < 64; ++l) {
    float e1a = er[l][ty],      e2a = ei[l][ty];
    float e1b = er[l][ty + 32], e2b = ei[l][ty + 32];
#pragma unroll
    for (int j = 0; j < 4; ++j) {
      float vr = xr[l][tx * 4 + j], vi = xi[l][tx * 4 + j];
      acc[0][j] += e1a * vr + e2a * vi;
      acc[1][j] += e1b * vr + e2b * vi;
    }
  }
  for (int r = 0; r < 2; ++r) {
    int h = ty + r * 32;
    for (int j = 0; j < 4; ++j)
      Sr[(size_t)b * SLICE + (size_t)h * 12288 + q0 + tx * 4 + j] = acc[r][j];
  }
}

// ----------------------------------------------------------------------------
// Haar branch, in-place on xh. grid (128, 32)
// ----------------------------------------------------------------------------
__global__ __launch_bounds__(256) void haar_kernel(
    float* xh, const float* kmap, const int* sel)
{
  int b = blockIdx.y;
  if (sel[b] != 2) return;
  int h = blockIdx.x >> 1;
  int w0 = (blockIdx.x & 1) * 32;
  size_t base = (size_t)b * SLICE + ((size_t)h * 64 + w0) * 192;
  __shared__ float A[32 * 192];
  __shared__ float Bf[32 * 192];
  int t = threadIdx.x;
  for (int i = t; i < 6144; i += 256) A[i] = xh[base + i];
  __syncthreads();
  for (int u = t; u < 32 * 96; u += 256) {
    int p = u / 96, r = u - p * 96;
    int ch = r >> 5, i = r & 31;
    float v0 = A[p * 192 + ch * 64 + 2 * i];
    float v1 = A[p * 192 + ch * 64 + 2 * i + 1];
    Bf[p * 192 + ch * 64 + i]      = (v0 + v1) * 0.5f;
    Bf[p * 192 + ch * 64 + 32 + i] = (v0 - v1) * 0.5f;
  }
  __syncthreads();
  for (int u = t; u < 32 * 96; u += 256) {
    int p = u / 96, i = u - p * 96;
    float v0 = Bf[p * 192 + 2 * i];
    float v1 = Bf[p * 192 + 2 * i + 1];
    A[p * 192 + i]      = (v0 + v1) * 0.5f;
    A[p * 192 + 96 + i] = (v0 - v1) * 0.5f;
  }
  __syncthreads();
  for (int i = t; i < 6144; i += 256)
    A[i] *= kmap[((size_t)h * 64 + w0) * 192 + i];
  __syncthreads();
  for (int u = t; u < 32 * 96; u += 256) {
    int p = u / 96, r = u - p * 96;
    int ch = r >> 5, i = r & 31;
    float a = A[p * 192 + ch * 64 + i];
    float d = A[p * 192 + ch * 64 + 32 + i];
    Bf[p * 192 + ch * 64 + 2 * i]     = a + d;
    Bf[p * 192 + ch * 64 + 2 * i + 1] = a - d;
  }
  __syncthreads();
  for (int u = t; u < 32 * 96; u += 256) {
    int p = u / 96, i = u - p * 96;
    float a = Bf[p * 192 + i];
    float d = Bf[p * 192 + 96 + i];
    A[p * 192 + 2 * i]     = a + d;
    A[p * 192 + 2 * i + 1] = a - d;
  }
  __syncthreads();
  for (int i = t; i < 6144; i += 256) xh[base + i] = A[i];
}

// ----------------------------------------------------------------------------
// final: LN(c) * silu(z) @ out_w^T + out_b via bf16 MFMA, dual-dtype store.
// grid 2048. Per block: 64 spatial rows x 192 ch. 4 waves, wave tile 64x48.
// LDS: As fp32 (staging [64][196] then D [192][66]) + Ab bf16 [64][200].
// ----------------------------------------------------------------------------
__global__ __launch_bounds__(256) void final_kernel(
    const float* comb, const bf16* zb, const float* lng, const float* lnb,
    const bf16* Ob, const float* outb, void* outp, const int* flag)
{
  int flg = *flag;
  int bi = blockIdx.x;
  int b = bi >> 6, h = bi & 63;
  size_t base = ((size_t)b * 4096 + (size_t)h * 64) * 192;
  __shared__ float As[12672];                  // max(64*196, 192*66)
  __shared__ __align__(16) short Ab[64 * 200];
  __shared__ float red[2][4][64];
  __shared__ float mu[64], rs[64];
  int t = threadIdx.x;
  // stage comb -> As[p*196+c] (float4, scrubbed)
  for (int idx = t; idx < 3072; idx += 256) {
    int q = idx << 2;
    int p = idx / 48, c = q - p * 192;
    float4 v = *(const float4*)&comb[base + q];
    v.x = scrub(v.x); v.y = scrub(v.y); v.z = scrub(v.z); v.w = scrub(v.w);
    *(float4*)&As[p * 196 + c] = v;
  }
  __syncthreads();
  // LN stats: 4 threads per row, single-pass sum/sumsq
  {
    int r = t & 63, part = t >> 6;
    const float* row = &As[r * 196 + part * 48];
    float s = 0.f, s2 = 0.f;
    for (int c = 0; c < 48; ++c) { float v = row[c]; s += v; s2 += v * v; }
    red[0][part][r] = s;
    red[1][part][r] = s2;
  }
  __syncthreads();
  if (t < 64) {
    float s  = red[0][0][t] + red[0][1][t] + red[0][2][t] + red[0][3][t];
    float s2 = red[1][0][t] + red[1][1][t] + red[1][2][t] + red[1][3][t];
    float m = s * (1.f / 192.f);
    float v = s2 * (1.f / 192.f) - m * m;
    v = v > 0.f ? v : 0.f;
    mu[t] = m;
    rs[t] = 1.f / sqrtf(v + 1e-5f);
  }
  __syncthreads();
  // LN * silu(z) -> bf16 Ab[p*200+c] (8 elems/iter)
  for (int idx = t; idx < 1536; idx += 256) {
    int q = idx << 3;
    int p = idx / 24, c = q - p * 192;
    float4 a0 = *(const float4*)&As[p * 196 + c];
    float4 a1 = *(const float4*)&As[p * 196 + c + 4];
    short8v z8 = *(const short8v*)&zb[base + q];
    float av[8] = {a0.x, a0.y, a0.z, a0.w, a1.x, a1.y, a1.z, a1.w};
    short o8[8];
    float m = mu[p], r = rs[p];
#pragma unroll
    for (int j = 0; j < 8; ++j) {
      float v = (av[j] - m) * r * lng[c + j] + lnb[c + j];
      float zv = scrub(bitsbf((unsigned short)z8[j]));
      v *= zv / (1.f + expf(-zv));
      o8[j] = f2bs(v);
    }
    *(short8v*)&Ab[p * 200 + c] = *(short8v*)o8;
  }
  __syncthreads();
  // MFMA: wave w -> co range [w*48, w*48+48)
  int wave = t >> 6, lane = t & 63;
  int lq = lane >> 4, lr = lane & 15;
  int n0 = wave * 48;
  float4v acc[4][3];
#pragma unroll
  for (int i = 0; i < 4; ++i)
#pragma unroll
    for (int j = 0; j < 3; ++j) acc[i][j] = (float4v){0.f, 0.f, 0.f, 0.f};
  for (int k0 = 0; k0 < 192; k0 += 32) {
    short8v af[4], bfr[3];
#pragma unroll
    for (int f = 0; f < 4; ++f)
      af[f] = *(const short8v*)&Ab[(f * 16 + lr) * 200 + k0 + lq * 8];
#pragma unroll
    for (int f = 0; f < 3; ++f)
      bfr[f] = *(const short8v*)&Ob[(size_t)(n0 + f * 16 + lr) * 192 + k0 + lq * 8];
#pragma unroll
    for (int fm = 0; fm < 4; ++fm)
#pragma unroll
      for (int fn = 0; fn < 3; ++fn)
        acc[fm][fn] = __builtin_amdgcn_mfma_f32_16x16x32_bf16(
            af[fm], bfr[fn], acc[fm][fn], 0, 0, 0);
  }
  __syncthreads();   // As staging reads done; safe to overwrite with D
#pragma unroll
  for (int fm = 0; fm < 4; ++fm)
#pragma unroll
    for (int e = 0; e < 4; ++e) {
      int p = fm * 16 + lq * 4 + e;
#pragma unroll
      for (int fn = 0; fn < 3; ++fn) {
        int co = n0 + fn * 16 + lr;
        As[co * 66 + p] = acc[fm][fn][e] + outb[co];
      }
    }
  __syncthreads();
  for (int e = t; e < 12288; e += 256) {
    int co = e >> 6, w = e & 63;
    size_t oi = (((size_t)b * 192 + co) * 64 + h) * 64 + w;
    float v = As[co * 66 + w];
    if (flg) ((float*)outp)[oi] = v;
    else     ((bf16*)outp)[oi] = __float2bfloat16(v);
  }
}

// ----------------------------------------------------------------------------
extern "C" void kernel_launch(void* const* d_in, const int* in_sizes, int n_in,
                              void* d_out, int out_size, void* d_ws, size_t ws_size,
                              hipStream_t stream) {
  (void)in_sizes; (void)n_in;
  if (ws_size < WS_NEEDED_BYTES) {
    fill_zero_kernel<<<(out_size + 255) / 256, 256, 0, stream>>>(
        (unsigned short*)d_out, out_size);
    return;
  }
  float* ws    = (float*)d_ws;
  float* xh    = ws + O_XH;
  float* Si    = ws + O_SI;
  bf16*  Yb    = (bf16*)(ws + O_YB);
  float* part  = ws + O_PART;
  bf16*  Wb    = (bf16*)(ws + O_WB);
  bf16*  zb    = (bf16*)(ws + O_ZB);
  float* kmap  = ws + O_KMAP;
  float2* E64  = (float2*)(ws + O_E64);
  float* Dm    = ws + O_DM;
  float* DT    = ws + O_DT;
  bf16*  Ob    = (bf16*)(ws + O_WT);
  float* pooled= ws + O_POOL;
  int*   sel   = (int*)(ws + O_SEL);
  int*   flag  = (int*)(ws + O_FLAG);

  sniff_kernel<<<1, 64, 0, stream>>>((const unsigned short*)d_in[0], flag);

  CvtArgs ca;
  const int srcidx[22] = {2,3,4,5,6,7,8,9,10,11,12,13,14,15,16,17,18,19,20,21,22,1};
  const int ns[22] = {96,1728,192,73728,384,49152,256,256,256,8192,32,32,32,96,3,
                      36864,192,192,192,36864,192,786432};
  const long long offs[22] = {
    (long long)W_GN,(long long)W_DWW,(long long)W_DWB,(long long)W_LINW,
    (long long)W_LINB,(long long)W_P1W,(long long)W_P1B,(long long)W_G1,
    (long long)W_B1,(long long)W_P2W,(long long)W_P2B,(long long)W_G2,
    (long long)W_B2,(long long)W_P3W,(long long)W_P3B,(long long)W_TOKW,
    (long long)W_TOKB,(long long)W_LNG,(long long)W_LNB,(long long)W_OUTW,
    (long long)W_OUTB,(long long)O_FREQ};
  for (int i = 0; i < 22; ++i) { ca.src[i] = d_in[srcidx[i]]; ca.n[i] = ns[i]; ca.off[i] = offs[i]; }
  cvt_kernel<<<64, 256, 0, stream>>>(ca, ws, flag);

  setup_kernel<<<64, 256, 0, stream>>>(Dm, DT, E64, Ob, ws + W_OUTW, Wb, ws + W_LINW);
  conv_kernel<<<dim3(6, 64, 32), 256, 0, stream>>>(d_in[0], flag, ws + W_DWW, ws + W_DWB,
                                                   Yb, part);
  linear_mfma_kernel<<<dim3(1024, 3), 256, 0, stream>>>(Yb, Wb, ws + W_LINB, xh, zb);
  pooled_kernel<<<12, 256, 0, stream>>>(part, ws + W_LINW, ws + W_LINB, pooled);
  mlp_kernel<<<1, 256, 0, stream>>>(pooled, ws + W_GN,
      ws + W_P1W, ws + W_P1B, ws + W_G1, ws + W_B1,
      ws + W_P2W, ws + W_P2B, ws + W_G2, ws + W_B2,
      ws + W_P3W, ws + W_P3B, sel);
  kmap_kernel<<<dim3(64, 3), 256, 0, stream>>>(ws + O_FREQ, ws + W_TOKW, ws + W_TOKB, kmap);
  // DCT branch (sel==0), in-place on xh
  axis0_kernel<<<dim3(192, 32), 256, 0, stream>>>(xh, Dm, sel, 0);
  axis1_kernel<<<dim3(192, 32), 256, 0, stream>>>(xh, Dm, kmap, sel, 0);
  axis1_kernel<<<dim3(192, 32), 256, 0, stream>>>(xh, DT, nullptr, sel, 0);
  axis0_kernel<<<dim3(192, 32), 256, 0, stream>>>(xh, DT, sel, 0);
  // FFT branch (sel==1); b-axis FFT/IFFT cancels analytically; in-place (xh,Si)
  ffth_kernel<<<dim3(192, 32), 256, 0, stream>>>(xh, Si, E64, sel);
  fftw_kernel<<<dim3(384, 32), 256, 0, stream>>>(xh, Si, E64, sel, 1.f);
  fftc_fused_kernel<<<dim3(128, 32), 256, 0, stream>>>(xh, Si, kmap, sel);
  fftw_kernel<<<dim3(384, 32), 256, 0, stream>>>(xh, Si, E64, sel, -1.f);
  ffthi_kernel<<<dim3(384, 32), 256, 0, stream>>>(xh, Si, E64, sel);
  // Haar branch (sel==2), in-place on xh
  haar_kernel<<<dim3(128, 32), 256, 0, stream>>>(xh, kmap, sel);
  // epilogue
  final_kernel<<<2048, 256, 0, stream>>>(xh, zb, ws + W_LNG, ws + W_LNB,
                                         Ob, ws + W_OUTB, d_out, flag);
}

// Round 5
// 1114.974 us; speedup vs baseline: 1.7906x; 1.1539x over previous
//
#include <hip/hip_runtime.h>
#include <hip/hip_bf16.h>
#include <math.h>

typedef __hip_bfloat16 bf16;
#define DEVI __device__ __forceinline__
static DEVI float b2f(bf16 v) { return __bfloat162float(v); }
static DEVI float scrub(float v) { return (v - v == 0.f) ? v : 0.f; }
static DEVI float bitsbf(unsigned short u) {
  union { unsigned int i; float f; } x; x.i = ((unsigned int)u) << 16; return x.f;
}
static DEVI short f2bs(float v) {
  bf16 h = __float2bfloat16(v); return *(short*)&h;
}

typedef __attribute__((ext_vector_type(8))) short short8v;   // 8 bf16 (4 VGPR)
typedef __attribute__((ext_vector_type(4))) float float4v;   // MFMA acc

constexpr int SLICE = 64 * 64 * 192;           // per-b elements = 786432

// ws layout (float offsets). Total 64,755,812 floats = 259,023,248 B (~247 MiB)
constexpr size_t O_XH   = 0;          // 25165824
constexpr size_t O_SI   = 25165824;   // 25165824 (imag buffer for FFT branch)
constexpr size_t O_ZB   = 50331648;   // bf16 z (25165824 elems = 12582912 slots)
constexpr size_t O_KMAP = 62914560;   // 786432
constexpr size_t O_FREQ = 63700992;   // 786432 (converted fp32 freq_embed)
constexpr size_t O_E64  = 64487424;   // 8192 (4096 float2)
constexpr size_t O_DM   = 64495616;   // 4096
constexpr size_t O_DT   = 64499712;   // 4096
constexpr size_t O_WT   = 64503808;   // 36864 (bf16 out_w, 36864 elems = 18432 slots)
constexpr size_t O_POOL = 64540672;   // 6144
constexpr size_t O_SEL  = 64546816;   // 32
constexpr size_t O_FLAG = 64546848;   // 32 (flag int + pad)
constexpr size_t O_W    = 64546880;   // 208932 packed fp32 weights
constexpr size_t WS_NEEDED_BYTES = (size_t)64755812 * 4;

// transient aliases inside O_SI (dead before ffth writes Si):
constexpr size_t O_YB   = O_SI;             // bf16 y, 25165824 elems (12582912 slots)
constexpr size_t O_PART = O_SI + 12600000;  // fp32 partial pooled [32][64][192] = 393216
constexpr size_t O_WB   = O_SI + 13100000;  // bf16 lin_w, 73728 elems (36864 slots)

// packed-weight offsets (relative to ws base)
constexpr size_t W_GN   = O_W + 0;      // 96
constexpr size_t W_DWW  = O_W + 96;     // 1728
constexpr size_t W_DWB  = O_W + 1824;   // 192
constexpr size_t W_LINW = O_W + 2016;   // 73728
constexpr size_t W_LINB = O_W + 75744;  // 384
constexpr size_t W_P1W  = O_W + 76128;  // 49152
constexpr size_t W_P1B  = O_W + 125280; // 256
constexpr size_t W_G1   = O_W + 125536; // 256
constexpr size_t W_B1   = O_W + 125792; // 256
constexpr size_t W_P2W  = O_W + 126048; // 8192
constexpr size_t W_P2B  = O_W + 134240; // 32
constexpr size_t W_G2   = O_W + 134272; // 32
constexpr size_t W_B2   = O_W + 134304; // 32
constexpr size_t W_P3W  = O_W + 134336; // 96
constexpr size_t W_P3B  = O_W + 134432; // 4 (3 used)
constexpr size_t W_TOKW = O_W + 134436; // 36864
constexpr size_t W_TOKB = O_W + 171300; // 192
constexpr size_t W_LNG  = O_W + 171492; // 192
constexpr size_t W_LNB  = O_W + 171684; // 192
constexpr size_t W_OUTW = O_W + 171876; // 36864
constexpr size_t W_OUTB = O_W + 208740; // 192

struct CvtArgs {
  const void* src[22];
  int n[22];
  long long off[22];   // float offset into ws
};

// ----------------------------------------------------------------------------
// dtype sniff
// ----------------------------------------------------------------------------
__global__ void sniff_kernel(const unsigned short* xu, int* flag) {
  __shared__ int cnt;
  if (threadIdx.x == 0) cnt = 0;
  __syncthreads();
  unsigned short u = xu[threadIdx.x];
  int e = (u >> 7) & 0xFF;
  int sane = ((e >= 97 && e <= 160) || (u & 0x7FFF) == 0) ? 1 : 0;
  atomicAdd(&cnt, sane);
  __syncthreads();
  if (threadIdx.x == 0) *flag = (cnt >= 56) ? 0 : 1;
}

// convert all small inputs (+freq) to fp32 in ws, per flag
__global__ __launch_bounds__(256) void cvt_kernel(CvtArgs a, float* ws, const int* flag) {
  int flg = *flag;
  int gt = blockIdx.x * 256 + threadIdx.x;
  int gs = gridDim.x * 256;
  for (int s = 0; s < 22; ++s) {
    const void* sp = a.src[s];
    int n = a.n[s];
    float* dst = ws + a.off[s];
    if (flg) {
      const float* f = (const float*)sp;
      for (int i = gt; i < n; i += gs) dst[i] = f[i];
    } else {
      const bf16* h = (const bf16*)sp;
      for (int i = gt; i < n; i += gs) dst[i] = b2f(h[i]);
    }
  }
}

// fallback: zero-fill
__global__ __launch_bounds__(256) void fill_zero_kernel(unsigned short* out, int n) {
  int i = blockIdx.x * 256 + threadIdx.x;
  if (i < n) out[i] = 0;
}

// ----------------------------------------------------------------------------
// setup: DCT matrices, E64 twiddles, bf16 out_w copy, bf16 lin_w copy
// ----------------------------------------------------------------------------
__global__ __launch_bounds__(256) void setup_kernel(
    float* Dm, float* DT, float2* E64, bf16* Ob, const float* out_w,
    bf16* Wb, const float* lin_w)
{
  int t = blockIdx.x * 256 + threadIdx.x;
  int NTH = gridDim.x * 256;
  const double PI = 3.14159265358979323846;
  for (int i = t; i < 64 * 64; i += NTH) {
    int n = i >> 6, x = i & 63;
    double v = cos((double)n * (((double)x + 0.5) / 64.0) * PI) * sqrt(2.0 / 64.0);
    if (n == 0) v *= 0.70710678118654752440;
    Dm[n * 64 + x] = (float)v;
    DT[x * 64 + n] = (float)v;
  }
  for (int i = t; i < 64 * 64; i += NTH) {
    int k = i >> 6, n = i & 63;
    int m = (k * n) & 63;
    double th = -2.0 * PI * (double)m / 64.0;
    E64[i] = make_float2((float)cos(th), (float)sin(th));
  }
  for (int i = t; i < 192 * 192; i += NTH)
    Ob[i] = __float2bfloat16(out_w[i]);
  for (int i = t; i < 384 * 192; i += NTH)
    Wb[i] = __float2bfloat16(lin_w[i]);
}

// ----------------------------------------------------------------------------
// depthwise 3x3 conv (NCHW in, NHWC bf16 out), pad 1. grid (6,64,32)
// also emits fp32 partial pooled sums over w: partial[b][h][c]
// ----------------------------------------------------------------------------
__global__ __launch_bounds__(256) void conv_kernel(
    const void* xin, const int* flag, const float* dww, const float* dwb,
    bf16* out, float* partial)
{
  int flg = *flag;
  const float* xf = (const float*)xin;
  const bf16*  xb = (const bf16*)xin;
  int c0 = blockIdx.x * 32;
  int h  = blockIdx.y;
  int b  = blockIdx.z;
  __shared__ float in_s[3][32][66];
  __shared__ float wg[32][10];
  __shared__ float bias[32];
  __shared__ float psum[8][33];
  int t = threadIdx.x;
  for (int idx = t; idx < 3 * 32 * 66; idx += 256) {
    int r = idx / (32 * 66);
    int rem = idx - r * (32 * 66);
    int ci = rem / 66, wi = rem - ci * 66;
    int hh = h + r - 1, wwi = wi - 1;
    float v = 0.f;
    if (hh >= 0 && hh < 64 && wwi >= 0 && wwi < 64) {
      size_t ix = (((size_t)b * 192 + c0 + ci) * 64 + hh) * 64 + wwi;
      v = flg ? xf[ix] : b2f(xb[ix]);
    }
    in_s[r][ci][wi] = v;
  }
  for (int idx = t; idx < 32 * 9; idx += 256) {
    int ci = idx / 9;
    wg[ci][idx - ci * 9] = dww[(c0 + ci) * 9 + (idx - ci * 9)];
  }
  if (t < 32) bias[t] = dwb[c0 + t];
  __syncthreads();
  int cc = t & 31, wq = t >> 5;
  float ls = 0.f;
  for (int j = 0; j < 8; ++j) {
    int w = wq + 8 * j;
    float acc = bias[cc];
#pragma unroll
    for (int r = 0; r < 3; ++r)
#pragma unroll
      for (int kw = 0; kw < 3; ++kw)
        acc += in_s[r][cc][w + kw] * wg[cc][r * 3 + kw];
    out[(((size_t)b * 64 + h) * 64 + w) * 192 + c0 + cc] = __float2bfloat16(acc);
    ls += scrub(acc);
  }
  psum[wq][cc] = ls;
  __syncthreads();
  if (t < 32) {
    float s = 0.f;
    for (int r = 0; r < 8; ++r) s += psum[r][t];
    partial[((size_t)b * 64 + h) * 192 + c0 + t] = s;
  }
}

// ----------------------------------------------------------------------------
// linear via bf16 MFMA. grid (1024, 3).
// ----------------------------------------------------------------------------
__global__ __launch_bounds__(256) void linear_mfma_kernel(
    const bf16* Yb, const bf16* Wb, const float* bias, float* xh, bf16* zb)
{
  __shared__ __align__(16) short Asm[128 * 40];
  __shared__ __align__(16) short Bsm[128 * 40];
  int m0 = blockIdx.x * 128, n0 = blockIdx.y * 128;
  int t = threadIdx.x;
  int wave = t >> 6, lane = t & 63;
  int wm = (wave & 1) * 64, wn = (wave >> 1) * 64;
  int lq = lane >> 4, lr = lane & 15;
  float4v acc[4][4];
#pragma unroll
  for (int i = 0; i < 4; ++i)
#pragma unroll
    for (int j = 0; j < 4; ++j) acc[i][j] = (float4v){0.f, 0.f, 0.f, 0.f};

  for (int k0 = 0; k0 < 192; k0 += 32) {
#pragma unroll
    for (int i = 0; i < 4; ++i) {
      int ch = t + 256 * i;
      int isB = ch >> 9, c = ch & 511;
      int r = c >> 2, kc = c & 3;
      const bf16* src = isB ? (Wb + (size_t)(n0 + r) * 192 + k0 + kc * 8)
                            : (Yb + (size_t)(m0 + r) * 192 + k0 + kc * 8);
      float4 v = *(const float4*)src;
      short* dst = (isB ? Bsm : Asm) + r * 40 + kc * 8;
      *(float4*)dst = v;
    }
    __syncthreads();
    short8v af[4], bfr[4];
#pragma unroll
    for (int f = 0; f < 4; ++f) {
      af[f]  = *(const short8v*)&Asm[(wm + f * 16 + lr) * 40 + lq * 8];
      bfr[f] = *(const short8v*)&Bsm[(wn + f * 16 + lr) * 40 + lq * 8];
    }
#pragma unroll
    for (int fm = 0; fm < 4; ++fm)
#pragma unroll
      for (int fn = 0; fn < 4; ++fn)
        acc[fm][fn] = __builtin_amdgcn_mfma_f32_16x16x32_bf16(
            af[fm], bfr[fn], acc[fm][fn], 0, 0, 0);
    __syncthreads();
  }
#pragma unroll
  for (int fm = 0; fm < 4; ++fm)
#pragma unroll
    for (int e = 0; e < 4; ++e) {
      int m = m0 + wm + fm * 16 + lq * 4 + e;
#pragma unroll
      for (int fn = 0; fn < 4; ++fn) {
        int n = n0 + wn + fn * 16 + lr;
        float v = acc[fm][fn][e] + bias[n];
        if (n < 192) xh[(size_t)m * 192 + n] = v;
        else         zb[(size_t)m * 192 + (n - 192)] = __float2bfloat16(v);
      }
    }
}

// ----------------------------------------------------------------------------
// pooled = mean_hw(y) @ lin_w[0:192]^T + lin_b  (fp32-exact sel path)
// ----------------------------------------------------------------------------
__global__ __launch_bounds__(256) void pooled_kernel(
    const float* partial, const float* linW, const float* linB, float* pooled)
{
  __shared__ float pcs[32 * 193];
  int t = threadIdx.x;
  int c0 = blockIdx.x * 16;
  for (int i = t; i < 6144; i += 256) {
    int b = i / 192, c = i - b * 192;
    float s = 0.f;
    const float* p = partial + (size_t)b * 64 * 192 + c;
    for (int h = 0; h < 64; ++h) s += p[h * 192];
    pcs[b * 193 + c] = s;
  }
  __syncthreads();
  int c = c0 + (t & 15), bp = t >> 4;
#pragma unroll
  for (int half = 0; half < 2; ++half) {
    int b = bp + 16 * half;
    float a = 0.f;
    for (int k = 0; k < 192; ++k) a += pcs[b * 193 + k] * linW[(size_t)c * 192 + k];
    pooled[b * 192 + c] = linB[c] + a * (1.f / 4096.f);
  }
}

// ----------------------------------------------------------------------------
// kmap. grid (64, 3)
// ----------------------------------------------------------------------------
__global__ __launch_bounds__(256) void kmap_kernel(
    const float* A, const float* Wt, const float* bias, float* kout)
{
  __shared__ float As[32][65];
  __shared__ float Bs[32][65];
  int m0 = blockIdx.x * 64, n0 = blockIdx.y * 64;
  int t = threadIdx.x, tx = t & 15, ty = t >> 4;
  float acc[4][4] = {};
  for (int k0 = 0; k0 < 192; k0 += 32) {
    int kk = t & 31, mm = t >> 5;
#pragma unroll
    for (int i = 0; i < 8; ++i) {
      As[kk][mm + 8 * i] = A[(size_t)(m0 + mm + 8 * i) * 192 + k0 + kk];
      Bs[kk][mm + 8 * i] = Wt[(size_t)(n0 + mm + 8 * i) * 192 + k0 + kk];
    }
    __syncthreads();
    for (int k = 0; k < 32; ++k) {
      float a[4], bb[4];
#pragma unroll
      for (int i = 0; i < 4; ++i) a[i] = As[k][ty * 4 + i];
#pragma unroll
      for (int j = 0; j < 4; ++j) bb[j] = Bs[k][tx * 4 + j];
#pragma unroll
      for (int i = 0; i < 4; ++i)
#pragma unroll
        for (int j = 0; j < 4; ++j) acc[i][j] += a[i] * bb[j];
    }
    __syncthreads();
  }
  const float PI2 = 9.86960440108935862f;
  for (int i = 0; i < 4; ++i) {
    int m = m0 + ty * 4 + i;
    int ii = m >> 6, jj = m & 63;
    float d2 = (PI2 / 4096.f) * (float)(ii * ii + jj * jj);
    for (int j = 0; j < 4; ++j) {
      int n = n0 + tx * 4 + j;
      float e = acc[i][j] + bias[n];
      e = e > 0.f ? e : 0.f;
      kout[(size_t)m * 192 + n] = expf(-d2 * e);
    }
  }
}

// ----------------------------------------------------------------------------
// MLP + batchnorms + gumbel argmax -> sel[32] ; 1 block
// ----------------------------------------------------------------------------
__global__ __launch_bounds__(256) void mlp_kernel(
    const float* pooled, const float* gn,
    const float* p1w, const float* p1b, const float* g1, const float* b1,
    const float* p2w, const float* p2b, const float* g2, const float* b2,
    const float* p3w, const float* p3b, int* sel)
{
  __shared__ float pl[32 * 192];
  __shared__ float h1s[32 * 256];
  __shared__ float h2s[32 * 32];
  int t = threadIdx.x;
  for (int i = t; i < 32 * 192; i += 256) pl[i] = pooled[i];
  __syncthreads();
  {
    float acc[32];
    float bb = p1b[t];
#pragma unroll
    for (int b = 0; b < 32; ++b) acc[b] = bb;
    for (int c = 0; c < 192; ++c) {
      float w = p1w[t * 192 + c];
#pragma unroll
      for (int b = 0; b < 32; ++b) acc[b] += w * pl[b * 192 + c];
    }
    for (int b = 0; b < 32; ++b) {
      float v = acc[b];
      v = v > 0.f ? v : 0.1f * v;
      h1s[b * 256 + t] = v;
    }
  }
  __syncthreads();
  {
    float m = 0.f;
    for (int b = 0; b < 32; ++b) m += h1s[b * 256 + t];
    m *= (1.f / 32.f);
    float v = 0.f;
    for (int b = 0; b < 32; ++b) { float d = h1s[b * 256 + t] - m; v += d * d; }
    v *= (1.f / 32.f);
    float sc = g1[t] / sqrtf(v + 1e-5f);
    float sh = b1[t] - m * sc;
    for (int b = 0; b < 32; ++b) h1s[b * 256 + t] = h1s[b * 256 + t] * sc + sh;
  }
  __syncthreads();
  {
    int j = t & 31, bg = t >> 5;
    float acc[4];
    float bb = p2b[j];
    for (int i = 0; i < 4; ++i) acc[i] = bb;
    for (int c = 0; c < 256; ++c) {
      float w = p2w[j * 256 + c];
#pragma unroll
      for (int i = 0; i < 4; ++i) acc[i] += w * h1s[(bg * 4 + i) * 256 + c];
    }
    for (int i = 0; i < 4; ++i) {
      float v = acc[i];
      v = v > 0.f ? v : 0.1f * v;
      h2s[(bg * 4 + i) * 32 + j] = v;
    }
  }
  __syncthreads();
  if (t < 32) {
    float m = 0.f;
    for (int b = 0; b < 32; ++b) m += h2s[b * 32 + t];
    m *= (1.f / 32.f);
    float v = 0.f;
    for (int b = 0; b < 32; ++b) { float d = h2s[b * 32 + t] - m; v += d * d; }
    v *= (1.f / 32.f);
    float sc = g2[t] / sqrtf(v + 1e-5f);
    float sh = b2[t] - m * sc;
    for (int b = 0; b < 32; ++b) h2s[b * 32 + t] = h2s[b * 32 + t] * sc + sh;
  }
  __syncthreads();
  if (t < 32) {
    float best = -1e30f; int bi = 0;
    for (int r = 0; r < 3; ++r) {
      float l = p3b[r];
      for (int c = 0; c < 32; ++c) l += p3w[r * 32 + c] * h2s[t * 32 + c];
      l += gn[t * 3 + r];
      if (l > best) { best = l; bi = r; }
    }
    sel[t] = bi;
  }
}

// ----------------------------------------------------------------------------
// DCT stage over first axis of (64, 12288), in-place. grid (192, 32)
// ----------------------------------------------------------------------------
__global__ __launch_bounds__(256) void axis0_kernel(
    float* buf, const float* mat, const int* sel, int branch)
{
  int b = blockIdx.y;
  if (sel[b] != branch) return;
  int q0 = blockIdx.x * 64;
  __shared__ float mT[64][65];
  __shared__ float xs[64][65];
  int t = threadIdx.x;
  for (int i = t; i < 4096; i += 256) {
    int r = i >> 6, c = i & 63;
    mT[c][r] = mat[i];
    xs[r][c] = buf[(size_t)b * SLICE + r * 12288 + q0 + c];
  }
  __syncthreads();
  int tx = t & 15, ty = t >> 4;
  float acc[4][4] = {};
  for (int l = 0; l < 64; ++l) {
    float a[4], xv[4];
#pragma unroll
    for (int i = 0; i < 4; ++i) a[i] = mT[l][ty * 4 + i];
#pragma unroll
    for (int j = 0; j < 4; ++j) xv[j] = xs[l][tx * 4 + j];
#pragma unroll
    for (int i = 0; i < 4; ++i)
#pragma unroll
      for (int j = 0; j < 4; ++j) acc[i][j] += a[i] * xv[j];
  }
  float* ob = buf + (size_t)b * SLICE;
  for (int i = 0; i < 4; ++i)
    for (int j = 0; j < 4; ++j)
      ob[(ty * 4 + i) * 12288 + q0 + tx * 4 + j] = acc[i][j];
}

// DCT stage over middle axis, in-place, optional k multiply. grid (192, 32)
__global__ __launch_bounds__(256) void axis1_kernel(
    float* buf, const float* mat, const float* kmul, const int* sel, int branch)
{
  int b = blockIdx.y;
  if (sel[b] != branch) return;
  int n = blockIdx.x / 3;
  int ct = (blockIdx.x - n * 3) * 64;
  float* base = buf + (size_t)b * SLICE + n * (64 * 192) + ct;
  __shared__ float mT[64][65];
  __shared__ float xs[64][65];
  int t = threadIdx.x;
  for (int i = t; i < 4096; i += 256) {
    int r = i >> 6, c = i & 63;
    mT[c][r] = mat[i];
    xs[r][c] = base[r * 192 + c];
  }
  __syncthreads();
  int tx = t & 15, ty = t >> 4;
  float acc[4][4] = {};
  for (int l = 0; l < 64; ++l) {
    float a[4], xv[4];
#pragma unroll
    for (int i = 0; i < 4; ++i) a[i] = mT[l][ty * 4 + i];
#pragma unroll
    for (int j = 0; j < 4; ++j) xv[j] = xs[l][tx * 4 + j];
#pragma unroll
    for (int i = 0; i < 4; ++i)
#pragma unroll
      for (int j = 0; j < 4; ++j) acc[i][j] += a[i] * xv[j];
  }
  if (kmul) {
    for (int i = 0; i < 4; ++i)
      for (int j = 0; j < 4; ++j)
        acc[i][j] *= kmul[(size_t)(n * 64 + ty * 4 + i) * 192 + ct + tx * 4 + j];
  }
  for (int i = 0; i < 4; ++i)
    for (int j = 0; j < 4; ++j)
      base[(ty * 4 + i) * 192 + tx * 4 + j] = acc[i][j];
}

// ----------------------------------------------------------------------------
// FFT forward over h (real -> complex), real in-place into xh, imag -> Si
// ----------------------------------------------------------------------------
__global__ __launch_bounds__(256) void ffth_kernel(
    float* xh, float* Si, const float2* E64, const int* sel)
{
  int b = blockIdx.y;
  if (sel[b] != 1) return;
  int q0 = blockIdx.x * 64;
  __shared__ float er[64][65], ei[64][65], xs[64][65];
  int t = threadIdx.x;
  for (int i = t; i < 4096; i += 256) {
    int r = i >> 6, c = i & 63;
    float2 e = E64[i];
    er[r][c] = e.x; ei[r][c] = e.y;
    xs[r][c] = xh[(size_t)b * SLICE + r * 12288 + q0 + c];
  }
  __syncthreads();
  int tx = t & 15, ty = t >> 4;
  float ar[4][4] = {}, ai[4][4] = {};
  for (int l = 0; l < 64; ++l) {
    float e1[4], e2[4], xv[4];
#pragma unroll
    for (int i = 0; i < 4; ++i) { e1[i] = er[l][ty * 4 + i]; e2[i] = ei[l][ty * 4 + i]; }
#pragma unroll
    for (int j = 0; j < 4; ++j) xv[j] = xs[l][tx * 4 + j];
#pragma unroll
    for (int i = 0; i < 4; ++i)
#pragma unroll
      for (int j = 0; j < 4; ++j) { ar[i][j] += e1[i] * xv[j]; ai[i][j] += e2[i] * xv[j]; }
  }
  size_t ob = (size_t)b * SLICE;
  for (int i = 0; i < 4; ++i)
    for (int j = 0; j < 4; ++j) {
      size_t o = ob + (size_t)(ty * 4 + i) * 12288 + q0 + tx * 4 + j;
      xh[o] = ar[i][j];
      Si[o] = ai[i][j];
    }
}

// FFT over w (complex, in-place). grid (384, 32)
__global__ __launch_bounds__(256) void fftw_kernel(
    float* Sr, float* Si, const float2* E64, const int* sel, float s)
{
  int b = blockIdx.y;
  if (sel[b] != 1) return;
  int kh = blockIdx.x / 6;
  int ct = (blockIdx.x - kh * 6) * 32;
  float* br = Sr + (size_t)b * SLICE + kh * 12288 + ct;
  float* bi = Si + (size_t)b * SLICE + kh * 12288 + ct;
  __shared__ float er[64][65], ei[64][65];
  __shared__ float xr[64][33], xi[64][33];
  int t = threadIdx.x;
  for (int i = t; i < 4096; i += 256) {
    float2 e = E64[i];
    er[i >> 6][i & 63] = e.x;
    ei[i >> 6][i & 63] = s * e.y;
  }
  for (int i = t; i < 2048; i += 256) {
    int l = i >> 5, q = i & 31;
    xr[l][q] = br[l * 192 + q];
    xi[l][q] = bi[l * 192 + q];
  }
  __syncthreads();
  int tx = t & 7, ty = t >> 3;
  float ar[2][4] = {}, ac[2][4] = {};
  for (int l = 0; l < 64; ++l) {
    float e1a = er[l][ty],      e2a = ei[l][ty];
    float e1b = er[l][ty + 32], e2b = ei[l][ty + 32];
#pragma unroll
    for (int j = 0; j < 4; ++j) {
      float vr = xr[l][tx * 4 + j], vi = xi[l][tx * 4 + j];
      ar[0][j] += e1a * vr - e2a * vi;
      ac[0][j] += e1a * vi + e2a * vr;
      ar[1][j] += e1b * vr - e2b * vi;
      ac[1][j] += e1b * vi + e2b * vr;
    }
  }
  for (int r = 0; r < 2; ++r) {
    int kw = ty + r * 32;
    for (int j = 0; j < 4; ++j) {
      br[kw * 192 + tx * 4 + j] = ar[r][j];
      bi[kw * 192 + tx * 4 + j] = ac[r][j];
    }
  }
}

// ----------------------------------------------------------------------------
// DFT-8 butterfly, SGN=-1: X[k]=sum x_n e^{-2pi i nk/8}; SGN=+1: conjugated.
// Verified against omega^k deltas for both signs.
// ----------------------------------------------------------------------------
template<int SGN>
static DEVI void dft8(float* xr, float* xi) {
  const float s = 0.70710678118654752440f;
  float s0r = xr[0] + xr[4], s0i = xi[0] + xi[4];
  float s1r = xr[0] - xr[4], s1i = xi[0] - xi[4];
  float s2r = xr[2] + xr[6], s2i = xi[2] + xi[6];
  float s3r = xr[2] - xr[6], s3i = xi[2] - xi[6];
  float w3r = (SGN < 0) ? s3i : -s3i;
  float w3i = (SGN < 0) ? -s3r : s3r;
  float E0r = s0r + s2r, E0i = s0i + s2i;
  float E2r = s0r - s2r, E2i = s0i - s2i;
  float E1r = s1r + w3r, E1i = s1i + w3i;
  float E3r = s1r - w3r, E3i = s1i - w3i;
  float r0r = xr[1] + xr[5], r0i = xi[1] + xi[5];
  float r1r = xr[1] - xr[5], r1i = xi[1] - xi[5];
  float r2r = xr[3] + xr[7], r2i = xi[3] + xi[7];
  float r3r = xr[3] - xr[7], r3i = xi[3] - xi[7];
  float v3r = (SGN < 0) ? r3i : -r3i;
  float v3i = (SGN < 0) ? -r3r : r3r;
  float O0r = r0r + r2r, O0i = r0i + r2i;
  float O2r = r0r - r2r, O2i = r0i - r2i;
  float O1r = r1r + v3r, O1i = r1i + v3i;
  float O3r = r1r - v3r, O3i = r1i - v3i;
  xr[0] = E0r + O0r; xi[0] = E0i + O0i;
  xr[4] = E0r - O0r; xi[4] = E0i - O0i;
  float t2r = (SGN < 0) ? O2i : -O2i;
  float t2i = (SGN < 0) ? -O2r : O2r;
  xr[2] = E2r + t2r; xi[2] = E2i + t2i;
  xr[6] = E2r - t2r; xi[6] = E2i - t2i;
  float t1r = (SGN < 0) ? s * (O1r + O1i) : s * (O1r - O1i);
  float t1i = (SGN < 0) ? s * (O1i - O1r) : s * (O1r + O1i);
  xr[1] = E1r + t1r; xi[1] = E1i + t1i;
  xr[5] = E1r - t1r; xi[5] = E1i - t1i;
  float t3r = (SGN < 0) ? s * (O3i - O3r) : -s * (O3r + O3i);
  float t3i = (SGN < 0) ? -s * (O3r + O3i) : s * (O3r - O3i);
  xr[3] = E3r + t3r; xi[3] = E3i + t3i;
  xr[7] = E3r - t3r; xi[7] = E3i - t3i;
}

// ----------------------------------------------------------------------------
// Fused c-stage: radix-3 x (radix-8 x radix-8) Cooley-Tukey, fp32 exact.
// S <- IDFT_c( DFT_c(S) * k*SCALE ) per 32-row tile, in-place.
// DFT-64 per (row,n1) now two DFT-8 stages through LDS (was direct O(64^2)).
// T[192][33]: f-stride 66 words == 2 mod 32 -> all patterns 2-way-alias free.
// 768 stage-items = 3/thread. grid (128, 32). LDS 51.2 KB -> 3 blocks/CU.
// ----------------------------------------------------------------------------
__global__ __launch_bounds__(256, 3) void fftc_fused_kernel(
    float* Sr, float* Si, const float* kmap, const float2* E64, const int* sel)
{
  int b = blockIdx.y;
  if (sel[b] != 1) return;
  int m0 = blockIdx.x * 32;
  float* gr = Sr + (size_t)b * SLICE + (size_t)m0 * 192;
  float* gi = Si + (size_t)b * SLICE + (size_t)m0 * 192;
  __shared__ __align__(16) float2 T[192][33];
  __shared__ float2 wtab[64];          // w64^n (from E64 row 1)
  int t = threadIdx.x;
  for (int i = t; i < 6144; i += 256) {
    int row = i / 192, c = i - row * 192;
    T[c][row] = make_float2(gr[i], gi[i]);
  }
  if (t < 64) wtab[t] = E64[64 + t];
  __syncthreads();

  float xr[3][8], xim[3][8];

  // ---- fwd stage A: C_p[j] = sum_q x[3(p+8q)+n1] w8^{qj}; * w64^{pj} ----
#pragma unroll
  for (int it = 0; it < 3; ++it) {
    int g = t + 256 * it;
    int row = g & 31, rest = g >> 5;
    int n1 = rest >> 3, p = rest & 7;
#pragma unroll
    for (int q = 0; q < 8; ++q) {
      float2 v = T[3 * (p + 8 * q) + n1][row];
      xr[it][q] = v.x; xim[it][q] = v.y;
    }
    dft8<-1>(xr[it], xim[it]);
#pragma unroll
    for (int j = 1; j < 8; ++j) {
      float2 w = wtab[p * j];
      float a = xr[it][j], bb = xim[it][j];
      xr[it][j]  = a * w.x - bb * w.y;
      xim[it][j] = a * w.y + bb * w.x;
    }
  }
  __syncthreads();
#pragma unroll
  for (int it = 0; it < 3; ++it) {
    int g = t + 256 * it;
    int row = g & 31, rest = g >> 5;
    int n1 = rest >> 3, p = rest & 7;
#pragma unroll
    for (int j = 0; j < 8; ++j)
      T[n1 * 64 + p * 8 + j][row] = make_float2(xr[it][j], xim[it][j]);
  }
  __syncthreads();

  // ---- fwd stage B: Y[j+8m2] = sum_p B_p[j] w8^{p m2} ----
#pragma unroll
  for (int it = 0; it < 3; ++it) {
    int g = t + 256 * it;
    int row = g & 31, rest = g >> 5;
    int n1 = rest >> 3, j = rest & 7;
#pragma unroll
    for (int p = 0; p < 8; ++p) {
      float2 v = T[n1 * 64 + p * 8 + j][row];
      xr[it][p] = v.x; xim[it][p] = v.y;
    }
    dft8<-1>(xr[it], xim[it]);
  }
  __syncthreads();
#pragma unroll
  for (int it = 0; it < 3; ++it) {
    int g = t + 256 * it;
    int row = g & 31, rest = g >> 5;
    int n1 = rest >> 3, j = rest & 7;
#pragma unroll
    for (int m2 = 0; m2 < 8; ++m2)
      T[n1 * 64 + j + 8 * m2][row] = make_float2(xr[it][m2], xim[it][m2]);
  }
  __syncthreads();

  // ---- middle: W192 twiddle + radix-3 + k + inverse (owner-exclusive) ----
  {
    int tx = t & 31, ty = t >> 5;
    int rbase = ty * 4;
    double A = 2.0 * 3.14159265358979323846 * (double)tx;
    double sb, cb;
    sincos(A / 192.0, &sb, &cb);
    float cw = (float)cb, sw = (float)sb;
    const float S3 = 0.86602540378443864676f;
    float w1r[2], w1i[2], w2r[2], w2i[2];
    w1r[0] = cw;                   w1i[0] = -sw;
    w1r[1] = 0.5f * cw - S3 * sw;  w1i[1] = -S3 * cw - 0.5f * sw;
#pragma unroll
    for (int u = 0; u < 2; ++u) {
      w2r[u] = w1r[u] * w1r[u] - w1i[u] * w1i[u];
      w2i[u] = 2.f * w1r[u] * w1i[u];
    }
    float ar[2][3][4], ai[2][3][4];
#pragma unroll
    for (int u = 0; u < 2; ++u)
#pragma unroll
      for (int n1 = 0; n1 < 3; ++n1)
#pragma unroll
        for (int r = 0; r < 4; ++r) {
          float2 v = T[n1 * 64 + tx + 32 * u][rbase + r];
          ar[u][n1][r] = v.x; ai[u][n1][r] = v.y;
        }
    const float SCALE = 1.0f / 786432.0f;
#pragma unroll
    for (int u = 0; u < 2; ++u) {
      int m = tx + 32 * u;
#pragma unroll
      for (int r = 0; r < 4; ++r) {
        int row = rbase + r;
        float Y0r = ar[u][0][r], Y0i = ai[u][0][r];
        float Y1r = ar[u][1][r], Y1i = ai[u][1][r];
        float Y2r = ar[u][2][r], Y2i = ai[u][2][r];
        float T1r = Y1r * w1r[u] - Y1i * w1i[u];
        float T1i = Y1r * w1i[u] + Y1i * w1r[u];
        float T2r = Y2r * w2r[u] - Y2i * w2i[u];
        float T2i = Y2r * w2i[u] + Y2i * w2r[u];
        float aRr = T1r + T2r, aRi = T1i + T2i;
        float bRr = T1r - T2r, bRi = T1i - T2i;
        float X0r = Y0r + aRr, X0i = Y0i + aRi;
        float cfr = Y0r - 0.5f * aRr, cfi = Y0i - 0.5f * aRi;
        float X1r = cfr + S3 * bRi, X1i = cfi - S3 * bRr;
        float X2r = cfr - S3 * bRi, X2i = cfi + S3 * bRr;
        const float* kp = kmap + (size_t)(m0 + row) * 192 + m;
        float k0 = kp[0] * SCALE, k1 = kp[64] * SCALE, k2 = kp[128] * SCALE;
        X0r *= k0; X0i *= k0; X1r *= k1; X1i *= k1; X2r *= k2; X2i *= k2;
        float a2r = X1r + X2r, a2i = X1i + X2i;
        float b2r = X1r - X2r, b2i = X1i - X2i;
        float U0r = X0r + a2r, U0i = X0i + a2i;
        float c2r = X0r - 0.5f * a2r, c2i = X0i - 0.5f * a2i;
        float U1r = c2r - S3 * b2i, U1i = c2i + S3 * b2r;
        float U2r = c2r + S3 * b2i, U2i = c2i - S3 * b2r;
        ar[u][0][r] = U0r;
        ai[u][0][r] = U0i;
        ar[u][1][r] = U1r * w1r[u] + U1i * w1i[u];
        ai[u][1][r] = U1i * w1r[u] - U1r * w1i[u];
        ar[u][2][r] = U2r * w2r[u] + U2i * w2i[u];
        ai[u][2][r] = U2i * w2r[u] - U2r * w2i[u];
      }
    }
#pragma unroll
    for (int u = 0; u < 2; ++u)
#pragma unroll
      for (int n1 = 0; n1 < 3; ++n1)
#pragma unroll
        for (int r = 0; r < 4; ++r)
          T[n1 * 64 + tx + 32 * u][rbase + r] =
              make_float2(ar[u][n1][r], ai[u][n1][r]);
  }
  __syncthreads();

  // ---- inv stage A': D_mu[a] = sum_nu V[mu+8nu] w8^{-nu a}; * w64^{-mu a} ----
#pragma unroll
  for (int it = 0; it < 3; ++it) {
    int g = t + 256 * it;
    int row = g & 31, rest = g >> 5;
    int n1 = rest >> 3, mu = rest & 7;
#pragma unroll
    for (int nu = 0; nu < 8; ++nu) {
      float2 v = T[n1 * 64 + mu + 8 * nu][row];
      xr[it][nu] = v.x; xim[it][nu] = v.y;
    }
    dft8<1>(xr[it], xim[it]);
#pragma unroll
    for (int a = 1; a < 8; ++a) {
      float2 w = wtab[(mu * a) & 63];
      float aa = xr[it][a], bb = xim[it][a];
      xr[it][a]  = aa * w.x + bb * w.y;     // * conj(w)
      xim[it][a] = bb * w.x - aa * w.y;
    }
  }
  __syncthreads();
#pragma unroll
  for (int it = 0; it < 3; ++it) {
    int g = t + 256 * it;
    int row = g & 31, rest = g >> 5;
    int n1 = rest >> 3, mu = rest & 7;
#pragma unroll
    for (int a = 0; a < 8; ++a)
      T[n1 * 64 + mu * 8 + a][row] = make_float2(xr[it][a], xim[it][a]);
  }
  __syncthreads();

  // ---- inv stage B': x[a+8b] = sum_mu E_mu[a] w8^{-mu b} ----
#pragma unroll
  for (int it = 0; it < 3; ++it) {
    int g = t + 256 * it;
    int row = g & 31, rest = g >> 5;
    int n1 = rest >> 3, aa = rest & 7;
#pragma unroll
    for (int mu = 0; mu < 8; ++mu) {
      float2 v = T[n1 * 64 + mu * 8 + aa][row];
      xr[it][mu] = v.x; xim[it][mu] = v.y;
    }
    dft8<1>(xr[it], xim[it]);
  }
  __syncthreads();
#pragma unroll
  for (int it = 0; it < 3; ++it) {
    int g = t + 256 * it;
    int row = g & 31, rest = g >> 5;
    int n1 = rest >> 3, aa = rest & 7;
#pragma unroll
    for (int bq = 0; bq < 8; ++bq)
      T[3 * (aa + 8 * bq) + n1][row] = make_float2(xr[it][bq], xim[it][bq]);
  }
  __syncthreads();

  for (int i = t; i < 6144; i += 256) {
    int row = i / 192, c = i - row * 192;
    float2 v = T[c][row];
    gr[i] = v.x;
    gi[i] = v.y;
  }
}

// inverse h-stage, real part only, in-place into xh. grid (384, 32)
__global__ __launch_bounds__(256) void ffthi_kernel(
    float* Sr, const float* Si, const float2* E64, const int* sel)
{
  int b = blockIdx.y;
  if (sel[b] != 1) return;
  int q0 = blockIdx.x * 32;
  __shared__ float er[64][65], ei[64][65];
  __shared__ float xr[64][33], xi[64][33];
  int t = threadIdx.x;
  for (int i = t; i < 4096; i += 256) {
    float2 e = E64[i];
    er[i >> 6][i & 63] = e.x;
    ei[i >> 6][i & 63] = e.y;
  }
  for (int i = t; i < 2048; i += 256) {
    int l = i >> 5, q = i & 31;
    size_t o = (size_t)b * SLICE + (size_t)l * 12288 + q0 + q;
    xr[l][q] = Sr[o];
    xi[l][q] = Si[o];
  }
  __syncthreads();
  int tx = t & 7, ty = t >> 3;
  float acc[2][4] = {};
  for (int l = 0; l < 64; ++l) {
    float e1a = er[l][ty],      e2a = ei[l][ty];
    float e1b = er[l][ty + 32], e2b = ei[l][ty + 32];
#pragma unroll
    for (int j = 0; j < 4; ++j) {
      float vr = xr[l][tx * 4 + j], vi = xi[l][tx * 4 + j];
      acc[0][j] += e1a * vr + e2a * vi;
      acc[1][j] += e1b * vr + e2b * vi;
    }
  }
  for (int r = 0; r < 2; ++r) {
    int h = ty + r * 32;
    for (int j = 0; j < 4; ++j)
      Sr[(size_t)b * SLICE + (size_t)h * 12288 + q0 + tx * 4 + j] = acc[r][j];
  }
}

// ----------------------------------------------------------------------------
// Haar branch, in-place on xh. grid (128, 32)
// ----------------------------------------------------------------------------
__global__ __launch_bounds__(256) void haar_kernel(
    float* xh, const float* kmap, const int* sel)
{
  int b = blockIdx.y;
  if (sel[b] != 2) return;
  int h = blockIdx.x >> 1;
  int w0 = (blockIdx.x & 1) * 32;
  size_t base = (size_t)b * SLICE + ((size_t)h * 64 + w0) * 192;
  __shared__ float A[32 * 192];
  __shared__ float Bf[32 * 192];
  int t = threadIdx.x;
  for (int i = t; i < 6144; i += 256) A[i] = xh[base + i];
  __syncthreads();
  for (int u = t; u < 32 * 96; u += 256) {
    int p = u / 96, r = u - p * 96;
    int ch = r >> 5, i = r & 31;
    float v0 = A[p * 192 + ch * 64 + 2 * i];
    float v1 = A[p * 192 + ch * 64 + 2 * i + 1];
    Bf[p * 192 + ch * 64 + i]      = (v0 + v1) * 0.5f;
    Bf[p * 192 + ch * 64 + 32 + i] = (v0 - v1) * 0.5f;
  }
  __syncthreads();
  for (int u = t; u < 32 * 96; u += 256) {
    int p = u / 96, i = u - p * 96;
    float v0 = Bf[p * 192 + 2 * i];
    float v1 = Bf[p * 192 + 2 * i + 1];
    A[p * 192 + i]      = (v0 + v1) * 0.5f;
    A[p * 192 + 96 + i] = (v0 - v1) * 0.5f;
  }
  __syncthreads();
  for (int i = t; i < 6144; i += 256)
    A[i] *= kmap[((size_t)h * 64 + w0) * 192 + i];
  __syncthreads();
  for (int u = t; u < 32 * 96; u += 256) {
    int p = u / 96, r = u - p * 96;
    int ch = r >> 5, i = r & 31;
    float a = A[p * 192 + ch * 64 + i];
    float d = A[p * 192 + ch * 64 + 32 + i];
    Bf[p * 192 + ch * 64 + 2 * i]     = a + d;
    Bf[p * 192 + ch * 64 + 2 * i + 1] = a - d;
  }
  __syncthreads();
  for (int u = t; u < 32 * 96; u += 256) {
    int p = u / 96, i = u - p * 96;
    float a = Bf[p * 192 + i];
    float d = Bf[p * 192 + 96 + i];
    A[p * 192 + 2 * i]     = a + d;
    A[p * 192 + 2 * i + 1] = a - d;
  }
  __syncthreads();
  for (int i = t; i < 6144; i += 256) xh[base + i] = A[i];
}

// ----------------------------------------------------------------------------
// final: LN(c) * silu(z) @ out_w^T + out_b via bf16 MFMA, dual-dtype store.
// grid 2048.
// ----------------------------------------------------------------------------
__global__ __launch_bounds__(256) void final_kernel(
    const float* comb, const bf16* zb, const float* lng, const float* lnb,
    const bf16* Ob, const float* outb, void* outp, const int* flag)
{
  int flg = *flag;
  int bi = blockIdx.x;
  int b = bi >> 6, h = bi & 63;
  size_t base = ((size_t)b * 4096 + (size_t)h * 64) * 192;
  __shared__ float As[12672];                  // max(64*196, 192*66)
  __shared__ __align__(16) short Ab[64 * 200];
  __shared__ float red[2][4][64];
  __shared__ float mu[64], rs[64];
  int t = threadIdx.x;
  for (int idx = t; idx < 3072; idx += 256) {
    int q = idx << 2;
    int p = idx / 48, c = q - p * 192;
    float4 v = *(const float4*)&comb[base + q];
    v.x = scrub(v.x); v.y = scrub(v.y); v.z = scrub(v.z); v.w = scrub(v.w);
    *(float4*)&As[p * 196 + c] = v;
  }
  __syncthreads();
  {
    int r = t & 63, part = t >> 6;
    const float* row = &As[r * 196 + part * 48];
    float s = 0.f, s2 = 0.f;
    for (int c = 0; c < 48; ++c) { float v = row[c]; s += v; s2 += v * v; }
    red[0][part][r] = s;
    red[1][part][r] = s2;
  }
  __syncthreads();
  if (t < 64) {
    float s  = red[0][0][t] + red[0][1][t] + red[0][2][t] + red[0][3][t];
    float s2 = red[1][0][t] + red[1][1][t] + red[1][2][t] + red[1][3][t];
    float m = s * (1.f / 192.f);
    float v = s2 * (1.f / 192.f) - m * m;
    v = v > 0.f ? v : 0.f;
    mu[t] = m;
    rs[t] = 1.f / sqrtf(v + 1e-5f);
  }
  __syncthreads();
  for (int idx = t; idx < 1536; idx += 256) {
    int q = idx << 3;
    int p = idx / 24, c = q - p * 192;
    float4 a0 = *(const float4*)&As[p * 196 + c];
    float4 a1 = *(const float4*)&As[p * 196 + c + 4];
    short8v z8 = *(const short8v*)&zb[base + q];
    float av[8] = {a0.x, a0.y, a0.z, a0.w, a1.x, a1.y, a1.z, a1.w};
    short o8[8];
    float m = mu[p], r = rs[p];
#pragma unroll
    for (int j = 0; j < 8; ++j) {
      float v = (av[j] - m) * r * lng[c + j] + lnb[c + j];
      float zv = scrub(bitsbf((unsigned short)z8[j]));
      v *= zv / (1.f + expf(-zv));
      o8[j] = f2bs(v);
    }
    *(short8v*)&Ab[p * 200 + c] = *(short8v*)o8;
  }
  __syncthreads();
  int wave = t >> 6, lane = t & 63;
  int lq = lane >> 4, lr = lane & 15;
  int n0 = wave * 48;
  float4v acc[4][3];
#pragma unroll
  for (int i = 0; i < 4; ++i)
#pragma unroll
    for (int j = 0; j < 3; ++j) acc[i][j] = (float4v){0.f, 0.f, 0.f, 0.f};
  for (int k0 = 0; k0 < 192; k0 += 32) {
    short8v af[4], bfr[3];
#pragma unroll
    for (int f = 0; f < 4; ++f)
      af[f] = *(const short8v*)&Ab[(f * 16 + lr) * 200 + k0 + lq * 8];
#pragma unroll
    for (int f = 0; f < 3; ++f)
      bfr[f] = *(const short8v*)&Ob[(size_t)(n0 + f * 16 + lr) * 192 + k0 + lq * 8];
#pragma unroll
    for (int fm = 0; fm < 4; ++fm)
#pragma unroll
      for (int fn = 0; fn < 3; ++fn)
        acc[fm][fn] = __builtin_amdgcn_mfma_f32_16x16x32_bf16(
            af[fm], bfr[fn], acc[fm][fn], 0, 0, 0);
  }
  __syncthreads();
#pragma unroll
  for (int fm = 0; fm < 4; ++fm)
#pragma unroll
    for (int e = 0; e < 4; ++e) {
      int p = fm * 16 + lq * 4 + e;
#pragma unroll
      for (int fn = 0; fn < 3; ++fn) {
        int co = n0 + fn * 16 + lr;
        As[co * 66 + p] = acc[fm][fn][e] + outb[co];
      }
    }
  __syncthreads();
  for (int e = t; e < 12288; e += 256) {
    int co = e >> 6, w = e & 63;
    size_t oi = (((size_t)b * 192 + co) * 64 + h) * 64 + w;
    float v = As[co * 66 + w];
    if (flg) ((float*)outp)[oi] = v;
    else     ((bf16*)outp)[oi] = __float2bfloat16(v);
  }
}

// ----------------------------------------------------------------------------
extern "C" void kernel_launch(void* const* d_in, const int* in_sizes, int n_in,
                              void* d_out, int out_size, void* d_ws, size_t ws_size,
                              hipStream_t stream) {
  (void)in_sizes; (void)n_in;
  if (ws_size < WS_NEEDED_BYTES) {
    fill_zero_kernel<<<(out_size + 255) / 256, 256, 0, stream>>>(
        (unsigned short*)d_out, out_size);
    return;
  }
  float* ws    = (float*)d_ws;
  float* xh    = ws + O_XH;
  float* Si    = ws + O_SI;
  bf16*  Yb    = (bf16*)(ws + O_YB);
  float* part  = ws + O_PART;
  bf16*  Wb    = (bf16*)(ws + O_WB);
  bf16*  zb    = (bf16*)(ws + O_ZB);
  float* kmap  = ws + O_KMAP;
  float2* E64  = (float2*)(ws + O_E64);
  float* Dm    = ws + O_DM;
  float* DT    = ws + O_DT;
  bf16*  Ob    = (bf16*)(ws + O_WT);
  float* pooled= ws + O_POOL;
  int*   sel   = (int*)(ws + O_SEL);
  int*   flag  = (int*)(ws + O_FLAG);

  sniff_kernel<<<1, 64, 0, stream>>>((const unsigned short*)d_in[0], flag);

  CvtArgs ca;
  const int srcidx[22] = {2,3,4,5,6,7,8,9,10,11,12,13,14,15,16,17,18,19,20,21,22,1};
  const int ns[22] = {96,1728,192,73728,384,49152,256,256,256,8192,32,32,32,96,3,
                      36864,192,192,192,36864,192,786432};
  const long long offs[22] = {
    (long long)W_GN,(long long)W_DWW,(long long)W_DWB,(long long)W_LINW,
    (long long)W_LINB,(long long)W_P1W,(long long)W_P1B,(long long)W_G1,
    (long long)W_B1,(long long)W_P2W,(long long)W_P2B,(long long)W_G2,
    (long long)W_B2,(long long)W_P3W,(long long)W_P3B,(long long)W_TOKW,
    (long long)W_TOKB,(long long)W_LNG,(long long)W_LNB,(long long)W_OUTW,
    (long long)W_OUTB,(long long)O_FREQ};
  for (int i = 0; i < 22; ++i) { ca.src[i] = d_in[srcidx[i]]; ca.n[i] = ns[i]; ca.off[i] = offs[i]; }
  cvt_kernel<<<64, 256, 0, stream>>>(ca, ws, flag);

  setup_kernel<<<64, 256, 0, stream>>>(Dm, DT, E64, Ob, ws + W_OUTW, Wb, ws + W_LINW);
  conv_kernel<<<dim3(6, 64, 32), 256, 0, stream>>>(d_in[0], flag, ws + W_DWW, ws + W_DWB,
                                                   Yb, part);
  linear_mfma_kernel<<<dim3(1024, 3), 256, 0, stream>>>(Yb, Wb, ws + W_LINB, xh, zb);
  pooled_kernel<<<12, 256, 0, stream>>>(part, ws + W_LINW, ws + W_LINB, pooled);
  mlp_kernel<<<1, 256, 0, stream>>>(pooled, ws + W_GN,
      ws + W_P1W, ws + W_P1B, ws + W_G1, ws + W_B1,
      ws + W_P2W, ws + W_P2B, ws + W_G2, ws + W_B2,
      ws + W_P3W, ws + W_P3B, sel);
  kmap_kernel<<<dim3(64, 3), 256, 0, stream>>>(ws + O_FREQ, ws + W_TOKW, ws + W_TOKB, kmap);
  // DCT branch (sel==0), in-place on xh
  axis0_kernel<<<dim3(192, 32), 256, 0, stream>>>(xh, Dm, sel, 0);
  axis1_kernel<<<dim3(192, 32), 256, 0, stream>>>(xh, Dm, kmap, sel, 0);
  axis1_kernel<<<dim3(192, 32), 256, 0, stream>>>(xh, DT, nullptr, sel, 0);
  axis0_kernel<<<dim3(192, 32), 256, 0, stream>>>(xh, DT, sel, 0);
  // FFT branch (sel==1); b-axis FFT/IFFT cancels analytically; in-place (xh,Si)
  ffth_kernel<<<dim3(192, 32), 256, 0, stream>>>(xh, Si, E64, sel);
  fftw_kernel<<<dim3(384, 32), 256, 0, stream>>>(xh, Si, E64, sel, 1.f);
  fftc_fused_kernel<<<dim3(128, 32), 256, 0, stream>>>(xh, Si, kmap, E64, sel);
  fftw_kernel<<<dim3(384, 32), 256, 0, stream>>>(xh, Si, E64, sel, -1.f);
  ffthi_kernel<<<dim3(384, 32), 256, 0, stream>>>(xh, Si, E64, sel);
  // Haar branch (sel==2), in-place on xh
  haar_kernel<<<dim3(128, 32), 256, 0, stream>>>(xh, kmap, sel);
  // epilogue
  final_kernel<<<2048, 256, 0, stream>>>(xh, zb, ws + W_LNG, ws + W_LNB,
                                         Ob, ws + W_OUTB, d_out, flag);
}

// Round 6
// 1010.555 us; speedup vs baseline: 1.9756x; 1.1033x over previous
//
#include <hip/hip_runtime.h>
#include <hip/hip_bf16.h>
#include <math.h>

typedef __hip_bfloat16 bf16;
#define DEVI __device__ __forceinline__
static DEVI float b2f(bf16 v) { return __bfloat162float(v); }
static DEVI float scrub(float v) { return (v - v == 0.f) ? v : 0.f; }
static DEVI float bitsbf(unsigned short u) {
  union { unsigned int i; float f; } x; x.i = ((unsigned int)u) << 16; return x.f;
}
static DEVI short f2bs(float v) {
  bf16 h = __float2bfloat16(v); return *(short*)&h;
}

typedef __attribute__((ext_vector_type(8))) short short8v;   // 8 bf16 (4 VGPR)
typedef __attribute__((ext_vector_type(4))) float float4v;   // MFMA acc

constexpr int SLICE = 64 * 64 * 192;           // per-b elements = 786432

// ws layout (float offsets). Total 64,755,812 floats = 259,023,248 B (~247 MiB)
constexpr size_t O_XH   = 0;          // 25165824
constexpr size_t O_SI   = 25165824;   // 25165824 (imag buffer for FFT branch)
constexpr size_t O_ZB   = 50331648;   // bf16 z (25165824 elems = 12582912 slots)
constexpr size_t O_KMAP = 62914560;   // 786432
constexpr size_t O_FREQ = 63700992;   // 786432 (converted fp32 freq_embed)
constexpr size_t O_E64  = 64487424;   // 8192 (4096 float2)
constexpr size_t O_DM   = 64495616;   // 4096
constexpr size_t O_DT   = 64499712;   // 4096
constexpr size_t O_WT   = 64503808;   // 36864 (bf16 out_w, 36864 elems = 18432 slots)
constexpr size_t O_POOL = 64540672;   // 6144
constexpr size_t O_SEL  = 64546816;   // 32
constexpr size_t O_FLAG = 64546848;   // 32 (flag int + pad)
constexpr size_t O_W    = 64546880;   // 208932 packed fp32 weights
constexpr size_t WS_NEEDED_BYTES = (size_t)64755812 * 4;

// transient aliases inside O_SI (dead before ffth writes Si):
constexpr size_t O_YB   = O_SI;             // bf16 y, 25165824 elems (12582912 slots)
constexpr size_t O_PART = O_SI + 12600000;  // fp32 partial pooled [32][64][192] = 393216
constexpr size_t O_WB   = O_SI + 13100000;  // bf16 lin_w, 73728 elems (36864 slots)

// packed-weight offsets (relative to ws base)
constexpr size_t W_GN   = O_W + 0;      // 96
constexpr size_t W_DWW  = O_W + 96;     // 1728
constexpr size_t W_DWB  = O_W + 1824;   // 192
constexpr size_t W_LINW = O_W + 2016;   // 73728
constexpr size_t W_LINB = O_W + 75744;  // 384
constexpr size_t W_P1W  = O_W + 76128;  // 49152
constexpr size_t W_P1B  = O_W + 125280; // 256
constexpr size_t W_G1   = O_W + 125536; // 256
constexpr size_t W_B1   = O_W + 125792; // 256
constexpr size_t W_P2W  = O_W + 126048; // 8192
constexpr size_t W_P2B  = O_W + 134240; // 32
constexpr size_t W_G2   = O_W + 134272; // 32
constexpr size_t W_B2   = O_W + 134304; // 32
constexpr size_t W_P3W  = O_W + 134336; // 96
constexpr size_t W_P3B  = O_W + 134432; // 4 (3 used)
constexpr size_t W_TOKW = O_W + 134436; // 36864
constexpr size_t W_TOKB = O_W + 171300; // 192
constexpr size_t W_LNG  = O_W + 171492; // 192
constexpr size_t W_LNB  = O_W + 171684; // 192
constexpr size_t W_OUTW = O_W + 171876; // 36864
constexpr size_t W_OUTB = O_W + 208740; // 192

struct CvtArgs {
  const void* src[22];
  int n[22];
  long long off[22];   // float offset into ws
};

// ----------------------------------------------------------------------------
// dtype sniff
// ----------------------------------------------------------------------------
__global__ void sniff_kernel(const unsigned short* xu, int* flag) {
  __shared__ int cnt;
  if (threadIdx.x == 0) cnt = 0;
  __syncthreads();
  unsigned short u = xu[threadIdx.x];
  int e = (u >> 7) & 0xFF;
  int sane = ((e >= 97 && e <= 160) || (u & 0x7FFF) == 0) ? 1 : 0;
  atomicAdd(&cnt, sane);
  __syncthreads();
  if (threadIdx.x == 0) *flag = (cnt >= 56) ? 0 : 1;
}

// convert all small inputs (+freq) to fp32 in ws, per flag
__global__ __launch_bounds__(256) void cvt_kernel(CvtArgs a, float* ws, const int* flag) {
  int flg = *flag;
  int gt = blockIdx.x * 256 + threadIdx.x;
  int gs = gridDim.x * 256;
  for (int s = 0; s < 22; ++s) {
    const void* sp = a.src[s];
    int n = a.n[s];
    float* dst = ws + a.off[s];
    if (flg) {
      const float* f = (const float*)sp;
      for (int i = gt; i < n; i += gs) dst[i] = f[i];
    } else {
      const bf16* h = (const bf16*)sp;
      for (int i = gt; i < n; i += gs) dst[i] = b2f(h[i]);
    }
  }
}

// fallback: zero-fill
__global__ __launch_bounds__(256) void fill_zero_kernel(unsigned short* out, int n) {
  int i = blockIdx.x * 256 + threadIdx.x;
  if (i < n) out[i] = 0;
}

// ----------------------------------------------------------------------------
// setup: DCT matrices, E64 twiddles, bf16 out_w copy, bf16 lin_w copy
// ----------------------------------------------------------------------------
__global__ __launch_bounds__(256) void setup_kernel(
    float* Dm, float* DT, float2* E64, bf16* Ob, const float* out_w,
    bf16* Wb, const float* lin_w)
{
  int t = blockIdx.x * 256 + threadIdx.x;
  int NTH = gridDim.x * 256;
  const double PI = 3.14159265358979323846;
  for (int i = t; i < 64 * 64; i += NTH) {
    int n = i >> 6, x = i & 63;
    double v = cos((double)n * (((double)x + 0.5) / 64.0) * PI) * sqrt(2.0 / 64.0);
    if (n == 0) v *= 0.70710678118654752440;
    Dm[n * 64 + x] = (float)v;
    DT[x * 64 + n] = (float)v;
  }
  for (int i = t; i < 64 * 64; i += NTH) {
    int k = i >> 6, n = i & 63;
    int m = (k * n) & 63;
    double th = -2.0 * PI * (double)m / 64.0;
    E64[i] = make_float2((float)cos(th), (float)sin(th));
  }
  for (int i = t; i < 192 * 192; i += NTH)
    Ob[i] = __float2bfloat16(out_w[i]);
  for (int i = t; i < 384 * 192; i += NTH)
    Wb[i] = __float2bfloat16(lin_w[i]);
}

// ----------------------------------------------------------------------------
// depthwise 3x3 conv (NCHW in, NHWC bf16 out), pad 1. grid (6,16,32):
// 32 ch x 4 h-rows x 64 w per block. float4 staging, shift-only index math,
// register 3x10 window per h-row. Re-read factor 1.5 (was 3). psum reuses
// in_s after barrier -> 52.9 KB LDS -> 3 blocks/CU.
// ----------------------------------------------------------------------------
__global__ __launch_bounds__(256) void conv_kernel(
    const void* xin, const int* flag, const float* dww, const float* dwb,
    bf16* out, float* partial)
{
  int flg = *flag;
  const float* xf = (const float*)xin;
  const bf16*  xb = (const bf16*)xin;
  int c0 = blockIdx.x * 32;
  int h0 = blockIdx.y * 4;
  int b  = blockIdx.z;
  __shared__ float in_s[6][32][67];
  __shared__ float wg[32][10];
  __shared__ float bias[32];
  int t = threadIdx.x;
  // interior: 6 rows x 32 ch x 16 float4 = 3072 items, 12/thread (shift math)
#pragma unroll
  for (int i = 0; i < 12; ++i) {
    int idx = t + 256 * i;
    int r  = idx >> 9;           // 0..5
    int ci = (idx >> 4) & 31;
    int qw = idx & 15;
    int hh = h0 + r - 1;
    float4 v = make_float4(0.f, 0.f, 0.f, 0.f);
    if (hh >= 0 && hh < 64) {
      size_t ix = (((size_t)b * 192 + c0 + ci) * 64 + hh) * 64 + qw * 4;
      if (flg) {
        v = *(const float4*)&xf[ix];
      } else {
        short4 s = *(const short4*)&xb[ix];
        v.x = bitsbf((unsigned short)s.x); v.y = bitsbf((unsigned short)s.y);
        v.z = bitsbf((unsigned short)s.z); v.w = bitsbf((unsigned short)s.w);
      }
    }
    float* d = &in_s[r][ci][1 + qw * 4];
    d[0] = v.x; d[1] = v.y; d[2] = v.z; d[3] = v.w;
  }
  // halo zeros (wi=0 and wi=65)
  for (int i = t; i < 384; i += 256) {
    int r = i >> 6, rem = i & 63;
    int ci = rem >> 1, side = rem & 1;
    in_s[r][ci][side ? 65 : 0] = 0.f;
  }
  for (int idx = t; idx < 288; idx += 256) {
    int ci = idx / 9;
    wg[ci][idx - ci * 9] = dww[(c0 + ci) * 9 + (idx - ci * 9)];
  }
  if (t < 32) bias[t] = dwb[c0 + t];
  __syncthreads();
  int cc = t & 31, wq = t >> 5;      // wq 0..7 -> w base
  int w0 = wq * 8;
  float w_[9];
#pragma unroll
  for (int k = 0; k < 9; ++k) w_[k] = wg[cc][k];
  float bs = bias[cc];
  float lsum[4];
#pragma unroll
  for (int hr = 0; hr < 4; ++hr) {
    float rowv[3][10];
#pragma unroll
    for (int r = 0; r < 3; ++r)
#pragma unroll
      for (int q = 0; q < 10; ++q)
        rowv[r][q] = in_s[hr + r][cc][w0 + q];
    float ls = 0.f;
#pragma unroll
    for (int j = 0; j < 8; ++j) {
      float acc = bs;
#pragma unroll
      for (int r = 0; r < 3; ++r)
#pragma unroll
        for (int kw = 0; kw < 3; ++kw)
          acc += rowv[r][j + kw] * w_[r * 3 + kw];
      out[(((size_t)b * 64 + h0 + hr) * 64 + w0 + j) * 192 + c0 + cc] =
          __float2bfloat16(acc);
      ls += scrub(acc);
    }
    lsum[hr] = ls;
  }
  __syncthreads();                    // all in_s reads done -> reuse for psum
  float* ps = &in_s[0][0][0];         // layout [8 wq][4 hr][33]
#pragma unroll
  for (int hr = 0; hr < 4; ++hr)
    ps[(wq * 4 + hr) * 33 + cc] = lsum[hr];
  __syncthreads();
  if (t < 128) {
    int hr = t >> 5, ci = t & 31;
    float s = 0.f;
#pragma unroll
    for (int r = 0; r < 8; ++r) s += ps[(r * 4 + hr) * 33 + ci];
    partial[((size_t)b * 64 + h0 + hr) * 192 + c0 + ci] = s;
  }
}

// ----------------------------------------------------------------------------
// linear via bf16 MFMA. grid (1024, 3).
// ----------------------------------------------------------------------------
__global__ __launch_bounds__(256) void linear_mfma_kernel(
    const bf16* Yb, const bf16* Wb, const float* bias, float* xh, bf16* zb)
{
  __shared__ __align__(16) short Asm[128 * 40];
  __shared__ __align__(16) short Bsm[128 * 40];
  int m0 = blockIdx.x * 128, n0 = blockIdx.y * 128;
  int t = threadIdx.x;
  int wave = t >> 6, lane = t & 63;
  int wm = (wave & 1) * 64, wn = (wave >> 1) * 64;
  int lq = lane >> 4, lr = lane & 15;
  float4v acc[4][4];
#pragma unroll
  for (int i = 0; i < 4; ++i)
#pragma unroll
    for (int j = 0; j < 4; ++j) acc[i][j] = (float4v){0.f, 0.f, 0.f, 0.f};

  for (int k0 = 0; k0 < 192; k0 += 32) {
#pragma unroll
    for (int i = 0; i < 4; ++i) {
      int ch = t + 256 * i;
      int isB = ch >> 9, c = ch & 511;
      int r = c >> 2, kc = c & 3;
      const bf16* src = isB ? (Wb + (size_t)(n0 + r) * 192 + k0 + kc * 8)
                            : (Yb + (size_t)(m0 + r) * 192 + k0 + kc * 8);
      float4 v = *(const float4*)src;
      short* dst = (isB ? Bsm : Asm) + r * 40 + kc * 8;
      *(float4*)dst = v;
    }
    __syncthreads();
    short8v af[4], bfr[4];
#pragma unroll
    for (int f = 0; f < 4; ++f) {
      af[f]  = *(const short8v*)&Asm[(wm + f * 16 + lr) * 40 + lq * 8];
      bfr[f] = *(const short8v*)&Bsm[(wn + f * 16 + lr) * 40 + lq * 8];
    }
#pragma unroll
    for (int fm = 0; fm < 4; ++fm)
#pragma unroll
      for (int fn = 0; fn < 4; ++fn)
        acc[fm][fn] = __builtin_amdgcn_mfma_f32_16x16x32_bf16(
            af[fm], bfr[fn], acc[fm][fn], 0, 0, 0);
    __syncthreads();
  }
#pragma unroll
  for (int fm = 0; fm < 4; ++fm)
#pragma unroll
    for (int e = 0; e < 4; ++e) {
      int m = m0 + wm + fm * 16 + lq * 4 + e;
#pragma unroll
      for (int fn = 0; fn < 4; ++fn) {
        int n = n0 + wn + fn * 16 + lr;
        float v = acc[fm][fn][e] + bias[n];
        if (n < 192) xh[(size_t)m * 192 + n] = v;
        else         zb[(size_t)m * 192 + (n - 192)] = __float2bfloat16(v);
      }
    }
}

// ----------------------------------------------------------------------------
// pooled = mean_hw(y) @ lin_w[0:192]^T + lin_b  (fp32-exact sel path)
// ----------------------------------------------------------------------------
__global__ __launch_bounds__(256) void pooled_kernel(
    const float* partial, const float* linW, const float* linB, float* pooled)
{
  __shared__ float pcs[32 * 193];
  int t = threadIdx.x;
  int c0 = blockIdx.x * 16;
  for (int i = t; i < 6144; i += 256) {
    int b = i / 192, c = i - b * 192;
    float s = 0.f;
    const float* p = partial + (size_t)b * 64 * 192 + c;
    for (int h = 0; h < 64; ++h) s += p[h * 192];
    pcs[b * 193 + c] = s;
  }
  __syncthreads();
  int c = c0 + (t & 15), bp = t >> 4;
#pragma unroll
  for (int half = 0; half < 2; ++half) {
    int b = bp + 16 * half;
    float a = 0.f;
    for (int k = 0; k < 192; ++k) a += pcs[b * 193 + k] * linW[(size_t)c * 192 + k];
    pooled[b * 192 + c] = linB[c] + a * (1.f / 4096.f);
  }
}

// ----------------------------------------------------------------------------
// kmap. grid (64, 3)
// ----------------------------------------------------------------------------
__global__ __launch_bounds__(256) void kmap_kernel(
    const float* A, const float* Wt, const float* bias, float* kout)
{
  __shared__ float As[32][65];
  __shared__ float Bs[32][65];
  int m0 = blockIdx.x * 64, n0 = blockIdx.y * 64;
  int t = threadIdx.x, tx = t & 15, ty = t >> 4;
  float acc[4][4] = {};
  for (int k0 = 0; k0 < 192; k0 += 32) {
    int kk = t & 31, mm = t >> 5;
#pragma unroll
    for (int i = 0; i < 8; ++i) {
      As[kk][mm + 8 * i] = A[(size_t)(m0 + mm + 8 * i) * 192 + k0 + kk];
      Bs[kk][mm + 8 * i] = Wt[(size_t)(n0 + mm + 8 * i) * 192 + k0 + kk];
    }
    __syncthreads();
    for (int k = 0; k < 32; ++k) {
      float a[4], bb[4];
#pragma unroll
      for (int i = 0; i < 4; ++i) a[i] = As[k][ty * 4 + i];
#pragma unroll
      for (int j = 0; j < 4; ++j) bb[j] = Bs[k][tx * 4 + j];
#pragma unroll
      for (int i = 0; i < 4; ++i)
#pragma unroll
        for (int j = 0; j < 4; ++j) acc[i][j] += a[i] * bb[j];
    }
    __syncthreads();
  }
  const float PI2 = 9.86960440108935862f;
  for (int i = 0; i < 4; ++i) {
    int m = m0 + ty * 4 + i;
    int ii = m >> 6, jj = m & 63;
    float d2 = (PI2 / 4096.f) * (float)(ii * ii + jj * jj);
    for (int j = 0; j < 4; ++j) {
      int n = n0 + tx * 4 + j;
      float e = acc[i][j] + bias[n];
      e = e > 0.f ? e : 0.f;
      kout[(size_t)m * 192 + n] = expf(-d2 * e);
    }
  }
}

// ----------------------------------------------------------------------------
// MLP + batchnorms + gumbel argmax -> sel[32] ; 1 block
// ----------------------------------------------------------------------------
__global__ __launch_bounds__(256) void mlp_kernel(
    const float* pooled, const float* gn,
    const float* p1w, const float* p1b, const float* g1, const float* b1,
    const float* p2w, const float* p2b, const float* g2, const float* b2,
    const float* p3w, const float* p3b, int* sel)
{
  __shared__ float pl[32 * 192];
  __shared__ float h1s[32 * 256];
  __shared__ float h2s[32 * 32];
  int t = threadIdx.x;
  for (int i = t; i < 32 * 192; i += 256) pl[i] = pooled[i];
  __syncthreads();
  {
    float acc[32];
    float bb = p1b[t];
#pragma unroll
    for (int b = 0; b < 32; ++b) acc[b] = bb;
    for (int c = 0; c < 192; ++c) {
      float w = p1w[t * 192 + c];
#pragma unroll
      for (int b = 0; b < 32; ++b) acc[b] += w * pl[b * 192 + c];
    }
    for (int b = 0; b < 32; ++b) {
      float v = acc[b];
      v = v > 0.f ? v : 0.1f * v;
      h1s[b * 256 + t] = v;
    }
  }
  __syncthreads();
  {
    float m = 0.f;
    for (int b = 0; b < 32; ++b) m += h1s[b * 256 + t];
    m *= (1.f / 32.f);
    float v = 0.f;
    for (int b = 0; b < 32; ++b) { float d = h1s[b * 256 + t] - m; v += d * d; }
    v *= (1.f / 32.f);
    float sc = g1[t] / sqrtf(v + 1e-5f);
    float sh = b1[t] - m * sc;
    for (int b = 0; b < 32; ++b) h1s[b * 256 + t] = h1s[b * 256 + t] * sc + sh;
  }
  __syncthreads();
  {
    int j = t & 31, bg = t >> 5;
    float acc[4];
    float bb = p2b[j];
    for (int i = 0; i < 4; ++i) acc[i] = bb;
    for (int c = 0; c < 256; ++c) {
      float w = p2w[j * 256 + c];
#pragma unroll
      for (int i = 0; i < 4; ++i) acc[i] += w * h1s[(bg * 4 + i) * 256 + c];
    }
    for (int i = 0; i < 4; ++i) {
      float v = acc[i];
      v = v > 0.f ? v : 0.1f * v;
      h2s[(bg * 4 + i) * 32 + j] = v;
    }
  }
  __syncthreads();
  if (t < 32) {
    float m = 0.f;
    for (int b = 0; b < 32; ++b) m += h2s[b * 32 + t];
    m *= (1.f / 32.f);
    float v = 0.f;
    for (int b = 0; b < 32; ++b) { float d = h2s[b * 32 + t] - m; v += d * d; }
    v *= (1.f / 32.f);
    float sc = g2[t] / sqrtf(v + 1e-5f);
    float sh = b2[t] - m * sc;
    for (int b = 0; b < 32; ++b) h2s[b * 32 + t] = h2s[b * 32 + t] * sc + sh;
  }
  __syncthreads();
  if (t < 32) {
    float best = -1e30f; int bi = 0;
    for (int r = 0; r < 3; ++r) {
      float l = p3b[r];
      for (int c = 0; c < 32; ++c) l += p3w[r * 32 + c] * h2s[t * 32 + c];
      l += gn[t * 3 + r];
      if (l > best) { best = l; bi = r; }
    }
    sel[t] = bi;
  }
}

// ----------------------------------------------------------------------------
// DCT stage over first axis of (64, 12288), in-place. grid (192, 32)
// ----------------------------------------------------------------------------
__global__ __launch_bounds__(256) void axis0_kernel(
    float* buf, const float* mat, const int* sel, int branch)
{
  int b = blockIdx.y;
  if (sel[b] != branch) return;
  int q0 = blockIdx.x * 64;
  __shared__ float mT[64][65];
  __shared__ float xs[64][65];
  int t = threadIdx.x;
  for (int i = t; i < 4096; i += 256) {
    int r = i >> 6, c = i & 63;
    mT[c][r] = mat[i];
    xs[r][c] = buf[(size_t)b * SLICE + r * 12288 + q0 + c];
  }
  __syncthreads();
  int tx = t & 15, ty = t >> 4;
  float acc[4][4] = {};
  for (int l = 0; l < 64; ++l) {
    float a[4], xv[4];
#pragma unroll
    for (int i = 0; i < 4; ++i) a[i] = mT[l][ty * 4 + i];
#pragma unroll
    for (int j = 0; j < 4; ++j) xv[j] = xs[l][tx * 4 + j];
#pragma unroll
    for (int i = 0; i < 4; ++i)
#pragma unroll
      for (int j = 0; j < 4; ++j) acc[i][j] += a[i] * xv[j];
  }
  float* ob = buf + (size_t)b * SLICE;
  for (int i = 0; i < 4; ++i)
    for (int j = 0; j < 4; ++j)
      ob[(ty * 4 + i) * 12288 + q0 + tx * 4 + j] = acc[i][j];
}

// DCT stage over middle axis, in-place, optional k multiply. grid (192, 32)
__global__ __launch_bounds__(256) void axis1_kernel(
    float* buf, const float* mat, const float* kmul, const int* sel, int branch)
{
  int b = blockIdx.y;
  if (sel[b] != branch) return;
  int n = blockIdx.x / 3;
  int ct = (blockIdx.x - n * 3) * 64;
  float* base = buf + (size_t)b * SLICE + n * (64 * 192) + ct;
  __shared__ float mT[64][65];
  __shared__ float xs[64][65];
  int t = threadIdx.x;
  for (int i = t; i < 4096; i += 256) {
    int r = i >> 6, c = i & 63;
    mT[c][r] = mat[i];
    xs[r][c] = base[r * 192 + c];
  }
  __syncthreads();
  int tx = t & 15, ty = t >> 4;
  float acc[4][4] = {};
  for (int l = 0; l < 64; ++l) {
    float a[4], xv[4];
#pragma unroll
    for (int i = 0; i < 4; ++i) a[i] = mT[l][ty * 4 + i];
#pragma unroll
    for (int j = 0; j < 4; ++j) xv[j] = xs[l][tx * 4 + j];
#pragma unroll
    for (int i = 0; i < 4; ++i)
#pragma unroll
      for (int j = 0; j < 4; ++j) acc[i][j] += a[i] * xv[j];
  }
  if (kmul) {
    for (int i = 0; i < 4; ++i)
      for (int j = 0; j < 4; ++j)
        acc[i][j] *= kmul[(size_t)(n * 64 + ty * 4 + i) * 192 + ct + tx * 4 + j];
  }
  for (int i = 0; i < 4; ++i)
    for (int j = 0; j < 4; ++j)
      base[(ty * 4 + i) * 192 + tx * 4 + j] = acc[i][j];
}

// ----------------------------------------------------------------------------
// FFT forward over h (real -> complex), real in-place into xh, imag -> Si
// ----------------------------------------------------------------------------
__global__ __launch_bounds__(256) void ffth_kernel(
    float* xh, float* Si, const float2* E64, const int* sel)
{
  int b = blockIdx.y;
  if (sel[b] != 1) return;
  int q0 = blockIdx.x * 64;
  __shared__ float er[64][65], ei[64][65], xs[64][65];
  int t = threadIdx.x;
  for (int i = t; i < 4096; i += 256) {
    int r = i >> 6, c = i & 63;
    float2 e = E64[i];
    er[r][c] = e.x; ei[r][c] = e.y;
    xs[r][c] = xh[(size_t)b * SLICE + r * 12288 + q0 + c];
  }
  __syncthreads();
  int tx = t & 15, ty = t >> 4;
  float ar[4][4] = {}, ai[4][4] = {};
  for (int l = 0; l < 64; ++l) {
    float e1[4], e2[4], xv[4];
#pragma unroll
    for (int i = 0; i < 4; ++i) { e1[i] = er[l][ty * 4 + i]; e2[i] = ei[l][ty * 4 + i]; }
#pragma unroll
    for (int j = 0; j < 4; ++j) xv[j] = xs[l][tx * 4 + j];
#pragma unroll
    for (int i = 0; i < 4; ++i)
#pragma unroll
      for (int j = 0; j < 4; ++j) { ar[i][j] += e1[i] * xv[j]; ai[i][j] += e2[i] * xv[j]; }
  }
  size_t ob = (size_t)b * SLICE;
  for (int i = 0; i < 4; ++i)
    for (int j = 0; j < 4; ++j) {
      size_t o = ob + (size_t)(ty * 4 + i) * 12288 + q0 + tx * 4 + j;
      xh[o] = ar[i][j];
      Si[o] = ai[i][j];
    }
}

// FFT over w (complex, in-place). grid (384, 32)
__global__ __launch_bounds__(256) void fftw_kernel(
    float* Sr, float* Si, const float2* E64, const int* sel, float s)
{
  int b = blockIdx.y;
  if (sel[b] != 1) return;
  int kh = blockIdx.x / 6;
  int ct = (blockIdx.x - kh * 6) * 32;
  float* br = Sr + (size_t)b * SLICE + kh * 12288 + ct;
  float* bi = Si + (size_t)b * SLICE + kh * 12288 + ct;
  __shared__ float er[64][65], ei[64][65];
  __shared__ float xr[64][33], xi[64][33];
  int t = threadIdx.x;
  for (int i = t; i < 4096; i += 256) {
    float2 e = E64[i];
    er[i >> 6][i & 63] = e.x;
    ei[i >> 6][i & 63] = s * e.y;
  }
  for (int i = t; i < 2048; i += 256) {
    int l = i >> 5, q = i & 31;
    xr[l][q] = br[l * 192 + q];
    xi[l][q] = bi[l * 192 + q];
  }
  __syncthreads();
  int tx = t & 7, ty = t >> 3;
  float ar[2][4] = {}, ac[2][4] = {};
  for (int l = 0; l < 64; ++l) {
    float e1a = er[l][ty],      e2a = ei[l][ty];
    float e1b = er[l][ty + 32], e2b = ei[l][ty + 32];
#pragma unroll
    for (int j = 0; j < 4; ++j) {
      float vr = xr[l][tx * 4 + j], vi = xi[l][tx * 4 + j];
      ar[0][j] += e1a * vr - e2a * vi;
      ac[0][j] += e1a * vi + e2a * vr;
      ar[1][j] += e1b * vr - e2b * vi;
      ac[1][j] += e1b * vi + e2b * vr;
    }
  }
  for (int r = 0; r < 2; ++r) {
    int kw = ty + r * 32;
    for (int j = 0; j < 4; ++j) {
      br[kw * 192 + tx * 4 + j] = ar[r][j];
      bi[kw * 192 + tx * 4 + j] = ac[r][j];
    }
  }
}

// ----------------------------------------------------------------------------
// DFT-8 butterfly, SGN=-1: X[k]=sum x_n e^{-2pi i nk/8}; SGN=+1: conjugated.
// ----------------------------------------------------------------------------
template<int SGN>
static DEVI void dft8(float* xr, float* xi) {
  const float s = 0.70710678118654752440f;
  float s0r = xr[0] + xr[4], s0i = xi[0] + xi[4];
  float s1r = xr[0] - xr[4], s1i = xi[0] - xi[4];
  float s2r = xr[2] + xr[6], s2i = xi[2] + xi[6];
  float s3r = xr[2] - xr[6], s3i = xi[2] - xi[6];
  float w3r = (SGN < 0) ? s3i : -s3i;
  float w3i = (SGN < 0) ? -s3r : s3r;
  float E0r = s0r + s2r, E0i = s0i + s2i;
  float E2r = s0r - s2r, E2i = s0i - s2i;
  float E1r = s1r + w3r, E1i = s1i + w3i;
  float E3r = s1r - w3r, E3i = s1i - w3i;
  float r0r = xr[1] + xr[5], r0i = xi[1] + xi[5];
  float r1r = xr[1] - xr[5], r1i = xi[1] - xi[5];
  float r2r = xr[3] + xr[7], r2i = xi[3] + xi[7];
  float r3r = xr[3] - xr[7], r3i = xi[3] - xi[7];
  float v3r = (SGN < 0) ? r3i : -r3i;
  float v3i = (SGN < 0) ? -r3r : r3r;
  float O0r = r0r + r2r, O0i = r0i + r2i;
  float O2r = r0r - r2r, O2i = r0i - r2i;
  float O1r = r1r + v3r, O1i = r1i + v3i;
  float O3r = r1r - v3r, O3i = r1i - v3i;
  xr[0] = E0r + O0r; xi[0] = E0i + O0i;
  xr[4] = E0r - O0r; xi[4] = E0i - O0i;
  float t2r = (SGN < 0) ? O2i : -O2i;
  float t2i = (SGN < 0) ? -O2r : O2r;
  xr[2] = E2r + t2r; xi[2] = E2i + t2i;
  xr[6] = E2r - t2r; xi[6] = E2i - t2i;
  float t1r = (SGN < 0) ? s * (O1r + O1i) : s * (O1r - O1i);
  float t1i = (SGN < 0) ? s * (O1i - O1r) : s * (O1r + O1i);
  xr[1] = E1r + t1r; xi[1] = E1i + t1i;
  xr[5] = E1r - t1r; xi[5] = E1i - t1i;
  float t3r = (SGN < 0) ? s * (O3i - O3r) : -s * (O3r + O3i);
  float t3i = (SGN < 0) ? -s * (O3r + O3i) : s * (O3r - O3i);
  xr[3] = E3r + t3r; xi[3] = E3i + t3i;
  xr[7] = E3r - t3r; xi[7] = E3i - t3i;
}

// ----------------------------------------------------------------------------
// Fused c-stage: radix-3 x (radix-8 x radix-8) Cooley-Tukey, fp32 exact.
// grid (128, 32). LDS 51.2 KB -> 3 blocks/CU.
// ----------------------------------------------------------------------------
__global__ __launch_bounds__(256, 3) void fftc_fused_kernel(
    float* Sr, float* Si, const float* kmap, const float2* E64, const int* sel)
{
  int b = blockIdx.y;
  if (sel[b] != 1) return;
  int m0 = blockIdx.x * 32;
  float* gr = Sr + (size_t)b * SLICE + (size_t)m0 * 192;
  float* gi = Si + (size_t)b * SLICE + (size_t)m0 * 192;
  __shared__ __align__(16) float2 T[192][33];
  __shared__ float2 wtab[64];          // w64^n (from E64 row 1)
  int t = threadIdx.x;
  for (int i = t; i < 6144; i += 256) {
    int row = i / 192, c = i - row * 192;
    T[c][row] = make_float2(gr[i], gi[i]);
  }
  if (t < 64) wtab[t] = E64[64 + t];
  __syncthreads();

  float xr[3][8], xim[3][8];

  // ---- fwd stage A ----
#pragma unroll
  for (int it = 0; it < 3; ++it) {
    int g = t + 256 * it;
    int row = g & 31, rest = g >> 5;
    int n1 = rest >> 3, p = rest & 7;
#pragma unroll
    for (int q = 0; q < 8; ++q) {
      float2 v = T[3 * (p + 8 * q) + n1][row];
      xr[it][q] = v.x; xim[it][q] = v.y;
    }
    dft8<-1>(xr[it], xim[it]);
#pragma unroll
    for (int j = 1; j < 8; ++j) {
      float2 w = wtab[p * j];
      float a = xr[it][j], bb = xim[it][j];
      xr[it][j]  = a * w.x - bb * w.y;
      xim[it][j] = a * w.y + bb * w.x;
    }
  }
  __syncthreads();
#pragma unroll
  for (int it = 0; it < 3; ++it) {
    int g = t + 256 * it;
    int row = g & 31, rest = g >> 5;
    int n1 = rest >> 3, p = rest & 7;
#pragma unroll
    for (int j = 0; j < 8; ++j)
      T[n1 * 64 + p * 8 + j][row] = make_float2(xr[it][j], xim[it][j]);
  }
  __syncthreads();

  // ---- fwd stage B ----
#pragma unroll
  for (int it = 0; it < 3; ++it) {
    int g = t + 256 * it;
    int row = g & 31, rest = g >> 5;
    int n1 = rest >> 3, j = rest & 7;
#pragma unroll
    for (int p = 0; p < 8; ++p) {
      float2 v = T[n1 * 64 + p * 8 + j][row];
      xr[it][p] = v.x; xim[it][p] = v.y;
    }
    dft8<-1>(xr[it], xim[it]);
  }
  __syncthreads();
#pragma unroll
  for (int it = 0; it < 3; ++it) {
    int g = t + 256 * it;
    int row = g & 31, rest = g >> 5;
    int n1 = rest >> 3, j = rest & 7;
#pragma unroll
    for (int m2 = 0; m2 < 8; ++m2)
      T[n1 * 64 + j + 8 * m2][row] = make_float2(xr[it][m2], xim[it][m2]);
  }
  __syncthreads();

  // ---- middle: W192 twiddle + radix-3 + k + inverse (owner-exclusive) ----
  {
    int tx = t & 31, ty = t >> 5;
    int rbase = ty * 4;
    double A = 2.0 * 3.14159265358979323846 * (double)tx;
    double sb, cb;
    sincos(A / 192.0, &sb, &cb);
    float cw = (float)cb, sw = (float)sb;
    const float S3 = 0.86602540378443864676f;
    float w1r[2], w1i[2], w2r[2], w2i[2];
    w1r[0] = cw;                   w1i[0] = -sw;
    w1r[1] = 0.5f * cw - S3 * sw;  w1i[1] = -S3 * cw - 0.5f * sw;
#pragma unroll
    for (int u = 0; u < 2; ++u) {
      w2r[u] = w1r[u] * w1r[u] - w1i[u] * w1i[u];
      w2i[u] = 2.f * w1r[u] * w1i[u];
    }
    float ar[2][3][4], ai[2][3][4];
#pragma unroll
    for (int u = 0; u < 2; ++u)
#pragma unroll
      for (int n1 = 0; n1 < 3; ++n1)
#pragma unroll
        for (int r = 0; r < 4; ++r) {
          float2 v = T[n1 * 64 + tx + 32 * u][rbase + r];
          ar[u][n1][r] = v.x; ai[u][n1][r] = v.y;
        }
    const float SCALE = 1.0f / 786432.0f;
#pragma unroll
    for (int u = 0; u < 2; ++u) {
      int m = tx + 32 * u;
#pragma unroll
      for (int r = 0; r < 4; ++r) {
        int row = rbase + r;
        float Y0r = ar[u][0][r], Y0i = ai[u][0][r];
        float Y1r = ar[u][1][r], Y1i = ai[u][1][r];
        float Y2r = ar[u][2][r], Y2i = ai[u][2][r];
        float T1r = Y1r * w1r[u] - Y1i * w1i[u];
        float T1i = Y1r * w1i[u] + Y1i * w1r[u];
        float T2r = Y2r * w2r[u] - Y2i * w2i[u];
        float T2i = Y2r * w2i[u] + Y2i * w2r[u];
        float aRr = T1r + T2r, aRi = T1i + T2i;
        float bRr = T1r - T2r, bRi = T1i - T2i;
        float X0r = Y0r + aRr, X0i = Y0i + aRi;
        float cfr = Y0r - 0.5f * aRr, cfi = Y0i - 0.5f * aRi;
        float X1r = cfr + S3 * bRi, X1i = cfi - S3 * bRr;
        float X2r = cfr - S3 * bRi, X2i = cfi + S3 * bRr;
        const float* kp = kmap + (size_t)(m0 + row) * 192 + m;
        float k0 = kp[0] * SCALE, k1 = kp[64] * SCALE, k2 = kp[128] * SCALE;
        X0r *= k0; X0i *= k0; X1r *= k1; X1i *= k1; X2r *= k2; X2i *= k2;
        float a2r = X1r + X2r, a2i = X1i + X2i;
        float b2r = X1r - X2r, b2i = X1i - X2i;
        float U0r = X0r + a2r, U0i = X0i + a2i;
        float c2r = X0r - 0.5f * a2r, c2i = X0i - 0.5f * a2i;
        float U1r = c2r - S3 * b2i, U1i = c2i + S3 * b2r;
        float U2r = c2r + S3 * b2i, U2i = c2i - S3 * b2r;
        ar[u][0][r] = U0r;
        ai[u][0][r] = U0i;
        ar[u][1][r] = U1r * w1r[u] + U1i * w1i[u];
        ai[u][1][r] = U1i * w1r[u] - U1r * w1i[u];
        ar[u][2][r] = U2r * w2r[u] + U2i * w2i[u];
        ai[u][2][r] = U2i * w2r[u] - U2r * w2i[u];
      }
    }
#pragma unroll
    for (int u = 0; u < 2; ++u)
#pragma unroll
      for (int n1 = 0; n1 < 3; ++n1)
#pragma unroll
        for (int r = 0; r < 4; ++r)
          T[n1 * 64 + tx + 32 * u][rbase + r] =
              make_float2(ar[u][n1][r], ai[u][n1][r]);
  }
  __syncthreads();

  // ---- inv stage A' ----
#pragma unroll
  for (int it = 0; it < 3; ++it) {
    int g = t + 256 * it;
    int row = g & 31, rest = g >> 5;
    int n1 = rest >> 3, mu = rest & 7;
#pragma unroll
    for (int nu = 0; nu < 8; ++nu) {
      float2 v = T[n1 * 64 + mu + 8 * nu][row];
      xr[it][nu] = v.x; xim[it][nu] = v.y;
    }
    dft8<1>(xr[it], xim[it]);
#pragma unroll
    for (int a = 1; a < 8; ++a) {
      float2 w = wtab[(mu * a) & 63];
      float aa = xr[it][a], bb = xim[it][a];
      xr[it][a]  = aa * w.x + bb * w.y;     // * conj(w)
      xim[it][a] = bb * w.x - aa * w.y;
    }
  }
  __syncthreads();
#pragma unroll
  for (int it = 0; it < 3; ++it) {
    int g = t + 256 * it;
    int row = g & 31, rest = g >> 5;
    int n1 = rest >> 3, mu = rest & 7;
#pragma unroll
    for (int a = 0; a < 8; ++a)
      T[n1 * 64 + mu * 8 + a][row] = make_float2(xr[it][a], xim[it][a]);
  }
  __syncthreads();

  // ---- inv stage B' ----
#pragma unroll
  for (int it = 0; it < 3; ++it) {
    int g = t + 256 * it;
    int row = g & 31, rest = g >> 5;
    int n1 = rest >> 3, aa = rest & 7;
#pragma unroll
    for (int mu = 0; mu < 8; ++mu) {
      float2 v = T[n1 * 64 + mu * 8 + aa][row];
      xr[it][mu] = v.x; xim[it][mu] = v.y;
    }
    dft8<1>(xr[it], xim[it]);
  }
  __syncthreads();
#pragma unroll
  for (int it = 0; it < 3; ++it) {
    int g = t + 256 * it;
    int row = g & 31, rest = g >> 5;
    int n1 = rest >> 3, aa = rest & 7;
#pragma unroll
    for (int bq = 0; bq < 8; ++bq)
      T[3 * (aa + 8 * bq) + n1][row] = make_float2(xr[it][bq], xim[it][bq]);
  }
  __syncthreads();

  for (int i = t; i < 6144; i += 256) {
    int row = i / 192, c = i - row * 192;
    float2 v = T[c][row];
    gr[i] = v.x;
    gi[i] = v.y;
  }
}

// inverse h-stage, real part only, in-place into xh. grid (384, 32)
__global__ __launch_bounds__(256) void ffthi_kernel(
    float* Sr, const float* Si, const float2* E64, const int* sel)
{
  int b = blockIdx.y;
  if (sel[b] != 1) return;
  int q0 = blockIdx.x * 32;
  __shared__ float er[64][65], ei[64][65];
  __shared__ float xr[64][33], xi[64][33];
  int t = threadIdx.x;
  for (int i = t; i < 4096; i += 256) {
    float2 e = E64[i];
    er[i >> 6][i & 63] = e.x;
    ei[i >> 6][i & 63] = e.y;
  }
  for (int i = t; i < 2048; i += 256) {
    int l = i >> 5, q = i & 31;
    size_t o = (size_t)b * SLICE + (size_t)l * 12288 + q0 + q;
    xr[l][q] = Sr[o];
    xi[l][q] = Si[o];
  }
  __syncthreads();
  int tx = t & 7, ty = t >> 3;
  float acc[2][4] = {};
  for (int l = 0; l < 64; ++l) {
    float e1a = er[l][ty],      e2a = ei[l][ty];
    float e1b = er[l][ty + 32], e2b = ei[l][ty + 32];
#pragma unroll
    for (int j = 0; j < 4; ++j) {
      float vr = xr[l][tx * 4 + j], vi = xi[l][tx * 4 + j];
      acc[0][j] += e1a * vr + e2a * vi;
      acc[1][j] += e1b * vr + e2b * vi;
    }
  }
  for (int r = 0; r < 2; ++r) {
    int h = ty + r * 32;
    for (int j = 0; j < 4; ++j)
      Sr[(size_t)b * SLICE + (size_t)h * 12288 + q0 + tx * 4 + j] = acc[r][j];
  }
}

// ----------------------------------------------------------------------------
// Haar branch, in-place on xh. grid (128, 32)
// ----------------------------------------------------------------------------
__global__ __launch_bounds__(256) void haar_kernel(
    float* xh, const float* kmap, const int* sel)
{
  int b = blockIdx.y;
  if (sel[b] != 2) return;
  int h = blockIdx.x >> 1;
  int w0 = (blockIdx.x & 1) * 32;
  size_t base = (size_t)b * SLICE + ((size_t)h * 64 + w0) * 192;
  __shared__ float A[32 * 192];
  __shared__ float Bf[32 * 192];
  int t = threadIdx.x;
  for (int i = t; i < 6144; i += 256) A[i] = xh[base + i];
  __syncthreads();
  for (int u = t; u < 32 * 96; u += 256) {
    int p = u / 96, r = u - p * 96;
    int ch = r >> 5, i = r & 31;
    float v0 = A[p * 192 + ch * 64 + 2 * i];
    float v1 = A[p * 192 + ch * 64 + 2 * i + 1];
    Bf[p * 192 + ch * 64 + i]      = (v0 + v1) * 0.5f;
    Bf[p * 192 + ch * 64 + 32 + i] = (v0 - v1) * 0.5f;
  }
  __syncthreads();
  for (int u = t; u < 32 * 96; u += 256) {
    int p = u / 96, i = u - p * 96;
    float v0 = Bf[p * 192 + 2 * i];
    float v1 = Bf[p * 192 + 2 * i + 1];
    A[p * 192 + i]      = (v0 + v1) * 0.5f;
    A[p * 192 + 96 + i] = (v0 - v1) * 0.5f;
  }
  __syncthreads();
  for (int i = t; i < 6144; i += 256)
    A[i] *= kmap[((size_t)h * 64 + w0) * 192 + i];
  __syncthreads();
  for (int u = t; u < 32 * 96; u += 256) {
    int p = u / 96, r = u - p * 96;
    int ch = r >> 5, i = r & 31;
    float a = A[p * 192 + ch * 64 + i];
    float d = A[p * 192 + ch * 64 + 32 + i];
    Bf[p * 192 + ch * 64 + 2 * i]     = a + d;
    Bf[p * 192 + ch * 64 + 2 * i + 1] = a - d;
  }
  __syncthreads();
  for (int u = t; u < 32 * 96; u += 256) {
    int p = u / 96, i = u - p * 96;
    float a = Bf[p * 192 + i];
    float d = Bf[p * 192 + 96 + i];
    A[p * 192 + 2 * i]     = a + d;
    A[p * 192 + 2 * i + 1] = a - d;
  }
  __syncthreads();
  for (int i = t; i < 6144; i += 256) xh[base + i] = A[i];
}

// ----------------------------------------------------------------------------
// final: LN(c) * silu(z) @ out_w^T + out_b via bf16 MFMA, dual-dtype store.
// grid 2048.
// ----------------------------------------------------------------------------
__global__ __launch_bounds__(256) void final_kernel(
    const float* comb, const bf16* zb, const float* lng, const float* lnb,
    const bf16* Ob, const float* outb, void* outp, const int* flag)
{
  int flg = *flag;
  int bi = blockIdx.x;
  int b = bi >> 6, h = bi & 63;
  size_t base = ((size_t)b * 4096 + (size_t)h * 64) * 192;
  __shared__ float As[12672];                  // max(64*196, 192*66)
  __shared__ __align__(16) short Ab[64 * 200];
  __shared__ float red[2][4][64];
  __shared__ float mu[64], rs[64];
  int t = threadIdx.x;
  for (int idx = t; idx < 3072; idx += 256) {
    int q = idx << 2;
    int p = idx / 48, c = q - p * 192;
    float4 v = *(const float4*)&comb[base + q];
    v.x = scrub(v.x); v.y = scrub(v.y); v.z = scrub(v.z); v.w = scrub(v.w);
    *(float4*)&As[p * 196 + c] = v;
  }
  __syncthreads();
  {
    int r = t & 63, part = t >> 6;
    const float* row = &As[r * 196 + part * 48];
    float s = 0.f, s2 = 0.f;
    for (int c = 0; c < 48; ++c) { float v = row[c]; s += v; s2 += v * v; }
    red[0][part][r] = s;
    red[1][part][r] = s2;
  }
  __syncthreads();
  if (t < 64) {
    float s  = red[0][0][t] + red[0][1][t] + red[0][2][t] + red[0][3][t];
    float s2 = red[1][0][t] + red[1][1][t] + red[1][2][t] + red[1][3][t];
    float m = s * (1.f / 192.f);
    float v = s2 * (1.f / 192.f) - m * m;
    v = v > 0.f ? v : 0.f;
    mu[t] = m;
    rs[t] = 1.f / sqrtf(v + 1e-5f);
  }
  __syncthreads();
  for (int idx = t; idx < 1536; idx += 256) {
    int q = idx << 3;
    int p = idx / 24, c = q - p * 192;
    float4 a0 = *(const float4*)&As[p * 196 + c];
    float4 a1 = *(const float4*)&As[p * 196 + c + 4];
    short8v z8 = *(const short8v*)&zb[base + q];
    float av[8] = {a0.x, a0.y, a0.z, a0.w, a1.x, a1.y, a1.z, a1.w};
    short o8[8];
    float m = mu[p], r = rs[p];
#pragma unroll
    for (int j = 0; j < 8; ++j) {
      float v = (av[j] - m) * r * lng[c + j] + lnb[c + j];
      float zv = scrub(bitsbf((unsigned short)z8[j]));
      v *= zv / (1.f + expf(-zv));
      o8[j] = f2bs(v);
    }
    *(short8v*)&Ab[p * 200 + c] = *(short8v*)o8;
  }
  __syncthreads();
  int wave = t >> 6, lane = t & 63;
  int lq = lane >> 4, lr = lane & 15;
  int n0 = wave * 48;
  float4v acc[4][3];
#pragma unroll
  for (int i = 0; i < 4; ++i)
#pragma unroll
    for (int j = 0; j < 3; ++j) acc[i][j] = (float4v){0.f, 0.f, 0.f, 0.f};
  for (int k0 = 0; k0 < 192; k0 += 32) {
    short8v af[4], bfr[3];
#pragma unroll
    for (int f = 0; f < 4; ++f)
      af[f] = *(const short8v*)&Ab[(f * 16 + lr) * 200 + k0 + lq * 8];
#pragma unroll
    for (int f = 0; f < 3; ++f)
      bfr[f] = *(const short8v*)&Ob[(size_t)(n0 + f * 16 + lr) * 192 + k0 + lq * 8];
#pragma unroll
    for (int fm = 0; fm < 4; ++fm)
#pragma unroll
      for (int fn = 0; fn < 3; ++fn)
        acc[fm][fn] = __builtin_amdgcn_mfma_f32_16x16x32_bf16(
            af[fm], bfr[fn], acc[fm][fn], 0, 0, 0);
  }
  __syncthreads();
#pragma unroll
  for (int fm = 0; fm < 4; ++fm)
#pragma unroll
    for (int e = 0; e < 4; ++e) {
      int p = fm * 16 + lq * 4 + e;
#pragma unroll
      for (int fn = 0; fn < 3; ++fn) {
        int co = n0 + fn * 16 + lr;
        As[co * 66 + p] = acc[fm][fn][e] + outb[co];
      }
    }
  __syncthreads();
  for (int e = t; e < 12288; e += 256) {
    int co = e >> 6, w = e & 63;
    size_t oi = (((size_t)b * 192 + co) * 64 + h) * 64 + w;
    float v = As[co * 66 + w];
    if (flg) ((float*)outp)[oi] = v;
    else     ((bf16*)outp)[oi] = __float2bfloat16(v);
  }
}

// ----------------------------------------------------------------------------
extern "C" void kernel_launch(void* const* d_in, const int* in_sizes, int n_in,
                              void* d_out, int out_size, void* d_ws, size_t ws_size,
                              hipStream_t stream) {
  (void)in_sizes; (void)n_in;
  if (ws_size < WS_NEEDED_BYTES) {
    fill_zero_kernel<<<(out_size + 255) / 256, 256, 0, stream>>>(
        (unsigned short*)d_out, out_size);
    return;
  }
  float* ws    = (float*)d_ws;
  float* xh    = ws + O_XH;
  float* Si    = ws + O_SI;
  bf16*  Yb    = (bf16*)(ws + O_YB);
  float* part  = ws + O_PART;
  bf16*  Wb    = (bf16*)(ws + O_WB);
  bf16*  zb    = (bf16*)(ws + O_ZB);
  float* kmap  = ws + O_KMAP;
  float2* E64  = (float2*)(ws + O_E64);
  float* Dm    = ws + O_DM;
  float* DT    = ws + O_DT;
  bf16*  Ob    = (bf16*)(ws + O_WT);
  float* pooled= ws + O_POOL;
  int*   sel   = (int*)(ws + O_SEL);
  int*   flag  = (int*)(ws + O_FLAG);

  sniff_kernel<<<1, 64, 0, stream>>>((const unsigned short*)d_in[0], flag);

  CvtArgs ca;
  const int srcidx[22] = {2,3,4,5,6,7,8,9,10,11,12,13,14,15,16,17,18,19,20,21,22,1};
  const int ns[22] = {96,1728,192,73728,384,49152,256,256,256,8192,32,32,32,96,3,
                      36864,192,192,192,36864,192,786432};
  const long long offs[22] = {
    (long long)W_GN,(long long)W_DWW,(long long)W_DWB,(long long)W_LINW,
    (long long)W_LINB,(long long)W_P1W,(long long)W_P1B,(long long)W_G1,
    (long long)W_B1,(long long)W_P2W,(long long)W_P2B,(long long)W_G2,
    (long long)W_B2,(long long)W_P3W,(long long)W_P3B,(long long)W_TOKW,
    (long long)W_TOKB,(long long)W_LNG,(long long)W_LNB,(long long)W_OUTW,
    (long long)W_OUTB,(long long)O_FREQ};
  for (int i = 0; i < 22; ++i) { ca.src[i] = d_in[srcidx[i]]; ca.n[i] = ns[i]; ca.off[i] = offs[i]; }
  cvt_kernel<<<64, 256, 0, stream>>>(ca, ws, flag);

  setup_kernel<<<64, 256, 0, stream>>>(Dm, DT, E64, Ob, ws + W_OUTW, Wb, ws + W_LINW);
  conv_kernel<<<dim3(6, 16, 32), 256, 0, stream>>>(d_in[0], flag, ws + W_DWW, ws + W_DWB,
                                                   Yb, part);
  linear_mfma_kernel<<<dim3(1024, 3), 256, 0, stream>>>(Yb, Wb, ws + W_LINB, xh, zb);
  pooled_kernel<<<12, 256, 0, stream>>>(part, ws + W_LINW, ws + W_LINB, pooled);
  mlp_kernel<<<1, 256, 0, stream>>>(pooled, ws + W_GN,
      ws + W_P1W, ws + W_P1B, ws + W_G1, ws + W_B1,
      ws + W_P2W, ws + W_P2B, ws + W_G2, ws + W_B2,
      ws + W_P3W, ws + W_P3B, sel);
  kmap_kernel<<<dim3(64, 3), 256, 0, stream>>>(ws + O_FREQ, ws + W_TOKW, ws + W_TOKB, kmap);
  // DCT branch (sel==0), in-place on xh
  axis0_kernel<<<dim3(192, 32), 256, 0, stream>>>(xh, Dm, sel, 0);
  axis1_kernel<<<dim3(192, 32), 256, 0, stream>>>(xh, Dm, kmap, sel, 0);
  axis1_kernel<<<dim3(192, 32), 256, 0, stream>>>(xh, DT, nullptr, sel, 0);
  axis0_kernel<<<dim3(192, 32), 256, 0, stream>>>(xh, DT, sel, 0);
  // FFT branch (sel==1); b-axis FFT/IFFT cancels analytically; in-place (xh,Si)
  ffth_kernel<<<dim3(192, 32), 256, 0, stream>>>(xh, Si, E64, sel);
  fftw_kernel<<<dim3(384, 32), 256, 0, stream>>>(xh, Si, E64, sel, 1.f);
  fftc_fused_kernel<<<dim3(128, 32), 256, 0, stream>>>(xh, Si, kmap, E64, sel);
  fftw_kernel<<<dim3(384, 32), 256, 0, stream>>>(xh, Si, E64, sel, -1.f);
  ffthi_kernel<<<dim3(384, 32), 256, 0, stream>>>(xh, Si, E64, sel);
  // Haar branch (sel==2), in-place on xh
  haar_kernel<<<dim3(128, 32), 256, 0, stream>>>(xh, kmap, sel);
  // epilogue
  final_kernel<<<2048, 256, 0, stream>>>(xh, zb, ws + W_LNG, ws + W_LNB,
                                         Ob, ws + W_OUTB, d_out, flag);
}

// Round 7
// 839.208 us; speedup vs baseline: 2.3790x; 1.2042x over previous
//
#include <hip/hip_runtime.h>
#include <hip/hip_bf16.h>
#include <math.h>

typedef __hip_bfloat16 bf16;
#define DEVI __device__ __forceinline__
static DEVI float b2f(bf16 v) { return __bfloat162float(v); }
static DEVI float scrub(float v) { return (v - v == 0.f) ? v : 0.f; }
static DEVI float bitsbf(unsigned short u) {
  union { unsigned int i; float f; } x; x.i = ((unsigned int)u) << 16; return x.f;
}
static DEVI short f2bs(float v) {
  bf16 h = __float2bfloat16(v); return *(short*)&h;
}

typedef __attribute__((ext_vector_type(8))) short short8v;   // 8 bf16 (4 VGPR)
typedef __attribute__((ext_vector_type(4))) float float4v;   // MFMA acc

constexpr int SLICE = 64 * 64 * 192;           // per-b elements = 786432

// ws layout (float offsets). Total 64,755,812 floats = 259,023,248 B (~247 MiB)
constexpr size_t O_XH   = 0;          // 25165824
constexpr size_t O_SI   = 25165824;   // 25165824 (imag buffer for FFT branch)
constexpr size_t O_ZB   = 50331648;   // bf16 z (25165824 elems = 12582912 slots)
constexpr size_t O_KMAP = 62914560;   // 786432
constexpr size_t O_FREQ = 63700992;   // 786432 (converted fp32 freq_embed)
constexpr size_t O_E64  = 64487424;   // 8192 (4096 float2)
constexpr size_t O_DM   = 64495616;   // 4096
constexpr size_t O_DT   = 64499712;   // 4096
constexpr size_t O_WT   = 64503808;   // 36864 (bf16 out_w, 36864 elems = 18432 slots)
constexpr size_t O_POOL = 64540672;   // 6144
constexpr size_t O_SEL  = 64546816;   // 32
constexpr size_t O_FLAG = 64546848;   // 32 (flag int + pad)
constexpr size_t O_W    = 64546880;   // 208932 packed fp32 weights
constexpr size_t WS_NEEDED_BYTES = (size_t)64755812 * 4;

// transient aliases inside O_SI (dead before ffth writes Si):
constexpr size_t O_YB   = O_SI;             // bf16 y, 25165824 elems (12582912 slots)
constexpr size_t O_PART = O_SI + 12600000;  // fp32 partial pooled [32][64][192] = 393216
constexpr size_t O_WB   = O_SI + 13100000;  // bf16 lin_w, 73728 elems (36864 slots)

// packed-weight offsets (relative to ws base)
constexpr size_t W_GN   = O_W + 0;      // 96
constexpr size_t W_DWW  = O_W + 96;     // 1728
constexpr size_t W_DWB  = O_W + 1824;   // 192
constexpr size_t W_LINW = O_W + 2016;   // 73728
constexpr size_t W_LINB = O_W + 75744;  // 384
constexpr size_t W_P1W  = O_W + 76128;  // 49152
constexpr size_t W_P1B  = O_W + 125280; // 256
constexpr size_t W_G1   = O_W + 125536; // 256
constexpr size_t W_B1   = O_W + 125792; // 256
constexpr size_t W_P2W  = O_W + 126048; // 8192
constexpr size_t W_P2B  = O_W + 134240; // 32
constexpr size_t W_G2   = O_W + 134272; // 32
constexpr size_t W_B2   = O_W + 134304; // 32
constexpr size_t W_P3W  = O_W + 134336; // 96
constexpr size_t W_P3B  = O_W + 134432; // 4 (3 used)
constexpr size_t W_TOKW = O_W + 134436; // 36864
constexpr size_t W_TOKB = O_W + 171300; // 192
constexpr size_t W_LNG  = O_W + 171492; // 192
constexpr size_t W_LNB  = O_W + 171684; // 192
constexpr size_t W_OUTW = O_W + 171876; // 36864
constexpr size_t W_OUTB = O_W + 208740; // 192

struct CvtArgs {
  const void* src[22];
  int n[22];
  long long off[22];   // float offset into ws
};

// ----------------------------------------------------------------------------
// dtype sniff
// ----------------------------------------------------------------------------
__global__ void sniff_kernel(const unsigned short* xu, int* flag) {
  __shared__ int cnt;
  if (threadIdx.x == 0) cnt = 0;
  __syncthreads();
  unsigned short u = xu[threadIdx.x];
  int e = (u >> 7) & 0xFF;
  int sane = ((e >= 97 && e <= 160) || (u & 0x7FFF) == 0) ? 1 : 0;
  atomicAdd(&cnt, sane);
  __syncthreads();
  if (threadIdx.x == 0) *flag = (cnt >= 56) ? 0 : 1;
}

// convert all small inputs (+freq) to fp32 in ws, per flag
__global__ __launch_bounds__(256) void cvt_kernel(CvtArgs a, float* ws, const int* flag) {
  int flg = *flag;
  int gt = blockIdx.x * 256 + threadIdx.x;
  int gs = gridDim.x * 256;
  for (int s = 0; s < 22; ++s) {
    const void* sp = a.src[s];
    int n = a.n[s];
    float* dst = ws + a.off[s];
    if (flg) {
      const float* f = (const float*)sp;
      for (int i = gt; i < n; i += gs) dst[i] = f[i];
    } else {
      const bf16* h = (const bf16*)sp;
      for (int i = gt; i < n; i += gs) dst[i] = b2f(h[i]);
    }
  }
}

// fallback: zero-fill
__global__ __launch_bounds__(256) void fill_zero_kernel(unsigned short* out, int n) {
  int i = blockIdx.x * 256 + threadIdx.x;
  if (i < n) out[i] = 0;
}

// ----------------------------------------------------------------------------
// setup: DCT matrices, E64 twiddles, bf16 out_w copy, bf16 lin_w copy
// ----------------------------------------------------------------------------
__global__ __launch_bounds__(256) void setup_kernel(
    float* Dm, float* DT, float2* E64, bf16* Ob, const float* out_w,
    bf16* Wb, const float* lin_w)
{
  int t = blockIdx.x * 256 + threadIdx.x;
  int NTH = gridDim.x * 256;
  const double PI = 3.14159265358979323846;
  for (int i = t; i < 64 * 64; i += NTH) {
    int n = i >> 6, x = i & 63;
    double v = cos((double)n * (((double)x + 0.5) / 64.0) * PI) * sqrt(2.0 / 64.0);
    if (n == 0) v *= 0.70710678118654752440;
    Dm[n * 64 + x] = (float)v;
    DT[x * 64 + n] = (float)v;
  }
  for (int i = t; i < 64 * 64; i += NTH) {
    int k = i >> 6, n = i & 63;
    int m = (k * n) & 63;
    double th = -2.0 * PI * (double)m / 64.0;
    E64[i] = make_float2((float)cos(th), (float)sin(th));
  }
  for (int i = t; i < 192 * 192; i += NTH)
    Ob[i] = __float2bfloat16(out_w[i]);
  for (int i = t; i < 384 * 192; i += NTH)
    Wb[i] = __float2bfloat16(lin_w[i]);
}

// ----------------------------------------------------------------------------
// depthwise 3x3 conv (NCHW in, NHWC bf16 out), pad 1. grid (6,16,32)
// ----------------------------------------------------------------------------
__global__ __launch_bounds__(256) void conv_kernel(
    const void* xin, const int* flag, const float* dww, const float* dwb,
    bf16* out, float* partial)
{
  int flg = *flag;
  const float* xf = (const float*)xin;
  const bf16*  xb = (const bf16*)xin;
  int c0 = blockIdx.x * 32;
  int h0 = blockIdx.y * 4;
  int b  = blockIdx.z;
  __shared__ float in_s[6][32][67];
  __shared__ float wg[32][10];
  __shared__ float bias[32];
  int t = threadIdx.x;
#pragma unroll
  for (int i = 0; i < 12; ++i) {
    int idx = t + 256 * i;
    int r  = idx >> 9;           // 0..5
    int ci = (idx >> 4) & 31;
    int qw = idx & 15;
    int hh = h0 + r - 1;
    float4 v = make_float4(0.f, 0.f, 0.f, 0.f);
    if (hh >= 0 && hh < 64) {
      size_t ix = (((size_t)b * 192 + c0 + ci) * 64 + hh) * 64 + qw * 4;
      if (flg) {
        v = *(const float4*)&xf[ix];
      } else {
        short4 s = *(const short4*)&xb[ix];
        v.x = bitsbf((unsigned short)s.x); v.y = bitsbf((unsigned short)s.y);
        v.z = bitsbf((unsigned short)s.z); v.w = bitsbf((unsigned short)s.w);
      }
    }
    float* d = &in_s[r][ci][1 + qw * 4];
    d[0] = v.x; d[1] = v.y; d[2] = v.z; d[3] = v.w;
  }
  for (int i = t; i < 384; i += 256) {
    int r = i >> 6, rem = i & 63;
    int ci = rem >> 1, side = rem & 1;
    in_s[r][ci][side ? 65 : 0] = 0.f;
  }
  for (int idx = t; idx < 288; idx += 256) {
    int ci = idx / 9;
    wg[ci][idx - ci * 9] = dww[(c0 + ci) * 9 + (idx - ci * 9)];
  }
  if (t < 32) bias[t] = dwb[c0 + t];
  __syncthreads();
  int cc = t & 31, wq = t >> 5;
  int w0 = wq * 8;
  float w_[9];
#pragma unroll
  for (int k = 0; k < 9; ++k) w_[k] = wg[cc][k];
  float bs = bias[cc];
  float lsum[4];
#pragma unroll
  for (int hr = 0; hr < 4; ++hr) {
    float rowv[3][10];
#pragma unroll
    for (int r = 0; r < 3; ++r)
#pragma unroll
      for (int q = 0; q < 10; ++q)
        rowv[r][q] = in_s[hr + r][cc][w0 + q];
    float ls = 0.f;
#pragma unroll
    for (int j = 0; j < 8; ++j) {
      float acc = bs;
#pragma unroll
      for (int r = 0; r < 3; ++r)
#pragma unroll
        for (int kw = 0; kw < 3; ++kw)
          acc += rowv[r][j + kw] * w_[r * 3 + kw];
      out[(((size_t)b * 64 + h0 + hr) * 64 + w0 + j) * 192 + c0 + cc] =
          __float2bfloat16(acc);
      ls += scrub(acc);
    }
    lsum[hr] = ls;
  }
  __syncthreads();
  float* ps = &in_s[0][0][0];
#pragma unroll
  for (int hr = 0; hr < 4; ++hr)
    ps[(wq * 4 + hr) * 33 + cc] = lsum[hr];
  __syncthreads();
  if (t < 128) {
    int hr = t >> 5, ci = t & 31;
    float s = 0.f;
#pragma unroll
    for (int r = 0; r < 8; ++r) s += ps[(r * 4 + hr) * 33 + ci];
    partial[((size_t)b * 64 + h0 + hr) * 192 + c0 + ci] = s;
  }
}

// ----------------------------------------------------------------------------
// linear via bf16 MFMA. grid (1024, 3).
// ----------------------------------------------------------------------------
__global__ __launch_bounds__(256) void linear_mfma_kernel(
    const bf16* Yb, const bf16* Wb, const float* bias, float* xh, bf16* zb)
{
  __shared__ __align__(16) short Asm[128 * 40];
  __shared__ __align__(16) short Bsm[128 * 40];
  int m0 = blockIdx.x * 128, n0 = blockIdx.y * 128;
  int t = threadIdx.x;
  int wave = t >> 6, lane = t & 63;
  int wm = (wave & 1) * 64, wn = (wave >> 1) * 64;
  int lq = lane >> 4, lr = lane & 15;
  float4v acc[4][4];
#pragma unroll
  for (int i = 0; i < 4; ++i)
#pragma unroll
    for (int j = 0; j < 4; ++j) acc[i][j] = (float4v){0.f, 0.f, 0.f, 0.f};

  for (int k0 = 0; k0 < 192; k0 += 32) {
#pragma unroll
    for (int i = 0; i < 4; ++i) {
      int ch = t + 256 * i;
      int isB = ch >> 9, c = ch & 511;
      int r = c >> 2, kc = c & 3;
      const bf16* src = isB ? (Wb + (size_t)(n0 + r) * 192 + k0 + kc * 8)
                            : (Yb + (size_t)(m0 + r) * 192 + k0 + kc * 8);
      float4 v = *(const float4*)src;
      short* dst = (isB ? Bsm : Asm) + r * 40 + kc * 8;
      *(float4*)dst = v;
    }
    __syncthreads();
    short8v af[4], bfr[4];
#pragma unroll
    for (int f = 0; f < 4; ++f) {
      af[f]  = *(const short8v*)&Asm[(wm + f * 16 + lr) * 40 + lq * 8];
      bfr[f] = *(const short8v*)&Bsm[(wn + f * 16 + lr) * 40 + lq * 8];
    }
#pragma unroll
    for (int fm = 0; fm < 4; ++fm)
#pragma unroll
      for (int fn = 0; fn < 4; ++fn)
        acc[fm][fn] = __builtin_amdgcn_mfma_f32_16x16x32_bf16(
            af[fm], bfr[fn], acc[fm][fn], 0, 0, 0);
    __syncthreads();
  }
#pragma unroll
  for (int fm = 0; fm < 4; ++fm)
#pragma unroll
    for (int e = 0; e < 4; ++e) {
      int m = m0 + wm + fm * 16 + lq * 4 + e;
#pragma unroll
      for (int fn = 0; fn < 4; ++fn) {
        int n = n0 + wn + fn * 16 + lr;
        float v = acc[fm][fn][e] + bias[n];
        if (n < 192) xh[(size_t)m * 192 + n] = v;
        else         zb[(size_t)m * 192 + (n - 192)] = __float2bfloat16(v);
      }
    }
}

// ----------------------------------------------------------------------------
// pooled = mean_hw(y) @ lin_w[0:192]^T + lin_b  (fp32-exact sel path)
// ----------------------------------------------------------------------------
__global__ __launch_bounds__(256) void pooled_kernel(
    const float* partial, const float* linW, const float* linB, float* pooled)
{
  __shared__ float pcs[32 * 193];
  int t = threadIdx.x;
  int c0 = blockIdx.x * 16;
  for (int i = t; i < 6144; i += 256) {
    int b = i / 192, c = i - b * 192;
    float s = 0.f;
    const float* p = partial + (size_t)b * 64 * 192 + c;
    for (int h = 0; h < 64; ++h) s += p[h * 192];
    pcs[b * 193 + c] = s;
  }
  __syncthreads();
  int c = c0 + (t & 15), bp = t >> 4;
#pragma unroll
  for (int half = 0; half < 2; ++half) {
    int b = bp + 16 * half;
    float a = 0.f;
    for (int k = 0; k < 192; ++k) a += pcs[b * 193 + k] * linW[(size_t)c * 192 + k];
    pooled[b * 192 + c] = linB[c] + a * (1.f / 4096.f);
  }
}

// ----------------------------------------------------------------------------
// kmap. grid (64, 3)
// ----------------------------------------------------------------------------
__global__ __launch_bounds__(256) void kmap_kernel(
    const float* A, const float* Wt, const float* bias, float* kout)
{
  __shared__ float As[32][65];
  __shared__ float Bs[32][65];
  int m0 = blockIdx.x * 64, n0 = blockIdx.y * 64;
  int t = threadIdx.x, tx = t & 15, ty = t >> 4;
  float acc[4][4] = {};
  for (int k0 = 0; k0 < 192; k0 += 32) {
    int kk = t & 31, mm = t >> 5;
#pragma unroll
    for (int i = 0; i < 8; ++i) {
      As[kk][mm + 8 * i] = A[(size_t)(m0 + mm + 8 * i) * 192 + k0 + kk];
      Bs[kk][mm + 8 * i] = Wt[(size_t)(n0 + mm + 8 * i) * 192 + k0 + kk];
    }
    __syncthreads();
    for (int k = 0; k < 32; ++k) {
      float a[4], bb[4];
#pragma unroll
      for (int i = 0; i < 4; ++i) a[i] = As[k][ty * 4 + i];
#pragma unroll
      for (int j = 0; j < 4; ++j) bb[j] = Bs[k][tx * 4 + j];
#pragma unroll
      for (int i = 0; i < 4; ++i)
#pragma unroll
        for (int j = 0; j < 4; ++j) acc[i][j] += a[i] * bb[j];
    }
    __syncthreads();
  }
  const float PI2 = 9.86960440108935862f;
  for (int i = 0; i < 4; ++i) {
    int m = m0 + ty * 4 + i;
    int ii = m >> 6, jj = m & 63;
    float d2 = (PI2 / 4096.f) * (float)(ii * ii + jj * jj);
    for (int j = 0; j < 4; ++j) {
      int n = n0 + tx * 4 + j;
      float e = acc[i][j] + bias[n];
      e = e > 0.f ? e : 0.f;
      kout[(size_t)m * 192 + n] = expf(-d2 * e);
    }
  }
}

// ----------------------------------------------------------------------------
// MLP + batchnorms + gumbel argmax -> sel[32] ; 1 block
// ----------------------------------------------------------------------------
__global__ __launch_bounds__(256) void mlp_kernel(
    const float* pooled, const float* gn,
    const float* p1w, const float* p1b, const float* g1, const float* b1,
    const float* p2w, const float* p2b, const float* g2, const float* b2,
    const float* p3w, const float* p3b, int* sel)
{
  __shared__ float pl[32 * 192];
  __shared__ float h1s[32 * 256];
  __shared__ float h2s[32 * 32];
  int t = threadIdx.x;
  for (int i = t; i < 32 * 192; i += 256) pl[i] = pooled[i];
  __syncthreads();
  {
    float acc[32];
    float bb = p1b[t];
#pragma unroll
    for (int b = 0; b < 32; ++b) acc[b] = bb;
    for (int c = 0; c < 192; ++c) {
      float w = p1w[t * 192 + c];
#pragma unroll
      for (int b = 0; b < 32; ++b) acc[b] += w * pl[b * 192 + c];
    }
    for (int b = 0; b < 32; ++b) {
      float v = acc[b];
      v = v > 0.f ? v : 0.1f * v;
      h1s[b * 256 + t] = v;
    }
  }
  __syncthreads();
  {
    float m = 0.f;
    for (int b = 0; b < 32; ++b) m += h1s[b * 256 + t];
    m *= (1.f / 32.f);
    float v = 0.f;
    for (int b = 0; b < 32; ++b) { float d = h1s[b * 256 + t] - m; v += d * d; }
    v *= (1.f / 32.f);
    float sc = g1[t] / sqrtf(v + 1e-5f);
    float sh = b1[t] - m * sc;
    for (int b = 0; b < 32; ++b) h1s[b * 256 + t] = h1s[b * 256 + t] * sc + sh;
  }
  __syncthreads();
  {
    int j = t & 31, bg = t >> 5;
    float acc[4];
    float bb = p2b[j];
    for (int i = 0; i < 4; ++i) acc[i] = bb;
    for (int c = 0; c < 256; ++c) {
      float w = p2w[j * 256 + c];
#pragma unroll
      for (int i = 0; i < 4; ++i) acc[i] += w * h1s[(bg * 4 + i) * 256 + c];
    }
    for (int i = 0; i < 4; ++i) {
      float v = acc[i];
      v = v > 0.f ? v : 0.1f * v;
      h2s[(bg * 4 + i) * 32 + j] = v;
    }
  }
  __syncthreads();
  if (t < 32) {
    float m = 0.f;
    for (int b = 0; b < 32; ++b) m += h2s[b * 32 + t];
    m *= (1.f / 32.f);
    float v = 0.f;
    for (int b = 0; b < 32; ++b) { float d = h2s[b * 32 + t] - m; v += d * d; }
    v *= (1.f / 32.f);
    float sc = g2[t] / sqrtf(v + 1e-5f);
    float sh = b2[t] - m * sc;
    for (int b = 0; b < 32; ++b) h2s[b * 32 + t] = h2s[b * 32 + t] * sc + sh;
  }
  __syncthreads();
  if (t < 32) {
    float best = -1e30f; int bi = 0;
    for (int r = 0; r < 3; ++r) {
      float l = p3b[r];
      for (int c = 0; c < 32; ++c) l += p3w[r * 32 + c] * h2s[t * 32 + c];
      l += gn[t * 3 + r];
      if (l > best) { best = l; bi = r; }
    }
    sel[t] = bi;
  }
}

// ----------------------------------------------------------------------------
// DCT stage over first axis of (64, 12288), in-place. grid (192, 32)
// ----------------------------------------------------------------------------
__global__ __launch_bounds__(256) void axis0_kernel(
    float* buf, const float* mat, const int* sel, int branch)
{
  int b = blockIdx.y;
  if (sel[b] != branch) return;
  int q0 = blockIdx.x * 64;
  __shared__ float mT[64][65];
  __shared__ float xs[64][65];
  int t = threadIdx.x;
  for (int i = t; i < 4096; i += 256) {
    int r = i >> 6, c = i & 63;
    mT[c][r] = mat[i];
    xs[r][c] = buf[(size_t)b * SLICE + r * 12288 + q0 + c];
  }
  __syncthreads();
  int tx = t & 15, ty = t >> 4;
  float acc[4][4] = {};
  for (int l = 0; l < 64; ++l) {
    float a[4], xv[4];
#pragma unroll
    for (int i = 0; i < 4; ++i) a[i] = mT[l][ty * 4 + i];
#pragma unroll
    for (int j = 0; j < 4; ++j) xv[j] = xs[l][tx * 4 + j];
#pragma unroll
    for (int i = 0; i < 4; ++i)
#pragma unroll
      for (int j = 0; j < 4; ++j) acc[i][j] += a[i] * xv[j];
  }
  float* ob = buf + (size_t)b * SLICE;
  for (int i = 0; i < 4; ++i)
    for (int j = 0; j < 4; ++j)
      ob[(ty * 4 + i) * 12288 + q0 + tx * 4 + j] = acc[i][j];
}

// DCT stage over middle axis, in-place, optional k multiply. grid (192, 32)
__global__ __launch_bounds__(256) void axis1_kernel(
    float* buf, const float* mat, const float* kmul, const int* sel, int branch)
{
  int b = blockIdx.y;
  if (sel[b] != branch) return;
  int n = blockIdx.x / 3;
  int ct = (blockIdx.x - n * 3) * 64;
  float* base = buf + (size_t)b * SLICE + n * (64 * 192) + ct;
  __shared__ float mT[64][65];
  __shared__ float xs[64][65];
  int t = threadIdx.x;
  for (int i = t; i < 4096; i += 256) {
    int r = i >> 6, c = i & 63;
    mT[c][r] = mat[i];
    xs[r][c] = base[r * 192 + c];
  }
  __syncthreads();
  int tx = t & 15, ty = t >> 4;
  float acc[4][4] = {};
  for (int l = 0; l < 64; ++l) {
    float a[4], xv[4];
#pragma unroll
    for (int i = 0; i < 4; ++i) a[i] = mT[l][ty * 4 + i];
#pragma unroll
    for (int j = 0; j < 4; ++j) xv[j] = xs[l][tx * 4 + j];
#pragma unroll
    for (int i = 0; i < 4; ++i)
#pragma unroll
      for (int j = 0; j < 4; ++j) acc[i][j] += a[i] * xv[j];
  }
  if (kmul) {
    for (int i = 0; i < 4; ++i)
      for (int j = 0; j < 4; ++j)
        acc[i][j] *= kmul[(size_t)(n * 64 + ty * 4 + i) * 192 + ct + tx * 4 + j];
  }
  for (int i = 0; i < 4; ++i)
    for (int j = 0; j < 4; ++j)
      base[(ty * 4 + i) * 192 + tx * 4 + j] = acc[i][j];
}

// ----------------------------------------------------------------------------
// DFT-8 butterfly, SGN=-1: X[k]=sum x_n e^{-2pi i nk/8}; SGN=+1: conjugated.
// ----------------------------------------------------------------------------
template<int SGN>
static DEVI void dft8(float* xr, float* xi) {
  const float s = 0.70710678118654752440f;
  float s0r = xr[0] + xr[4], s0i = xi[0] + xi[4];
  float s1r = xr[0] - xr[4], s1i = xi[0] - xi[4];
  float s2r = xr[2] + xr[6], s2i = xi[2] + xi[6];
  float s3r = xr[2] - xr[6], s3i = xi[2] - xi[6];
  float w3r = (SGN < 0) ? s3i : -s3i;
  float w3i = (SGN < 0) ? -s3r : s3r;
  float E0r = s0r + s2r, E0i = s0i + s2i;
  float E2r = s0r - s2r, E2i = s0i - s2i;
  float E1r = s1r + w3r, E1i = s1i + w3i;
  float E3r = s1r - w3r, E3i = s1i - w3i;
  float r0r = xr[1] + xr[5], r0i = xi[1] + xi[5];
  float r1r = xr[1] - xr[5], r1i = xi[1] - xi[5];
  float r2r = xr[3] + xr[7], r2i = xi[3] + xi[7];
  float r3r = xr[3] - xr[7], r3i = xi[3] - xi[7];
  float v3r = (SGN < 0) ? r3i : -r3i;
  float v3i = (SGN < 0) ? -r3r : r3r;
  float O0r = r0r + r2r, O0i = r0i + r2i;
  float O2r = r0r - r2r, O2i = r0i - r2i;
  float O1r = r1r + v3r, O1i = r1i + v3i;
  float O3r = r1r - v3r, O3i = r1i - v3i;
  xr[0] = E0r + O0r; xi[0] = E0i + O0i;
  xr[4] = E0r - O0r; xi[4] = E0i - O0i;
  float t2r = (SGN < 0) ? O2i : -O2i;
  float t2i = (SGN < 0) ? -O2r : O2r;
  xr[2] = E2r + t2r; xi[2] = E2i + t2i;
  xr[6] = E2r - t2r; xi[6] = E2i - t2i;
  float t1r = (SGN < 0) ? s * (O1r + O1i) : s * (O1r - O1i);
  float t1i = (SGN < 0) ? s * (O1i - O1r) : s * (O1r + O1i);
  xr[1] = E1r + t1r; xi[1] = E1i + t1i;
  xr[5] = E1r - t1r; xi[5] = E1i - t1i;
  float t3r = (SGN < 0) ? s * (O3i - O3r) : -s * (O3r + O3i);
  float t3i = (SGN < 0) ? -s * (O3r + O3i) : s * (O3r - O3i);
  xr[3] = E3r + t3r; xi[3] = E3i + t3i;
  xr[7] = E3r - t3r; xi[7] = E3i - t3i;
}

// ----------------------------------------------------------------------------
// In-place DFT-64 over the first index of a [64][33] float2 LDS tile, via
// radix-8 x radix-8 (same index algebra as fftc's verified stages).
// 256 threads = 8 p-slots x 32 cols. SGN=-1 fwd (e^-), SGN=+1 inv (e^+).
// Caller must __syncthreads() after staging; this fn ends synced.
// ----------------------------------------------------------------------------
template<int SGN>
static DEVI void fft64_tile(float2 (*T)[33], const float2* wtab, int t) {
  int col = t & 31, p = t >> 5;      // p in 0..7
  float xr[8], xi[8];
  // stage A: C_p[j] = (sum_q x[p+8q] w8^{qj}) * w64^{pj}
#pragma unroll
  for (int q = 0; q < 8; ++q) {
    float2 v = T[p + 8 * q][col];
    xr[q] = v.x; xi[q] = v.y;
  }
  dft8<SGN>(xr, xi);
#pragma unroll
  for (int j = 1; j < 8; ++j) {
    float2 w = wtab[p * j];
    float a = xr[j], b = xi[j];
    if (SGN < 0) { xr[j] = a * w.x - b * w.y; xi[j] = a * w.y + b * w.x; }
    else         { xr[j] = a * w.x + b * w.y; xi[j] = b * w.x - a * w.y; }
  }
  __syncthreads();
#pragma unroll
  for (int j = 0; j < 8; ++j)
    T[p * 8 + j][col] = make_float2(xr[j], xi[j]);
  __syncthreads();
  // stage B: X[j + 8 m2] = sum_p C_p[j] w8^{p m2}   (thread's j := p slot)
#pragma unroll
  for (int q = 0; q < 8; ++q) {
    float2 v = T[q * 8 + p][col];
    xr[q] = v.x; xi[q] = v.y;
  }
  dft8<SGN>(xr, xi);
  __syncthreads();
#pragma unroll
  for (int m2 = 0; m2 < 8; ++m2)
    T[p + 8 * m2][col] = make_float2(xr[m2], xi[m2]);
  __syncthreads();
}

// ----------------------------------------------------------------------------
// FFT forward over h (real -> complex), radix-8x8. grid (384, 32).
// real in-place into xh, imag -> Si. 32 cols of the 12288 (w,c)-dim per block.
// ----------------------------------------------------------------------------
__global__ __launch_bounds__(256) void ffth_kernel(
    float* xh, float* Si, const float2* E64, const int* sel)
{
  int b = blockIdx.y;
  if (sel[b] != 1) return;
  int q0 = blockIdx.x * 32;
  __shared__ __align__(16) float2 T[64][33];
  __shared__ float2 wtab[64];
  int t = threadIdx.x;
  for (int i = t; i < 2048; i += 256) {
    int r = i >> 5, c = i & 31;
    T[r][c] = make_float2(xh[(size_t)b * SLICE + (size_t)r * 12288 + q0 + c], 0.f);
  }
  if (t < 64) wtab[t] = E64[64 + t];
  __syncthreads();
  fft64_tile<-1>(T, wtab, t);
  for (int i = t; i < 2048; i += 256) {
    int r = i >> 5, c = i & 31;
    size_t o = (size_t)b * SLICE + (size_t)r * 12288 + q0 + c;
    float2 v = T[r][c];
    xh[o] = v.x;
    Si[o] = v.y;
  }
}

// FFT over w (complex, in-place), radix-8x8. grid (384, 32).
// DIR=-1 forward (old s=+1), DIR=+1 inverse (old s=-1).
template<int DIR>
__global__ __launch_bounds__(256) void fftw_kernel(
    float* Sr, float* Si, const float2* E64, const int* sel)
{
  int b = blockIdx.y;
  if (sel[b] != 1) return;
  int kh = blockIdx.x / 6;
  int ct = (blockIdx.x - kh * 6) * 32;
  float* br = Sr + (size_t)b * SLICE + kh * 12288 + ct;
  float* bi = Si + (size_t)b * SLICE + kh * 12288 + ct;
  __shared__ __align__(16) float2 T[64][33];
  __shared__ float2 wtab[64];
  int t = threadIdx.x;
  for (int i = t; i < 2048; i += 256) {
    int w = i >> 5, c = i & 31;
    T[w][c] = make_float2(br[w * 192 + c], bi[w * 192 + c]);
  }
  if (t < 64) wtab[t] = E64[64 + t];
  __syncthreads();
  fft64_tile<DIR>(T, wtab, t);
  for (int i = t; i < 2048; i += 256) {
    int w = i >> 5, c = i & 31;
    float2 v = T[w][c];
    br[w * 192 + c] = v.x;
    bi[w * 192 + c] = v.y;
  }
}

// ----------------------------------------------------------------------------
// Fused c-stage: radix-3 x (radix-8 x radix-8) Cooley-Tukey, fp32 exact.
// grid (128, 32). LDS 51.2 KB -> 3 blocks/CU.
// ----------------------------------------------------------------------------
__global__ __launch_bounds__(256, 3) void fftc_fused_kernel(
    float* Sr, float* Si, const float* kmap, const float2* E64, const int* sel)
{
  int b = blockIdx.y;
  if (sel[b] != 1) return;
  int m0 = blockIdx.x * 32;
  float* gr = Sr + (size_t)b * SLICE + (size_t)m0 * 192;
  float* gi = Si + (size_t)b * SLICE + (size_t)m0 * 192;
  __shared__ __align__(16) float2 T[192][33];
  __shared__ float2 wtab[64];          // w64^n (from E64 row 1)
  int t = threadIdx.x;
  for (int i = t; i < 6144; i += 256) {
    int row = i / 192, c = i - row * 192;
    T[c][row] = make_float2(gr[i], gi[i]);
  }
  if (t < 64) wtab[t] = E64[64 + t];
  __syncthreads();

  float xr[3][8], xim[3][8];

  // ---- fwd stage A ----
#pragma unroll
  for (int it = 0; it < 3; ++it) {
    int g = t + 256 * it;
    int row = g & 31, rest = g >> 5;
    int n1 = rest >> 3, p = rest & 7;
#pragma unroll
    for (int q = 0; q < 8; ++q) {
      float2 v = T[3 * (p + 8 * q) + n1][row];
      xr[it][q] = v.x; xim[it][q] = v.y;
    }
    dft8<-1>(xr[it], xim[it]);
#pragma unroll
    for (int j = 1; j < 8; ++j) {
      float2 w = wtab[p * j];
      float a = xr[it][j], bb = xim[it][j];
      xr[it][j]  = a * w.x - bb * w.y;
      xim[it][j] = a * w.y + bb * w.x;
    }
  }
  __syncthreads();
#pragma unroll
  for (int it = 0; it < 3; ++it) {
    int g = t + 256 * it;
    int row = g & 31, rest = g >> 5;
    int n1 = rest >> 3, p = rest & 7;
#pragma unroll
    for (int j = 0; j < 8; ++j)
      T[n1 * 64 + p * 8 + j][row] = make_float2(xr[it][j], xim[it][j]);
  }
  __syncthreads();

  // ---- fwd stage B ----
#pragma unroll
  for (int it = 0; it < 3; ++it) {
    int g = t + 256 * it;
    int row = g & 31, rest = g >> 5;
    int n1 = rest >> 3, j = rest & 7;
#pragma unroll
    for (int p = 0; p < 8; ++p) {
      float2 v = T[n1 * 64 + p * 8 + j][row];
      xr[it][p] = v.x; xim[it][p] = v.y;
    }
    dft8<-1>(xr[it], xim[it]);
  }
  __syncthreads();
#pragma unroll
  for (int it = 0; it < 3; ++it) {
    int g = t + 256 * it;
    int row = g & 31, rest = g >> 5;
    int n1 = rest >> 3, j = rest & 7;
#pragma unroll
    for (int m2 = 0; m2 < 8; ++m2)
      T[n1 * 64 + j + 8 * m2][row] = make_float2(xr[it][m2], xim[it][m2]);
  }
  __syncthreads();

  // ---- middle: W192 twiddle + radix-3 + k + inverse (owner-exclusive) ----
  {
    int tx = t & 31, ty = t >> 5;
    int rbase = ty * 4;
    double A = 2.0 * 3.14159265358979323846 * (double)tx;
    double sb, cb;
    sincos(A / 192.0, &sb, &cb);
    float cw = (float)cb, sw = (float)sb;
    const float S3 = 0.86602540378443864676f;
    float w1r[2], w1i[2], w2r[2], w2i[2];
    w1r[0] = cw;                   w1i[0] = -sw;
    w1r[1] = 0.5f * cw - S3 * sw;  w1i[1] = -S3 * cw - 0.5f * sw;
#pragma unroll
    for (int u = 0; u < 2; ++u) {
      w2r[u] = w1r[u] * w1r[u] - w1i[u] * w1i[u];
      w2i[u] = 2.f * w1r[u] * w1i[u];
    }
    float ar[2][3][4], ai[2][3][4];
#pragma unroll
    for (int u = 0; u < 2; ++u)
#pragma unroll
      for (int n1 = 0; n1 < 3; ++n1)
#pragma unroll
        for (int r = 0; r < 4; ++r) {
          float2 v = T[n1 * 64 + tx + 32 * u][rbase + r];
          ar[u][n1][r] = v.x; ai[u][n1][r] = v.y;
        }
    const float SCALE = 1.0f / 786432.0f;
#pragma unroll
    for (int u = 0; u < 2; ++u) {
      int m = tx + 32 * u;
#pragma unroll
      for (int r = 0; r < 4; ++r) {
        int row = rbase + r;
        float Y0r = ar[u][0][r], Y0i = ai[u][0][r];
        float Y1r = ar[u][1][r], Y1i = ai[u][1][r];
        float Y2r = ar[u][2][r], Y2i = ai[u][2][r];
        float T1r = Y1r * w1r[u] - Y1i * w1i[u];
        float T1i = Y1r * w1i[u] + Y1i * w1r[u];
        float T2r = Y2r * w2r[u] - Y2i * w2i[u];
        float T2i = Y2r * w2i[u] + Y2i * w2r[u];
        float aRr = T1r + T2r, aRi = T1i + T2i;
        float bRr = T1r - T2r, bRi = T1i - T2i;
        float X0r = Y0r + aRr, X0i = Y0i + aRi;
        float cfr = Y0r - 0.5f * aRr, cfi = Y0i - 0.5f * aRi;
        float X1r = cfr + S3 * bRi, X1i = cfi - S3 * bRr;
        float X2r = cfr - S3 * bRi, X2i = cfi + S3 * bRr;
        const float* kp = kmap + (size_t)(m0 + row) * 192 + m;
        float k0 = kp[0] * SCALE, k1 = kp[64] * SCALE, k2 = kp[128] * SCALE;
        X0r *= k0; X0i *= k0; X1r *= k1; X1i *= k1; X2r *= k2; X2i *= k2;
        float a2r = X1r + X2r, a2i = X1i + X2i;
        float b2r = X1r - X2r, b2i = X1i - X2i;
        float U0r = X0r + a2r, U0i = X0i + a2i;
        float c2r = X0r - 0.5f * a2r, c2i = X0i - 0.5f * a2i;
        float U1r = c2r - S3 * b2i, U1i = c2i + S3 * b2r;
        float U2r = c2r + S3 * b2i, U2i = c2i - S3 * b2r;
        ar[u][0][r] = U0r;
        ai[u][0][r] = U0i;
        ar[u][1][r] = U1r * w1r[u] + U1i * w1i[u];
        ai[u][1][r] = U1i * w1r[u] - U1r * w1i[u];
        ar[u][2][r] = U2r * w2r[u] + U2i * w2i[u];
        ai[u][2][r] = U2i * w2r[u] - U2r * w2i[u];
      }
    }
#pragma unroll
    for (int u = 0; u < 2; ++u)
#pragma unroll
      for (int n1 = 0; n1 < 3; ++n1)
#pragma unroll
        for (int r = 0; r < 4; ++r)
          T[n1 * 64 + tx + 32 * u][rbase + r] =
              make_float2(ar[u][n1][r], ai[u][n1][r]);
  }
  __syncthreads();

  // ---- inv stage A' ----
#pragma unroll
  for (int it = 0; it < 3; ++it) {
    int g = t + 256 * it;
    int row = g & 31, rest = g >> 5;
    int n1 = rest >> 3, mu = rest & 7;
#pragma unroll
    for (int nu = 0; nu < 8; ++nu) {
      float2 v = T[n1 * 64 + mu + 8 * nu][row];
      xr[it][nu] = v.x; xim[it][nu] = v.y;
    }
    dft8<1>(xr[it], xim[it]);
#pragma unroll
    for (int a = 1; a < 8; ++a) {
      float2 w = wtab[(mu * a) & 63];
      float aa = xr[it][a], bb = xim[it][a];
      xr[it][a]  = aa * w.x + bb * w.y;     // * conj(w)
      xim[it][a] = bb * w.x - aa * w.y;
    }
  }
  __syncthreads();
#pragma unroll
  for (int it = 0; it < 3; ++it) {
    int g = t + 256 * it;
    int row = g & 31, rest = g >> 5;
    int n1 = rest >> 3, mu = rest & 7;
#pragma unroll
    for (int a = 0; a < 8; ++a)
      T[n1 * 64 + mu * 8 + a][row] = make_float2(xr[it][a], xim[it][a]);
  }
  __syncthreads();

  // ---- inv stage B' ----
#pragma unroll
  for (int it = 0; it < 3; ++it) {
    int g = t + 256 * it;
    int row = g & 31, rest = g >> 5;
    int n1 = rest >> 3, aa = rest & 7;
#pragma unroll
    for (int mu = 0; mu < 8; ++mu) {
      float2 v = T[n1 * 64 + mu * 8 + aa][row];
      xr[it][mu] = v.x; xim[it][mu] = v.y;
    }
    dft8<1>(xr[it], xim[it]);
  }
  __syncthreads();
#pragma unroll
  for (int it = 0; it < 3; ++it) {
    int g = t + 256 * it;
    int row = g & 31, rest = g >> 5;
    int n1 = rest >> 3, aa = rest & 7;
#pragma unroll
    for (int bq = 0; bq < 8; ++bq)
      T[3 * (aa + 8 * bq) + n1][row] = make_float2(xr[it][bq], xim[it][bq]);
  }
  __syncthreads();

  for (int i = t; i < 6144; i += 256) {
    int row = i / 192, c = i - row * 192;
    float2 v = T[c][row];
    gr[i] = v.x;
    gi[i] = v.y;
  }
}

// inverse h-stage, real part only, radix-8x8, in-place into xh. grid (384, 32)
__global__ __launch_bounds__(256) void ffthi_kernel(
    float* Sr, const float* Si, const float2* E64, const int* sel)
{
  int b = blockIdx.y;
  if (sel[b] != 1) return;
  int q0 = blockIdx.x * 32;
  __shared__ __align__(16) float2 T[64][33];
  __shared__ float2 wtab[64];
  int t = threadIdx.x;
  for (int i = t; i < 2048; i += 256) {
    int r = i >> 5, c = i & 31;
    size_t o = (size_t)b * SLICE + (size_t)r * 12288 + q0 + c;
    T[r][c] = make_float2(Sr[o], Si[o]);
  }
  if (t < 64) wtab[t] = E64[64 + t];
  __syncthreads();
  fft64_tile<1>(T, wtab, t);
  for (int i = t; i < 2048; i += 256) {
    int r = i >> 5, c = i & 31;
    Sr[(size_t)b * SLICE + (size_t)r * 12288 + q0 + c] = T[r][c].x;
  }
}

// ----------------------------------------------------------------------------
// Haar branch, in-place on xh. grid (128, 32)
// ----------------------------------------------------------------------------
__global__ __launch_bounds__(256) void haar_kernel(
    float* xh, const float* kmap, const int* sel)
{
  int b = blockIdx.y;
  if (sel[b] != 2) return;
  int h = blockIdx.x >> 1;
  int w0 = (blockIdx.x & 1) * 32;
  size_t base = (size_t)b * SLICE + ((size_t)h * 64 + w0) * 192;
  __shared__ float A[32 * 192];
  __shared__ float Bf[32 * 192];
  int t = threadIdx.x;
  for (int i = t; i < 6144; i += 256) A[i] = xh[base + i];
  __syncthreads();
  for (int u = t; u < 32 * 96; u += 256) {
    int p = u / 96, r = u - p * 96;
    int ch = r >> 5, i = r & 31;
    float v0 = A[p * 192 + ch * 64 + 2 * i];
    float v1 = A[p * 192 + ch * 64 + 2 * i + 1];
    Bf[p * 192 + ch * 64 + i]      = (v0 + v1) * 0.5f;
    Bf[p * 192 + ch * 64 + 32 + i] = (v0 - v1) * 0.5f;
  }
  __syncthreads();
  for (int u = t; u < 32 * 96; u += 256) {
    int p = u / 96, i = u - p * 96;
    float v0 = Bf[p * 192 + 2 * i];
    float v1 = Bf[p * 192 + 2 * i + 1];
    A[p * 192 + i]      = (v0 + v1) * 0.5f;
    A[p * 192 + 96 + i] = (v0 - v1) * 0.5f;
  }
  __syncthreads();
  for (int i = t; i < 6144; i += 256)
    A[i] *= kmap[((size_t)h * 64 + w0) * 192 + i];
  __syncthreads();
  for (int u = t; u < 32 * 96; u += 256) {
    int p = u / 96, r = u - p * 96;
    int ch = r >> 5, i = r & 31;
    float a = A[p * 192 + ch * 64 + i];
    float d = A[p * 192 + ch * 64 + 32 + i];
    Bf[p * 192 + ch * 64 + 2 * i]     = a + d;
    Bf[p * 192 + ch * 64 + 2 * i + 1] = a - d;
  }
  __syncthreads();
  for (int u = t; u < 32 * 96; u += 256) {
    int p = u / 96, i = u - p * 96;
    float a = Bf[p * 192 + i];
    float d = Bf[p * 192 + 96 + i];
    A[p * 192 + 2 * i]     = a + d;
    A[p * 192 + 2 * i + 1] = a - d;
  }
  __syncthreads();
  for (int i = t; i < 6144; i += 256) xh[base + i] = A[i];
}

// ----------------------------------------------------------------------------
// final: LN(c) * silu(z) @ out_w^T + out_b via bf16 MFMA, dual-dtype store.
// grid 2048.
// ----------------------------------------------------------------------------
__global__ __launch_bounds__(256) void final_kernel(
    const float* comb, const bf16* zb, const float* lng, const float* lnb,
    const bf16* Ob, const float* outb, void* outp, const int* flag)
{
  int flg = *flag;
  int bi = blockIdx.x;
  int b = bi >> 6, h = bi & 63;
  size_t base = ((size_t)b * 4096 + (size_t)h * 64) * 192;
  __shared__ float As[12672];                  // max(64*196, 192*66)
  __shared__ __align__(16) short Ab[64 * 200];
  __shared__ float red[2][4][64];
  __shared__ float mu[64], rs[64];
  int t = threadIdx.x;
  for (int idx = t; idx < 3072; idx += 256) {
    int q = idx << 2;
    int p = idx / 48, c = q - p * 192;
    float4 v = *(const float4*)&comb[base + q];
    v.x = scrub(v.x); v.y = scrub(v.y); v.z = scrub(v.z); v.w = scrub(v.w);
    *(float4*)&As[p * 196 + c] = v;
  }
  __syncthreads();
  {
    int r = t & 63, part = t >> 6;
    const float* row = &As[r * 196 + part * 48];
    float s = 0.f, s2 = 0.f;
    for (int c = 0; c < 48; ++c) { float v = row[c]; s += v; s2 += v * v; }
    red[0][part][r] = s;
    red[1][part][r] = s2;
  }
  __syncthreads();
  if (t < 64) {
    float s  = red[0][0][t] + red[0][1][t] + red[0][2][t] + red[0][3][t];
    float s2 = red[1][0][t] + red[1][1][t] + red[1][2][t] + red[1][3][t];
    float m = s * (1.f / 192.f);
    float v = s2 * (1.f / 192.f) - m * m;
    v = v > 0.f ? v : 0.f;
    mu[t] = m;
    rs[t] = 1.f / sqrtf(v + 1e-5f);
  }
  __syncthreads();
  for (int idx = t; idx < 1536; idx += 256) {
    int q = idx << 3;
    int p = idx / 24, c = q - p * 192;
    float4 a0 = *(const float4*)&As[p * 196 + c];
    float4 a1 = *(const float4*)&As[p * 196 + c + 4];
    short8v z8 = *(const short8v*)&zb[base + q];
    float av[8] = {a0.x, a0.y, a0.z, a0.w, a1.x, a1.y, a1.z, a1.w};
    short o8[8];
    float m = mu[p], r = rs[p];
#pragma unroll
    for (int j = 0; j < 8; ++j) {
      float v = (av[j] - m) * r * lng[c + j] + lnb[c + j];
      float zv = scrub(bitsbf((unsigned short)z8[j]));
      v *= zv / (1.f + expf(-zv));
      o8[j] = f2bs(v);
    }
    *(short8v*)&Ab[p * 200 + c] = *(short8v*)o8;
  }
  __syncthreads();
  int wave = t >> 6, lane = t & 63;
  int lq = lane >> 4, lr = lane & 15;
  int n0 = wave * 48;
  float4v acc[4][3];
#pragma unroll
  for (int i = 0; i < 4; ++i)
#pragma unroll
    for (int j = 0; j < 3; ++j) acc[i][j] = (float4v){0.f, 0.f, 0.f, 0.f};
  for (int k0 = 0; k0 < 192; k0 += 32) {
    short8v af[4], bfr[3];
#pragma unroll
    for (int f = 0; f < 4; ++f)
      af[f] = *(const short8v*)&Ab[(f * 16 + lr) * 200 + k0 + lq * 8];
#pragma unroll
    for (int f = 0; f < 3; ++f)
      bfr[f] = *(const short8v*)&Ob[(size_t)(n0 + f * 16 + lr) * 192 + k0 + lq * 8];
#pragma unroll
    for (int fm = 0; fm < 4; ++fm)
#pragma unroll
      for (int fn = 0; fn < 3; ++fn)
        acc[fm][fn] = __builtin_amdgcn_mfma_f32_16x16x32_bf16(
            af[fm], bfr[fn], acc[fm][fn], 0, 0, 0);
  }
  __syncthreads();
#pragma unroll
  for (int fm = 0; fm < 4; ++fm)
#pragma unroll
    for (int e = 0; e < 4; ++e) {
      int p = fm * 16 + lq * 4 + e;
#pragma unroll
      for (int fn = 0; fn < 3; ++fn) {
        int co = n0 + fn * 16 + lr;
        As[co * 66 + p] = acc[fm][fn][e] + outb[co];
      }
    }
  __syncthreads();
  for (int e = t; e < 12288; e += 256) {
    int co = e >> 6, w = e & 63;
    size_t oi = (((size_t)b * 192 + co) * 64 + h) * 64 + w;
    float v = As[co * 66 + w];
    if (flg) ((float*)outp)[oi] = v;
    else     ((bf16*)outp)[oi] = __float2bfloat16(v);
  }
}

// ----------------------------------------------------------------------------
extern "C" void kernel_launch(void* const* d_in, const int* in_sizes, int n_in,
                              void* d_out, int out_size, void* d_ws, size_t ws_size,
                              hipStream_t stream) {
  (void)in_sizes; (void)n_in;
  if (ws_size < WS_NEEDED_BYTES) {
    fill_zero_kernel<<<(out_size + 255) / 256, 256, 0, stream>>>(
        (unsigned short*)d_out, out_size);
    return;
  }
  float* ws    = (float*)d_ws;
  float* xh    = ws + O_XH;
  float* Si    = ws + O_SI;
  bf16*  Yb    = (bf16*)(ws + O_YB);
  float* part  = ws + O_PART;
  bf16*  Wb    = (bf16*)(ws + O_WB);
  bf16*  zb    = (bf16*)(ws + O_ZB);
  float* kmap  = ws + O_KMAP;
  float2* E64  = (float2*)(ws + O_E64);
  float* Dm    = ws + O_DM;
  float* DT    = ws + O_DT;
  bf16*  Ob    = (bf16*)(ws + O_WT);
  float* pooled= ws + O_POOL;
  int*   sel   = (int*)(ws + O_SEL);
  int*   flag  = (int*)(ws + O_FLAG);

  sniff_kernel<<<1, 64, 0, stream>>>((const unsigned short*)d_in[0], flag);

  CvtArgs ca;
  const int srcidx[22] = {2,3,4,5,6,7,8,9,10,11,12,13,14,15,16,17,18,19,20,21,22,1};
  const int ns[22] = {96,1728,192,73728,384,49152,256,256,256,8192,32,32,32,96,3,
                      36864,192,192,192,36864,192,786432};
  const long long offs[22] = {
    (long long)W_GN,(long long)W_DWW,(long long)W_DWB,(long long)W_LINW,
    (long long)W_LINB,(long long)W_P1W,(long long)W_P1B,(long long)W_G1,
    (long long)W_B1,(long long)W_P2W,(long long)W_P2B,(long long)W_G2,
    (long long)W_B2,(long long)W_P3W,(long long)W_P3B,(long long)W_TOKW,
    (long long)W_TOKB,(long long)W_LNG,(long long)W_LNB,(long long)W_OUTW,
    (long long)W_OUTB,(long long)O_FREQ};
  for (int i = 0; i < 22; ++i) { ca.src[i] = d_in[srcidx[i]]; ca.n[i] = ns[i]; ca.off[i] = offs[i]; }
  cvt_kernel<<<64, 256, 0, stream>>>(ca, ws, flag);

  setup_kernel<<<64, 256, 0, stream>>>(Dm, DT, E64, Ob, ws + W_OUTW, Wb, ws + W_LINW);
  conv_kernel<<<dim3(6, 16, 32), 256, 0, stream>>>(d_in[0], flag, ws + W_DWW, ws + W_DWB,
                                                   Yb, part);
  linear_mfma_kernel<<<dim3(1024, 3), 256, 0, stream>>>(Yb, Wb, ws + W_LINB, xh, zb);
  pooled_kernel<<<12, 256, 0, stream>>>(part, ws + W_LINW, ws + W_LINB, pooled);
  mlp_kernel<<<1, 256, 0, stream>>>(pooled, ws + W_GN,
      ws + W_P1W, ws + W_P1B, ws + W_G1, ws + W_B1,
      ws + W_P2W, ws + W_P2B, ws + W_G2, ws + W_B2,
      ws + W_P3W, ws + W_P3B, sel);
  kmap_kernel<<<dim3(64, 3), 256, 0, stream>>>(ws + O_FREQ, ws + W_TOKW, ws + W_TOKB, kmap);
  // DCT branch (sel==0), in-place on xh
  axis0_kernel<<<dim3(192, 32), 256, 0, stream>>>(xh, Dm, sel, 0);
  axis1_kernel<<<dim3(192, 32), 256, 0, stream>>>(xh, Dm, kmap, sel, 0);
  axis1_kernel<<<dim3(192, 32), 256, 0, stream>>>(xh, DT, nullptr, sel, 0);
  axis0_kernel<<<dim3(192, 32), 256, 0, stream>>>(xh, DT, sel, 0);
  // FFT branch (sel==1); b-axis FFT/IFFT cancels analytically; in-place (xh,Si)
  ffth_kernel<<<dim3(384, 32), 256, 0, stream>>>(xh, Si, E64, sel);
  fftw_kernel<-1><<<dim3(384, 32), 256, 0, stream>>>(xh, Si, E64, sel);
  fftc_fused_kernel<<<dim3(128, 32), 256, 0, stream>>>(xh, Si, kmap, E64, sel);
  fftw_kernel<1><<<dim3(384, 32), 256, 0, stream>>>(xh, Si, E64, sel);
  ffthi_kernel<<<dim3(384, 32), 256, 0, stream>>>(xh, Si, E64, sel);
  // Haar branch (sel==2), in-place on xh
  haar_kernel<<<dim3(128, 32), 256, 0, stream>>>(xh, kmap, sel);
  // epilogue
  final_kernel<<<2048, 256, 0, stream>>>(xh, zb, ws + W_LNG, ws + W_LNB,
                                         Ob, ws + W_OUTB, d_out, flag);
}